// Round 2
// baseline (2088.731 us; speedup 1.0000x reference)
//
#include <hip/hip_runtime.h>
#include <hip/hip_bf16.h>
#include <math.h>

// Problem constants (fixed by setup_inputs): N=50000, E=800000, D=64, K=500, C=64
#define DD 64
#define KK 500
#define KK4 125

// ---------------- degree histogram ----------------
__global__ void hist_kernel(const int* __restrict__ rowv, const int* __restrict__ colv,
                            int* __restrict__ cnt_row, int* __restrict__ cnt_col, int E) {
    int e = blockIdx.x * blockDim.x + threadIdx.x;
    if (e >= E) return;
    atomicAdd(&cnt_row[rowv[e]], 1);
    atomicAdd(&cnt_col[colv[e]], 1);
}

// dinv = (1+outdeg)^-1/2 ; t initialized to dinv (self-loop term)
__global__ void dinv_kernel(const int* __restrict__ cnt_row, float* __restrict__ dinv,
                            float* __restrict__ t, int n) {
    int i = blockIdx.x * blockDim.x + threadIdx.x;
    if (i >= n) return;
    float deg = (float)(cnt_row[i] + 1);
    float di = 1.0f / sqrtf(deg);
    dinv[i] = di;
    t[i] = di;
}

// t[col_e] += dinv[row_e]  (bias aggregation scalar)
__global__ void tacc_kernel(const int* __restrict__ rowv, const int* __restrict__ colv,
                            const float* __restrict__ dinv, float* __restrict__ t, int E) {
    int e = blockIdx.x * blockDim.x + threadIdx.x;
    if (e >= E) return;
    atomicAdd(&t[colv[e]], dinv[rowv[e]]);
}

// xs = dinv[i] * x[i]  (float4 over N*16)
__global__ void xscale_kernel(const float* __restrict__ x, const float* __restrict__ dinv,
                              float* __restrict__ xs, int n16) {
    int idx = blockIdx.x * blockDim.x + threadIdx.x;
    if (idx >= n16) return;
    int i = idx >> 4;
    float di = dinv[i];
    float4 v = ((const float4*)x)[idx];
    ((float4*)xs)[idx] = make_float4(di*v.x, di*v.y, di*v.z, di*v.w);
}

// ---------------- exclusive scan (2 arrays, one block each) ----------------
__global__ void scan2_kernel(const int* __restrict__ cntA, int* __restrict__ offsA, int* __restrict__ curA,
                             const int* __restrict__ cntB, int* __restrict__ offsB, int* __restrict__ curB,
                             int n) {
    const int* cnt = blockIdx.x ? cntB : cntA;
    int* offs      = blockIdx.x ? offsB : offsA;
    int* cur       = blockIdx.x ? curB  : curA;
    __shared__ int sums[1024];
    int t = threadIdx.x;
    int chunk = (n + 1023) / 1024;
    int begin = min(t * chunk, n);
    int end   = min(begin + chunk, n);
    int s = 0;
    for (int i = begin; i < end; ++i) s += cnt[i];
    sums[t] = s;
    __syncthreads();
    for (int off = 1; off < 1024; off <<= 1) {
        int v = (t >= off) ? sums[t - off] : 0;
        __syncthreads();
        sums[t] += v;
        __syncthreads();
    }
    int run = (t == 0) ? 0 : sums[t - 1];
    for (int i = begin; i < end; ++i) {
        offs[i] = run; cur[i] = run; run += cnt[i];
    }
    if (t == 1023) offs[n] = sums[1023];
}

// ---------------- CSR placement (counting sort) ----------------
__global__ void place_kernel(const int* __restrict__ rowv, const int* __restrict__ colv,
                             int* __restrict__ cur_col, int* __restrict__ cur_row,
                             int* __restrict__ esrc, int* __restrict__ edst, int E) {
    int e = blockIdx.x * blockDim.x + threadIdx.x;
    if (e >= E) return;
    int r = rowv[e], c = colv[e];
    int p = atomicAdd(&cur_col[c], 1); esrc[p] = r;   // in-edge list of c
    int q = atomicAdd(&cur_row[r], 1); edst[q] = c;   // out-edge list of r
}

// ---------------- u[i] = xs[i] + sum_{in-edges} xs[src]; one wave/node ----------------
__global__ void agg_kernel(const float* __restrict__ xs, const int* __restrict__ offs,
                           const int* __restrict__ esrc, float* __restrict__ u, int n) {
    int wv = (blockIdx.x * blockDim.x + threadIdx.x) >> 6;
    int lane = threadIdx.x & 63;
    if (wv >= n) return;
    float acc = xs[(size_t)wv * 64 + lane];
    int p = offs[wv], pend = offs[wv + 1];
    for (; p + 1 < pend; p += 2) {
        int s0 = esrc[p], s1 = esrc[p + 1];
        float a = xs[(size_t)s0 * 64 + lane];
        float b = xs[(size_t)s1 * 64 + lane];
        acc += a + b;
    }
    if (p < pend) acc += xs[(size_t)esrc[p] * 64 + lane];
    u[(size_t)wv * 64 + lane] = acc;
}

// ---------------- Z = dinv*(u@W + t*b); 32 rows x 64 cols per block ----------------
__global__ void zgemm_kernel(const float* __restrict__ u, const float* __restrict__ W,
                             const float* __restrict__ bias, const float* __restrict__ dinv,
                             const float* __restrict__ tsum, float* __restrict__ out, int n) {
    const int C4 = 16;
    int r0 = blockIdx.x * 32;
    __shared__ float us[32 * 68];
    int t = threadIdx.x;
#pragma unroll
    for (int k = 0; k < 2; ++k) {
        int idx = t * 2 + k;
        int rr = idx >> 4, c4 = idx & 15;
        int row = r0 + rr;
        float4 v = make_float4(0.f, 0.f, 0.f, 0.f);
        if (row < n) v = ((const float4*)u)[(size_t)row * 16 + c4];
        *(float4*)&us[rr * 68 + c4 * 4] = v;
    }
    __syncthreads();
    int lr = t >> 3;
    int cg = t & 7;
    int f40 = cg * 2, f41 = f40 + 1;
    float4 acc0 = make_float4(0.f,0.f,0.f,0.f), acc1 = make_float4(0.f,0.f,0.f,0.f);
    const float4* W4 = (const float4*)W;
    for (int d = 0; d < 64; ++d) {
        float uv = us[lr * 68 + d];
        float4 w0 = W4[(size_t)d * C4 + f40];
        float4 w1 = W4[(size_t)d * C4 + f41];
        acc0.x += uv*w0.x; acc0.y += uv*w0.y; acc0.z += uv*w0.z; acc0.w += uv*w0.w;
        acc1.x += uv*w1.x; acc1.y += uv*w1.y; acc1.z += uv*w1.z; acc1.w += uv*w1.w;
    }
    int row = r0 + lr;
    if (row < n) {
        float di = dinv[row], tv = tsum[row];
        const float4* b4 = (const float4*)bias;
        float4* o4 = (float4*)out;
        float4 bv0 = b4[f40], bv1 = b4[f41];
        o4[(size_t)row * C4 + f40] = make_float4(di*(acc0.x+tv*bv0.x), di*(acc0.y+tv*bv0.y),
                                                 di*(acc0.z+tv*bv0.z), di*(acc0.w+tv*bv0.w));
        o4[(size_t)row * C4 + f41] = make_float4(di*(acc1.x+tv*bv1.x), di*(acc1.y+tv*bv1.y),
                                                 di*(acc1.z+tv*bv1.z), di*(acc1.w+tv*bv1.w));
    }
}

// ---------------- fused L = dinv*(u@W + t*b) + row softmax -> S; 16 rows/block ----------------
__global__ void lsoftmax_kernel(const float* __restrict__ u, const float* __restrict__ W,
                                const float* __restrict__ bias, const float* __restrict__ dinv,
                                const float* __restrict__ tsum, float* __restrict__ S, int n) {
    __shared__ float us[16 * 64];
    __shared__ float Ls[16 * 512];
    __shared__ float sd[16], st[16];
    int r0 = blockIdx.x * 16;
    int t = threadIdx.x;
    {
        int row = r0 + (t >> 4);
        float4 v = make_float4(0.f,0.f,0.f,0.f);
        if (row < n) v = ((const float4*)u)[(size_t)row * 16 + (t & 15)];
        *(float4*)&us[t * 4] = v;
        if (t < 16 && r0 + t < n) { sd[t] = dinv[r0 + t]; st[t] = tsum[r0 + t]; }
    }
    __syncthreads();
    int c0 = t * 2;
    if (c0 < KK) {
        float acc[16][2] = {};
        for (int d = 0; d < 64; ++d) {
            float w0 = W[(size_t)d * KK + c0], w1 = W[(size_t)d * KK + c0 + 1];
#pragma unroll
            for (int r = 0; r < 16; ++r) {
                float uv = us[r * 64 + d];
                acc[r][0] += uv * w0;
                acc[r][1] += uv * w1;
            }
        }
        float bv0 = bias[c0], bv1 = bias[c0 + 1];
#pragma unroll
        for (int r = 0; r < 16; ++r) {
            Ls[r * 512 + c0]     = sd[r] * (acc[r][0] + st[r] * bv0);
            Ls[r * 512 + c0 + 1] = sd[r] * (acc[r][1] + st[r] * bv1);
        }
    }
    __syncthreads();
    int w = t >> 6, lane = t & 63;
#pragma unroll
    for (int rr = 0; rr < 4; ++rr) {
        int r = w * 4 + rr;
        int grow = r0 + r;
        float v[8];
        float m = -1e30f;
#pragma unroll
        for (int j = 0; j < 8; ++j) {
            int idx = lane + j * 64;
            v[j] = (idx < KK) ? Ls[r * 512 + idx] : -1e30f;
            m = fmaxf(m, v[j]);
        }
#pragma unroll
        for (int o = 32; o > 0; o >>= 1) m = fmaxf(m, __shfl_xor(m, o, 64));
        float s = 0.f;
#pragma unroll
        for (int j = 0; j < 8; ++j) {
            int idx = lane + j * 64;
            if (idx < KK) { v[j] = expf(v[j] - m); s += v[j]; }
        }
#pragma unroll
        for (int o = 32; o > 0; o >>= 1) s += __shfl_xor(s, o, 64);
        float rs = 1.0f / s;
        if (grow < n) {
#pragma unroll
            for (int j = 0; j < 8; ++j) {
                int idx = lane + j * 64;
                if (idx < KK) S[(size_t)grow * KK + idx] = v[j] * rs;
            }
        }
    }
}

// ---------------- AS[r] = sum_{out-edges of r} S[dst]; one wave/node ----------------
__global__ void as_agg_kernel(const float* __restrict__ S, const int* __restrict__ offs,
                              const int* __restrict__ edst, float* __restrict__ AS, int n) {
    int wv = (blockIdx.x * blockDim.x + threadIdx.x) >> 6;
    int lane = threadIdx.x & 63;
    if (wv >= n) return;
    const float4* S4 = (const float4*)S;
    int i0 = lane;
    int i1 = lane + 64;
    bool v1 = (i1 < KK4);
    float4 a0 = make_float4(0.f,0.f,0.f,0.f), a1 = make_float4(0.f,0.f,0.f,0.f);
    int p = offs[wv], pend = offs[wv + 1];
    for (; p + 1 < pend; p += 2) {
        int c0 = edst[p], c1 = edst[p + 1];
        const float4* ra = S4 + (size_t)c0 * KK4;
        const float4* rb = S4 + (size_t)c1 * KK4;
        float4 qa0 = ra[i0], qb0 = rb[i0];
        a0.x += qa0.x + qb0.x; a0.y += qa0.y + qb0.y;
        a0.z += qa0.z + qb0.z; a0.w += qa0.w + qb0.w;
        if (v1) {
            float4 qa1 = ra[i1], qb1 = rb[i1];
            a1.x += qa1.x + qb1.x; a1.y += qa1.y + qb1.y;
            a1.z += qa1.z + qb1.z; a1.w += qa1.w + qb1.w;
        }
    }
    if (p < pend) {
        const float4* ra = S4 + (size_t)edst[p] * KK4;
        float4 qa0 = ra[i0];
        a0.x += qa0.x; a0.y += qa0.y; a0.z += qa0.z; a0.w += qa0.w;
        if (v1) { float4 qa1 = ra[i1];
                  a1.x += qa1.x; a1.y += qa1.y; a1.z += qa1.z; a1.w += qa1.w; }
    }
    float4* O4 = (float4*)AS;
    O4[(size_t)wv * KK4 + i0] = a0;
    if (v1) O4[(size_t)wv * KK4 + i1] = a1;
}

// ---------- out[a,b] += sum_n X[n,a]*Y[n,b]; 128x128 tile, 8x8/thread, split-N ----------
__global__ void gemm_tn128_kernel(const float* __restrict__ X, const float* __restrict__ Y,
                                  float* __restrict__ out, int n, int KA, int KB, int nPerBlock) {
    const int a0 = blockIdx.x * 128, b0 = blockIdx.y * 128;
    const int nbeg = blockIdx.z * nPerBlock;
    const int nend = min(nbeg + nPerBlock, n);
    __shared__ float Xs[8 * 128];
    __shared__ float Ys[8 * 128];
    const int t = threadIdx.x;
    const int tx = t & 15, ty = t >> 4;
    const int KA4 = KA >> 2, KB4 = KB >> 2;
    const int a04 = a0 >> 2, b04 = b0 >> 2;
    const int nr = t >> 5, f4 = t & 31;
    float acc[8][8] = {};
    for (int nb = nbeg; nb < nend; nb += 8) {
        __syncthreads();
        int nn = nb + nr;
        float4 vx = make_float4(0.f,0.f,0.f,0.f), vy = make_float4(0.f,0.f,0.f,0.f);
        if (nn < nend) {
            if (a04 + f4 < KA4) vx = ((const float4*)X)[(size_t)nn * KA4 + a04 + f4];
            if (b04 + f4 < KB4) vy = ((const float4*)Y)[(size_t)nn * KB4 + b04 + f4];
        }
        *(float4*)&Xs[nr * 128 + f4 * 4] = vx;
        *(float4*)&Ys[nr * 128 + f4 * 4] = vy;
        __syncthreads();
#pragma unroll
        for (int kk = 0; kk < 8; ++kk) {
            float xa[8], yb[8];
            *(float4*)&xa[0] = *(const float4*)&Xs[kk * 128 + tx * 8];
            *(float4*)&xa[4] = *(const float4*)&Xs[kk * 128 + tx * 8 + 4];
            *(float4*)&yb[0] = *(const float4*)&Ys[kk * 128 + ty * 8];
            *(float4*)&yb[4] = *(const float4*)&Ys[kk * 128 + ty * 8 + 4];
#pragma unroll
            for (int i = 0; i < 8; ++i)
#pragma unroll
                for (int j = 0; j < 8; ++j)
                    acc[i][j] += xa[i] * yb[j];
        }
    }
#pragma unroll
    for (int i = 0; i < 8; ++i) {
        int a = a0 + tx * 8 + i;
        if (a < KA) {
#pragma unroll
            for (int j = 0; j < 8; ++j) {
                int b = b0 + ty * 8 + j;
                if (b < KB) atomicAdd(&out[(size_t)a * KB + b], acc[i][j]);
            }
        }
    }
}

extern "C" void kernel_launch(void* const* d_in, const int* in_sizes, int n_in,
                              void* d_out, int out_size, void* d_ws, size_t ws_size,
                              hipStream_t stream) {
    const float* x        = (const float*)d_in[0];
    const int*   ei       = (const int*)d_in[1];
    const float* W_embed  = (const float*)d_in[2];
    const float* b_embed  = (const float*)d_in[3];
    const float* W_assign = (const float*)d_in[4];
    const float* b_assign = (const float*)d_in[5];

    const int N = in_sizes[0] / DD;     // 50000
    const int E = in_sizes[1] / 2;      // 800000
    const int C = in_sizes[3];          // 64
    const int K = in_sizes[5];          // 500

    const int* rowv = ei;               // sources
    const int* colv = ei + E;           // targets

    char* p = (char*)d_ws;
    auto alloc = [&](size_t bytes) -> void* {
        void* r = (void*)p;
        p += (bytes + 255) & ~(size_t)255;
        return r;
    };
    int*   cnt_col  = (int*)alloc((size_t)N * 4);
    int*   cnt_row  = (int*)alloc((size_t)N * 4);
    int*   offs_col = (int*)alloc((size_t)(N + 1) * 4);
    int*   offs_row = (int*)alloc((size_t)(N + 1) * 4);
    int*   cur_col  = (int*)alloc((size_t)N * 4);
    int*   cur_row  = (int*)alloc((size_t)N * 4);
    float* dinv     = (float*)alloc((size_t)N * 4);
    float* tsum     = (float*)alloc((size_t)N * 4);
    int*   esrc     = (int*)alloc((size_t)E * 4);
    int*   edst     = (int*)alloc((size_t)E * 4);
    float* xs       = (float*)alloc((size_t)N * DD * 4);   // dinv*x; reused as Z
    float* u        = (float*)alloc((size_t)N * DD * 4);   // shared GCN aggregation
    float* S        = (float*)alloc((size_t)N * KK * 4);   // softmax assignments
    float* AS       = (float*)alloc((size_t)N * KK * 4);   // A @ S

    float* Z = xs;                      // alias: xs dead after agg_kernel
    float* outX = (float*)d_out;        // [K, C]
    float* outA = outX + (size_t)K * C; // [K, K]

    hipMemsetAsync(cnt_col, 0, (size_t)N * 4, stream);
    hipMemsetAsync(cnt_row, 0, (size_t)N * 4, stream);
    hipMemsetAsync(d_out, 0, (size_t)out_size * 4, stream);

    hist_kernel<<<(E + 255) / 256, 256, 0, stream>>>(rowv, colv, cnt_row, cnt_col, E);
    dinv_kernel<<<(N + 255) / 256, 256, 0, stream>>>(cnt_row, dinv, tsum, N);
    tacc_kernel<<<(E + 255) / 256, 256, 0, stream>>>(rowv, colv, dinv, tsum, E);
    xscale_kernel<<<(N * 16 + 255) / 256, 256, 0, stream>>>(x, dinv, xs, N * 16);
    scan2_kernel<<<2, 1024, 0, stream>>>(cnt_col, offs_col, cur_col,
                                         cnt_row, offs_row, cur_row, N);
    place_kernel<<<(E + 255) / 256, 256, 0, stream>>>(rowv, colv, cur_col, cur_row, esrc, edst, E);

    // shared aggregation u = (A_hat-weighted sum of dinv*x)
    agg_kernel<<<(N + 3) / 4, 256, 0, stream>>>(xs, offs_col, esrc, u, N);

    // Z = dinv*(u@W_embed + t*b_embed)   (writes over xs)
    zgemm_kernel<<<(N + 31) / 32, 256, 0, stream>>>(u, W_embed, b_embed, dinv, tsum, Z, N);

    // S = softmax(dinv*(u@W_assign + t*b_assign))
    lsoftmax_kernel<<<(N + 15) / 16, 256, 0, stream>>>(u, W_assign, b_assign, dinv, tsum, S, N);

    // AS = A @ S
    as_agg_kernel<<<(N + 3) / 4, 256, 0, stream>>>(S, offs_row, edst, AS, N);

    // next_X = S^T @ Z   [500 x 64]
    {
        int nPer = 200;
        dim3 g((K + 127) / 128, 1, (N + nPer - 1) / nPer);
        gemm_tn128_kernel<<<g, 256, 0, stream>>>(S, Z, outX, N, K, C, nPer);
    }
    // next_A = S^T @ AS  [500 x 500]
    {
        int nPer = 800;
        dim3 g((K + 127) / 128, (K + 127) / 128, (N + nPer - 1) / nPer);
        gemm_tn128_kernel<<<g, 256, 0, stream>>>(S, AS, outA, N, K, K, nPer);
    }
}

// Round 3
// 831.920 us; speedup vs baseline: 2.5107x; 2.5107x over previous
//
#include <hip/hip_runtime.h>
#include <hip/hip_bf16.h>
#include <math.h>

// Problem constants: N=50000, E=800000, D=64, K=500, C=64
#define DD 64
#define KK 500
#define KPAD 512
#define NPAD 50048   // N padded to multiple of 64

typedef __attribute__((ext_vector_type(8))) short bf16x8;
typedef __attribute__((ext_vector_type(4))) float f32x4;

__device__ inline unsigned short f2bf(float f) {
    unsigned u = __float_as_uint(f);
    u += 0x7fffu + ((u >> 16) & 1u);          // RNE
    return (unsigned short)(u >> 16);
}
__device__ inline unsigned packbf(float lo, float hi) {
    return ((unsigned)f2bf(hi) << 16) | (unsigned)f2bf(lo);
}

// ---------------- degree histogram ----------------
__global__ void hist_kernel(const int* __restrict__ rowv, const int* __restrict__ colv,
                            int* __restrict__ cnt_row, int* __restrict__ cnt_col, int E) {
    int e = blockIdx.x * blockDim.x + threadIdx.x;
    if (e >= E) return;
    atomicAdd(&cnt_row[rowv[e]], 1);
    atomicAdd(&cnt_col[colv[e]], 1);
}

__global__ void dinv_kernel(const int* __restrict__ cnt_row, float* __restrict__ dinv,
                            float* __restrict__ t, int n) {
    int i = blockIdx.x * blockDim.x + threadIdx.x;
    if (i >= n) return;
    float deg = (float)(cnt_row[i] + 1);
    float di = 1.0f / sqrtf(deg);
    dinv[i] = di;
    t[i] = di;
}

__global__ void tacc_kernel(const int* __restrict__ rowv, const int* __restrict__ colv,
                            const float* __restrict__ dinv, float* __restrict__ t, int E) {
    int e = blockIdx.x * blockDim.x + threadIdx.x;
    if (e >= E) return;
    atomicAdd(&t[colv[e]], dinv[rowv[e]]);
}

// ---------------- exclusive scan (2 arrays, one block each) ----------------
__global__ void scan2_kernel(const int* __restrict__ cntA, int* __restrict__ offsA, int* __restrict__ curA,
                             const int* __restrict__ cntB, int* __restrict__ offsB, int* __restrict__ curB,
                             int n) {
    const int* cnt = blockIdx.x ? cntB : cntA;
    int* offs      = blockIdx.x ? offsB : offsA;
    int* cur       = blockIdx.x ? curB  : curA;
    __shared__ int sums[1024];
    int t = threadIdx.x;
    int chunk = (n + 1023) / 1024;
    int begin = min(t * chunk, n);
    int end   = min(begin + chunk, n);
    int s = 0;
    for (int i = begin; i < end; ++i) s += cnt[i];
    sums[t] = s;
    __syncthreads();
    for (int off = 1; off < 1024; off <<= 1) {
        int v = (t >= off) ? sums[t - off] : 0;
        __syncthreads();
        sums[t] += v;
        __syncthreads();
    }
    int run = (t == 0) ? 0 : sums[t - 1];
    for (int i = begin; i < end; ++i) {
        offs[i] = run; cur[i] = run; run += cnt[i];
    }
    if (t == 1023) offs[n] = sums[1023];
}

// ---------------- CSR placement ----------------
__global__ void place_kernel(const int* __restrict__ rowv, const int* __restrict__ colv,
                             int* __restrict__ cur_col, int* __restrict__ cur_row,
                             int* __restrict__ esrc, int* __restrict__ edst, int E) {
    int e = blockIdx.x * blockDim.x + threadIdx.x;
    if (e >= E) return;
    int r = rowv[e], c = colv[e];
    int p = atomicAdd(&cur_col[c], 1); esrc[p] = r;
    int q = atomicAdd(&cur_row[r], 1); edst[q] = c;
}

// ---------------- u[i] = dinv[i]*x[i] + sum_{in} dinv[s]*x[s]; one wave/node ----------------
__global__ void agg_kernel(const float* __restrict__ x, const float* __restrict__ dinv,
                           const int* __restrict__ offs, const int* __restrict__ esrc,
                           float* __restrict__ u, int n) {
    int wv = (blockIdx.x * blockDim.x + threadIdx.x) >> 6;
    int lane = threadIdx.x & 63;
    if (wv >= n) return;
    float acc = dinv[wv] * x[(size_t)wv * 64 + lane];
    int p = offs[wv], pend = offs[wv + 1];
    for (; p + 1 < pend; p += 2) {
        int s0 = esrc[p], s1 = esrc[p + 1];
        float w0 = dinv[s0], w1 = dinv[s1];
        acc += w0 * x[(size_t)s0 * 64 + lane] + w1 * x[(size_t)s1 * 64 + lane];
    }
    if (p < pend) { int s = esrc[p]; acc += dinv[s] * x[(size_t)s * 64 + lane]; }
    u[(size_t)wv * 64 + lane] = acc;
}

// ---------------- Z_b = bf16( dinv*(u@W + t*b) ); [N][64] bf16 ----------------
__global__ void zgemm_kernel(const float* __restrict__ u, const float* __restrict__ W,
                             const float* __restrict__ bias, const float* __restrict__ dinv,
                             const float* __restrict__ tsum, unsigned short* __restrict__ Zb, int n) {
    const int C4 = 16;
    int r0 = blockIdx.x * 32;
    __shared__ float us[32 * 68];
    int t = threadIdx.x;
#pragma unroll
    for (int k = 0; k < 2; ++k) {
        int idx = t * 2 + k;
        int rr = idx >> 4, c4 = idx & 15;
        int row = r0 + rr;
        float4 v = make_float4(0.f, 0.f, 0.f, 0.f);
        if (row < n) v = ((const float4*)u)[(size_t)row * 16 + c4];
        *(float4*)&us[rr * 68 + c4 * 4] = v;
    }
    __syncthreads();
    int lr = t >> 3;
    int cg = t & 7;
    int f40 = cg * 2, f41 = f40 + 1;
    float4 acc0 = make_float4(0.f,0.f,0.f,0.f), acc1 = make_float4(0.f,0.f,0.f,0.f);
    const float4* W4 = (const float4*)W;
    for (int d = 0; d < 64; ++d) {
        float uv = us[lr * 68 + d];
        float4 w0 = W4[(size_t)d * C4 + f40];
        float4 w1 = W4[(size_t)d * C4 + f41];
        acc0.x += uv*w0.x; acc0.y += uv*w0.y; acc0.z += uv*w0.z; acc0.w += uv*w0.w;
        acc1.x += uv*w1.x; acc1.y += uv*w1.y; acc1.z += uv*w1.z; acc1.w += uv*w1.w;
    }
    int row = r0 + lr;
    if (row < n) {
        float di = dinv[row], tv = tsum[row];
        const float4* b4 = (const float4*)bias;
        float4 bv0 = b4[f40], bv1 = b4[f41];
        float z0 = di*(acc0.x+tv*bv0.x), z1 = di*(acc0.y+tv*bv0.y);
        float z2 = di*(acc0.z+tv*bv0.z), z3 = di*(acc0.w+tv*bv0.w);
        float z4 = di*(acc1.x+tv*bv1.x), z5 = di*(acc1.y+tv*bv1.y);
        float z6 = di*(acc1.z+tv*bv1.z), z7 = di*(acc1.w+tv*bv1.w);
        uint4 o;
        o.x = packbf(z0, z1); o.y = packbf(z2, z3);
        o.z = packbf(z4, z5); o.w = packbf(z6, z7);
        ((uint4*)Zb)[(size_t)row * 8 + cg] = o;
    }
}

// ---------------- fused L = dinv*(u@W + t*b) + row softmax -> S_b bf16 [N][512] ----------------
__global__ void lsoftmax_kernel(const float* __restrict__ u, const float* __restrict__ W,
                                const float* __restrict__ bias, const float* __restrict__ dinv,
                                const float* __restrict__ tsum, unsigned short* __restrict__ Sb, int n) {
    __shared__ float us[16 * 64];
    __shared__ float Ls[16 * 512];
    __shared__ float sd[16], st[16];
    int r0 = blockIdx.x * 16;
    int t = threadIdx.x;
    {
        int row = r0 + (t >> 4);
        float4 v = make_float4(0.f,0.f,0.f,0.f);
        if (row < n) v = ((const float4*)u)[(size_t)row * 16 + (t & 15)];
        *(float4*)&us[t * 4] = v;
        if (t < 16 && r0 + t < n) { sd[t] = dinv[r0 + t]; st[t] = tsum[r0 + t]; }
    }
    __syncthreads();
    int c0 = t * 2;
    if (c0 < KK) {
        float acc[16][2] = {};
        for (int d = 0; d < 64; ++d) {
            float w0 = W[(size_t)d * KK + c0], w1 = W[(size_t)d * KK + c0 + 1];
#pragma unroll
            for (int r = 0; r < 16; ++r) {
                float uv = us[r * 64 + d];
                acc[r][0] += uv * w0;
                acc[r][1] += uv * w1;
            }
        }
        float bv0 = bias[c0], bv1 = bias[c0 + 1];
#pragma unroll
        for (int r = 0; r < 16; ++r) {
            Ls[r * 512 + c0]     = sd[r] * (acc[r][0] + st[r] * bv0);
            Ls[r * 512 + c0 + 1] = sd[r] * (acc[r][1] + st[r] * bv1);
        }
    }
    __syncthreads();
    int w = t >> 6, lane = t & 63;
#pragma unroll
    for (int rr = 0; rr < 4; ++rr) {
        int r = w * 4 + rr;
        int grow = r0 + r;
        float v[8];
        float m = -1e30f;
#pragma unroll
        for (int j = 0; j < 8; ++j) {
            int idx = lane + j * 64;
            v[j] = (idx < KK) ? Ls[r * 512 + idx] : -1e30f;
            m = fmaxf(m, v[j]);
        }
#pragma unroll
        for (int o = 32; o > 0; o >>= 1) m = fmaxf(m, __shfl_xor(m, o, 64));
        float s = 0.f;
#pragma unroll
        for (int j = 0; j < 8; ++j) {
            int idx = lane + j * 64;
            if (idx < KK) { v[j] = expf(v[j] - m); s += v[j]; }
        }
#pragma unroll
        for (int o = 32; o > 0; o >>= 1) s += __shfl_xor(s, o, 64);
        float rs = 1.0f / s;
        if (grow < n) {
#pragma unroll
            for (int j = 0; j < 8; ++j) {
                int idx = lane + j * 64;
                unsigned short h = (idx < KK) ? f2bf(v[j] * rs) : (unsigned short)0;
                Sb[(size_t)grow * KPAD + idx] = h;
            }
        }
    }
}

// ---------------- AS_b[r] = bf16( sum_{out-edges of r} S_b[dst] ); one wave/node ----------------
__global__ void as_agg_b(const unsigned short* __restrict__ Sb, const int* __restrict__ offs,
                         const int* __restrict__ edst, unsigned short* __restrict__ ASb, int n) {
    int wv = (blockIdx.x * blockDim.x + threadIdx.x) >> 6;
    int ln = threadIdx.x & 63;
    if (wv >= n) return;
    const uint4* S4 = (const uint4*)Sb;   // 64 uint4 per row (512 bf16)
    float a0=0,a1=0,a2=0,a3=0,a4=0,a5=0,a6=0,a7=0;
    int p = offs[wv], pend = offs[wv + 1];
    for (; p < pend; ++p) {
        int c = edst[p];
        uint4 v = S4[(size_t)c * 64 + ln];
        a0 += __uint_as_float(v.x << 16);  a1 += __uint_as_float(v.x & 0xffff0000u);
        a2 += __uint_as_float(v.y << 16);  a3 += __uint_as_float(v.y & 0xffff0000u);
        a4 += __uint_as_float(v.z << 16);  a5 += __uint_as_float(v.z & 0xffff0000u);
        a6 += __uint_as_float(v.w << 16);  a7 += __uint_as_float(v.w & 0xffff0000u);
    }
    uint4 o;
    o.x = packbf(a0, a1); o.y = packbf(a2, a3);
    o.z = packbf(a4, a5); o.w = packbf(a6, a7);
    ((uint4*)ASb)[(size_t)wv * 64 + ln] = o;
}

// ---------------- bf16 transpose: in[N][Cin] -> out[Cout][NPAD], zero-filled ----------------
__global__ void transpose_bf16(const unsigned short* __restrict__ in, unsigned short* __restrict__ out,
                               int N, int Cin) {
    __shared__ unsigned short tl[64 * 72];
    int n0 = blockIdx.x * 64, c0 = blockIdx.y * 64;
    int t = threadIdx.x;
    int r = t >> 2, s = t & 3;
    int n = n0 + r;
#pragma unroll
    for (int h = 0; h < 2; ++h) {
        int c = c0 + s * 16 + h * 8;
        uint4 v = make_uint4(0u, 0u, 0u, 0u);
        if (n < N && c < Cin) v = *(const uint4*)&in[(size_t)n * Cin + c];
        *(uint4*)&tl[r * 72 + s * 16 + h * 8] = v;
    }
    __syncthreads();
    int cc = t >> 2, seg = t & 3;
    unsigned wbuf[8];
#pragma unroll
    for (int k = 0; k < 8; ++k) {
        unsigned short lo = tl[(seg * 16 + 2 * k)     * 72 + cc];
        unsigned short hi = tl[(seg * 16 + 2 * k + 1) * 72 + cc];
        wbuf[k] = ((unsigned)hi << 16) | (unsigned)lo;
    }
    size_t ob = (size_t)(c0 + cc) * NPAD + n0 + seg * 16;
    *(uint4*)&out[ob]     = make_uint4(wbuf[0], wbuf[1], wbuf[2], wbuf[3]);
    *(uint4*)&out[ob + 8] = make_uint4(wbuf[4], wbuf[5], wbuf[6], wbuf[7]);
}

// ---------------- MFMA TN GEMM: partial[z][a][b] = sum_{n in slice} A_T[a][n]*B_T[b][n] ---------
// A_T: [512][NPAD] bf16, B_T: [NBpad][NPAD] bf16. Block: 128a x 128b, 4 waves (2x2 of 64x64).
__global__ void __launch_bounds__(256) mfma_tn_kernel(
        const unsigned short* __restrict__ A_T, const unsigned short* __restrict__ B_T,
        float* __restrict__ partial, int nPer, int NBpad) {
    const int a0 = blockIdx.x * 128, b0 = blockIdx.y * 128;
    const int nbeg = blockIdx.z * nPer;
    const int nend = min(nbeg + nPer, NPAD);
    __shared__ unsigned short Al[128 * 72];  // rows a, 64 n-cols (+8 pad)
    __shared__ unsigned short Bl[128 * 72];
    const int t = threadIdx.x;
    const int ln = t & 63, wv = t >> 6;
    const int wa = (wv & 1) * 64, wb = (wv >> 1) * 64;
    const int lm = ln & 15, lk = (ln >> 4) * 8;
    f32x4 acc[4][4];
#pragma unroll
    for (int i = 0; i < 4; ++i)
#pragma unroll
        for (int j = 0; j < 4; ++j) acc[i][j] = (f32x4){0.f, 0.f, 0.f, 0.f};
    for (int nb = nbeg; nb < nend; nb += 64) {
        __syncthreads();
#pragma unroll
        for (int i = 0; i < 4; ++i) {
            int idx = t + i * 256;
            int r = idx >> 3, c8 = (idx & 7) * 8;
            uint4 va = *(const uint4*)&A_T[(size_t)(a0 + r) * NPAD + nb + c8];
            uint4 vb = *(const uint4*)&B_T[(size_t)(b0 + r) * NPAD + nb + c8];
            *(uint4*)&Al[r * 72 + c8] = va;
            *(uint4*)&Bl[r * 72 + c8] = vb;
        }
        __syncthreads();
#pragma unroll
        for (int ks = 0; ks < 64; ks += 32) {
            bf16x8 af[4], bfr[4];
#pragma unroll
            for (int i = 0; i < 4; ++i)
                af[i] = *(const bf16x8*)&Al[(wa + i * 16 + lm) * 72 + ks + lk];
#pragma unroll
            for (int j = 0; j < 4; ++j)
                bfr[j] = *(const bf16x8*)&Bl[(wb + j * 16 + lm) * 72 + ks + lk];
#pragma unroll
            for (int i = 0; i < 4; ++i)
#pragma unroll
                for (int j = 0; j < 4; ++j)
                    acc[i][j] = __builtin_amdgcn_mfma_f32_16x16x32_bf16(af[i], bfr[j], acc[i][j], 0, 0, 0);
        }
    }
    float* op = partial + (size_t)blockIdx.z * 512 * NBpad;
#pragma unroll
    for (int i = 0; i < 4; ++i) {
#pragma unroll
        for (int j = 0; j < 4; ++j) {
            int bg = b0 + wb + j * 16 + lm;
#pragma unroll
            for (int r = 0; r < 4; ++r) {
                int ag = a0 + wa + i * 16 + (ln >> 4) * 4 + r;
                op[(size_t)ag * NBpad + bg] = acc[i][j][r];
            }
        }
    }
}

// ---------------- split-K reduce: out[a][b] = sum_z partial[z][a][b] ----------------
__global__ void reduce_kernel(const float* __restrict__ partial, float* __restrict__ out,
                              int rows, int cols, int NBpad, int Z) {
    int idx = blockIdx.x * blockDim.x + threadIdx.x;
    if (idx >= rows * cols) return;
    int a = idx / cols, b = idx - a * cols;
    const float* p = partial + (size_t)a * NBpad + b;
    size_t step = (size_t)512 * NBpad;
    float s = 0.f;
    for (int z = 0; z < Z; ++z) s += p[(size_t)z * step];
    out[idx] = s;
}

extern "C" void kernel_launch(void* const* d_in, const int* in_sizes, int n_in,
                              void* d_out, int out_size, void* d_ws, size_t ws_size,
                              hipStream_t stream) {
    const float* x        = (const float*)d_in[0];
    const int*   ei       = (const int*)d_in[1];
    const float* W_embed  = (const float*)d_in[2];
    const float* b_embed  = (const float*)d_in[3];
    const float* W_assign = (const float*)d_in[4];
    const float* b_assign = (const float*)d_in[5];

    const int N = in_sizes[0] / DD;     // 50000
    const int E = in_sizes[1] / 2;      // 800000
    const int C = in_sizes[3];          // 64
    const int K = in_sizes[5];          // 500

    const int* rowv = ei;
    const int* colv = ei + E;

    char* p = (char*)d_ws;
    auto alloc = [&](size_t bytes) -> void* {
        void* r = (void*)p;
        p += (bytes + 255) & ~(size_t)255;
        return r;
    };
    int*   cnt_col  = (int*)alloc((size_t)N * 4);
    int*   cnt_row  = (int*)alloc((size_t)N * 4);
    int*   offs_col = (int*)alloc((size_t)(N + 1) * 4);
    int*   offs_row = (int*)alloc((size_t)(N + 1) * 4);
    int*   cur_col  = (int*)alloc((size_t)N * 4);
    int*   cur_row  = (int*)alloc((size_t)N * 4);
    float* dinv     = (float*)alloc((size_t)N * 4);
    float* tsum     = (float*)alloc((size_t)N * 4);
    int*   esrc     = (int*)alloc((size_t)E * 4);
    int*   edst     = (int*)alloc((size_t)E * 4);
    float* u        = (float*)alloc((size_t)N * DD * 4);
    unsigned short* Sb   = (unsigned short*)alloc((size_t)N * KPAD * 2);   // 51.2 MB
    unsigned short* ASb  = (unsigned short*)alloc((size_t)N * KPAD * 2);   // 51.2 MB
    unsigned short* S_T  = (unsigned short*)alloc((size_t)KPAD * NPAD * 2);
    unsigned short* AS_T = (unsigned short*)alloc((size_t)KPAD * NPAD * 2);
    unsigned short* Zb   = (unsigned short*)alloc((size_t)N * DD * 2);
    unsigned short* Z_T  = (unsigned short*)alloc((size_t)128 * NPAD * 2);

    // split-K partials overlay buffers that are dead by GEMM time
    float* partialX = (float*)Sb;    // needs 61*512*128*4 = 16.0 MB  (Sb dead after S transpose)
    float* partialA = (float*)ASb;   // needs 32*512*512*4 = 33.6 MB  (ASb dead after AS transpose)

    float* outX = (float*)d_out;            // [500][64]
    float* outA = outX + (size_t)K * C;     // [500][500]

    hipMemsetAsync(cnt_col, 0, (size_t)N * 4, stream);
    hipMemsetAsync(cnt_row, 0, (size_t)N * 4, stream);

    hist_kernel<<<(E + 255) / 256, 256, 0, stream>>>(rowv, colv, cnt_row, cnt_col, E);
    dinv_kernel<<<(N + 255) / 256, 256, 0, stream>>>(cnt_row, dinv, tsum, N);
    tacc_kernel<<<(E + 255) / 256, 256, 0, stream>>>(rowv, colv, dinv, tsum, E);
    scan2_kernel<<<2, 1024, 0, stream>>>(cnt_col, offs_col, cur_col,
                                         cnt_row, offs_row, cur_row, N);
    place_kernel<<<(E + 255) / 256, 256, 0, stream>>>(rowv, colv, cur_col, cur_row, esrc, edst, E);

    // u = shared GCN aggregation (dinv-weighted x gather)
    agg_kernel<<<(N + 3) / 4, 256, 0, stream>>>(x, dinv, offs_col, esrc, u, N);

    // Z_b = bf16 GCN embed output [N][64]
    zgemm_kernel<<<(N + 31) / 32, 256, 0, stream>>>(u, W_embed, b_embed, dinv, tsum, Zb, N);

    // S_b = bf16 softmax assignments [N][512] (cols 500..511 zero)
    lsoftmax_kernel<<<(N + 15) / 16, 256, 0, stream>>>(u, W_assign, b_assign, dinv, tsum, Sb, N);

    // AS_b = bf16 A@S [N][512]
    as_agg_b<<<(N + 3) / 4, 256, 0, stream>>>(Sb, offs_row, edst, ASb, N);

    // transposes -> n-contiguous bf16 operands
    {
        dim3 g(NPAD / 64, KPAD / 64);
        transpose_bf16<<<g, 256, 0, stream>>>(Sb,  S_T,  N, KPAD);
        transpose_bf16<<<g, 256, 0, stream>>>(ASb, AS_T, N, KPAD);
        dim3 gz(NPAD / 64, 2);
        transpose_bf16<<<gz, 256, 0, stream>>>(Zb, Z_T, N, DD);
    }

    // next_X = S^T @ Z : A=S_T[512], B=Z_T[128], NBpad=128
    {
        const int nPer = 832;                       // multiple of 64
        const int ZX = (NPAD + nPer - 1) / nPer;    // 61
        dim3 g(4, 1, ZX);
        mfma_tn_kernel<<<g, 256, 0, stream>>>(S_T, Z_T, partialX, nPer, 128);
        reduce_kernel<<<(K * C + 255) / 256, 256, 0, stream>>>(partialX, outX, K, C, 128, ZX);
    }
    // next_A = S^T @ AS : A=S_T[512], B=AS_T[512], NBpad=512
    {
        const int nPer = 1600;                      // multiple of 64
        const int ZA = (NPAD + nPer - 1) / nPer;    // 32
        dim3 g(4, 4, ZA);
        mfma_tn_kernel<<<g, 256, 0, stream>>>(S_T, AS_T, partialA, nPer, 512);
        reduce_kernel<<<(K * K + 255) / 256, 256, 0, stream>>>(partialA, outA, K, K, 512, ZA);
    }
}

// Round 4
// 732.807 us; speedup vs baseline: 2.8503x; 1.1353x over previous
//
#include <hip/hip_runtime.h>
#include <hip/hip_bf16.h>
#include <math.h>

// Problem constants: N=50000, E=800000, D=64, K=500, C=64
#define DD 64
#define KK 500
#define KPAD 512
#define NPAD 50048   // N padded to multiple of 64

typedef __attribute__((ext_vector_type(8))) short bf16x8;
typedef __attribute__((ext_vector_type(4))) float f32x4;

__device__ inline unsigned short f2bf(float f) {
    unsigned u = __float_as_uint(f);
    u += 0x7fffu + ((u >> 16) & 1u);          // RNE
    return (unsigned short)(u >> 16);
}
__device__ inline unsigned packbf(float lo, float hi) {
    return ((unsigned)f2bf(hi) << 16) | (unsigned)f2bf(lo);
}

// ---------------- degree histogram (cnt_row: for dinv; cnt_col: for in-CSR) ----------------
__global__ void hist_kernel(const int* __restrict__ rowv, const int* __restrict__ colv,
                            int* __restrict__ cnt_row, int* __restrict__ cnt_col, int E) {
    int e = blockIdx.x * blockDim.x + threadIdx.x;
    if (e >= E) return;
    atomicAdd(&cnt_row[rowv[e]], 1);
    atomicAdd(&cnt_col[colv[e]], 1);
}

__global__ void dinv_kernel(const int* __restrict__ cnt_row, float* __restrict__ dinv, int n) {
    int i = blockIdx.x * blockDim.x + threadIdx.x;
    if (i >= n) return;
    dinv[i] = 1.0f / sqrtf((float)(cnt_row[i] + 1));
}

// ---------------- exclusive scan (single array, one block) ----------------
__global__ void scan1_kernel(const int* __restrict__ cnt, int* __restrict__ offs,
                             int* __restrict__ cur, int n) {
    __shared__ int sums[1024];
    int t = threadIdx.x;
    int chunk = (n + 1023) / 1024;
    int begin = min(t * chunk, n);
    int end   = min(begin + chunk, n);
    int s = 0;
    for (int i = begin; i < end; ++i) s += cnt[i];
    sums[t] = s;
    __syncthreads();
    for (int off = 1; off < 1024; off <<= 1) {
        int v = (t >= off) ? sums[t - off] : 0;
        __syncthreads();
        sums[t] += v;
        __syncthreads();
    }
    int run = (t == 0) ? 0 : sums[t - 1];
    for (int i = begin; i < end; ++i) {
        offs[i] = run; cur[i] = run; run += cnt[i];
    }
    if (t == 1023) offs[n] = sums[1023];
}

// ---------------- in-CSR placement only (counting sort by col) ----------------
__global__ void place_kernel(const int* __restrict__ rowv, const int* __restrict__ colv,
                             int* __restrict__ cur_col, int* __restrict__ esrc, int E) {
    int e = blockIdx.x * blockDim.x + threadIdx.x;
    if (e >= E) return;
    int p = atomicAdd(&cur_col[colv[e]], 1);
    esrc[p] = rowv[e];
}

// ---- u[i] = dinv[i]*x[i] + sum_{in} dinv[s]*x[s];  t[i] = dinv[i] + sum_{in} dinv[s] ----
__global__ void agg_kernel(const float* __restrict__ x, const float* __restrict__ dinv,
                           const int* __restrict__ offs, const int* __restrict__ esrc,
                           float* __restrict__ u, float* __restrict__ t, int n) {
    int wv = (blockIdx.x * blockDim.x + threadIdx.x) >> 6;
    int lane = threadIdx.x & 63;
    if (wv >= n) return;
    float di = dinv[wv];
    float acc = di * x[(size_t)wv * 64 + lane];
    float ts = 0.f;
    int p = offs[wv], pend = offs[wv + 1];
    for (; p + 1 < pend; p += 2) {
        int s0 = esrc[p], s1 = esrc[p + 1];
        float w0 = dinv[s0], w1 = dinv[s1];
        acc += w0 * x[(size_t)s0 * 64 + lane] + w1 * x[(size_t)s1 * 64 + lane];
        ts += w0 + w1;
    }
    if (p < pend) { int s = esrc[p]; float w = dinv[s];
                    acc += w * x[(size_t)s * 64 + lane]; ts += w; }
    u[(size_t)wv * 64 + lane] = acc;
    if (lane == 0) t[wv] = di + ts;
}

// ---------------- Z_b = bf16( dinv*(u@W + t*b) ); [N][64] bf16 ----------------
__global__ void zgemm_kernel(const float* __restrict__ u, const float* __restrict__ W,
                             const float* __restrict__ bias, const float* __restrict__ dinv,
                             const float* __restrict__ tsum, unsigned short* __restrict__ Zb, int n) {
    const int C4 = 16;
    int r0 = blockIdx.x * 32;
    __shared__ float us[32 * 68];
    int t = threadIdx.x;
#pragma unroll
    for (int k = 0; k < 2; ++k) {
        int idx = t * 2 + k;
        int rr = idx >> 4, c4 = idx & 15;
        int row = r0 + rr;
        float4 v = make_float4(0.f, 0.f, 0.f, 0.f);
        if (row < n) v = ((const float4*)u)[(size_t)row * 16 + c4];
        *(float4*)&us[rr * 68 + c4 * 4] = v;
    }
    __syncthreads();
    int lr = t >> 3;
    int cg = t & 7;
    int f40 = cg * 2, f41 = f40 + 1;
    float4 acc0 = make_float4(0.f,0.f,0.f,0.f), acc1 = make_float4(0.f,0.f,0.f,0.f);
    const float4* W4 = (const float4*)W;
    for (int d = 0; d < 64; ++d) {
        float uv = us[lr * 68 + d];
        float4 w0 = W4[(size_t)d * C4 + f40];
        float4 w1 = W4[(size_t)d * C4 + f41];
        acc0.x += uv*w0.x; acc0.y += uv*w0.y; acc0.z += uv*w0.z; acc0.w += uv*w0.w;
        acc1.x += uv*w1.x; acc1.y += uv*w1.y; acc1.z += uv*w1.z; acc1.w += uv*w1.w;
    }
    int row = r0 + lr;
    if (row < n) {
        float di = dinv[row], tv = tsum[row];
        const float4* b4 = (const float4*)bias;
        float4 bv0 = b4[f40], bv1 = b4[f41];
        float z0 = di*(acc0.x+tv*bv0.x), z1 = di*(acc0.y+tv*bv0.y);
        float z2 = di*(acc0.z+tv*bv0.z), z3 = di*(acc0.w+tv*bv0.w);
        float z4 = di*(acc1.x+tv*bv1.x), z5 = di*(acc1.y+tv*bv1.y);
        float z6 = di*(acc1.z+tv*bv1.z), z7 = di*(acc1.w+tv*bv1.w);
        uint4 o;
        o.x = packbf(z0, z1); o.y = packbf(z2, z3);
        o.z = packbf(z4, z5); o.w = packbf(z6, z7);
        ((uint4*)Zb)[(size_t)row * 8 + cg] = o;
    }
}

// ---------------- fused L = dinv*(u@W + t*b) + row softmax -> S_b bf16 [N][512] ----------------
__global__ void lsoftmax_kernel(const float* __restrict__ u, const float* __restrict__ W,
                                const float* __restrict__ bias, const float* __restrict__ dinv,
                                const float* __restrict__ tsum, unsigned short* __restrict__ Sb, int n) {
    __shared__ float us[16 * 64];
    __shared__ float Ls[16 * 512];
    __shared__ float sd[16], st[16];
    int r0 = blockIdx.x * 16;
    int t = threadIdx.x;
    {
        int row = r0 + (t >> 4);
        float4 v = make_float4(0.f,0.f,0.f,0.f);
        if (row < n) v = ((const float4*)u)[(size_t)row * 16 + (t & 15)];
        *(float4*)&us[t * 4] = v;
        if (t < 16 && r0 + t < n) { sd[t] = dinv[r0 + t]; st[t] = tsum[r0 + t]; }
    }
    __syncthreads();
    int c0 = t * 2;
    if (c0 < KK) {
        float acc[16][2] = {};
        for (int d = 0; d < 64; ++d) {
            float w0 = W[(size_t)d * KK + c0], w1 = W[(size_t)d * KK + c0 + 1];
#pragma unroll
            for (int r = 0; r < 16; ++r) {
                float uv = us[r * 64 + d];
                acc[r][0] += uv * w0;
                acc[r][1] += uv * w1;
            }
        }
        float bv0 = bias[c0], bv1 = bias[c0 + 1];
#pragma unroll
        for (int r = 0; r < 16; ++r) {
            Ls[r * 512 + c0]     = sd[r] * (acc[r][0] + st[r] * bv0);
            Ls[r * 512 + c0 + 1] = sd[r] * (acc[r][1] + st[r] * bv1);
        }
    }
    __syncthreads();
    int w = t >> 6, lane = t & 63;
#pragma unroll
    for (int rr = 0; rr < 4; ++rr) {
        int r = w * 4 + rr;
        int grow = r0 + r;
        float v[8];
        float m = -1e30f;
#pragma unroll
        for (int j = 0; j < 8; ++j) {
            int idx = lane + j * 64;
            v[j] = (idx < KK) ? Ls[r * 512 + idx] : -1e30f;
            m = fmaxf(m, v[j]);
        }
#pragma unroll
        for (int o = 32; o > 0; o >>= 1) m = fmaxf(m, __shfl_xor(m, o, 64));
        float s = 0.f;
#pragma unroll
        for (int j = 0; j < 8; ++j) {
            int idx = lane + j * 64;
            if (idx < KK) { v[j] = expf(v[j] - m); s += v[j]; }
        }
#pragma unroll
        for (int o = 32; o > 0; o >>= 1) s += __shfl_xor(s, o, 64);
        float rs = 1.0f / s;
        if (grow < n) {
#pragma unroll
            for (int j = 0; j < 8; ++j) {
                int idx = lane + j * 64;
                unsigned short h = (idx < KK) ? f2bf(v[j] * rs) : (unsigned short)0;
                Sb[(size_t)grow * KPAD + idx] = h;
            }
        }
    }
}

// -------- G = A^T S via in-CSR, written TRANSPOSED: G_T[k][n]; 32 nodes/block --------
#define GT_ROWS 32
__global__ void g_agg_t_kernel(const unsigned short* __restrict__ Sb, const int* __restrict__ offs,
                               const int* __restrict__ esrc, unsigned short* __restrict__ G_T, int n) {
    __shared__ unsigned short tl[GT_ROWS * 520];   // 520 stride: 16B-aligned rows, 8-way ph2 conflicts
    int base = blockIdx.x * GT_ROWS;
    int wv = threadIdx.x >> 6, ln = threadIdx.x & 63;
    const uint4* S4 = (const uint4*)Sb;
#pragma unroll
    for (int i = 0; i < GT_ROWS / 4; ++i) {        // 8 nodes per wave
        int r = wv * (GT_ROWS / 4) + i;
        int node = base + r;
        float a0=0,a1=0,a2=0,a3=0,a4=0,a5=0,a6=0,a7=0;
        if (node < n) {
            int p = offs[node], pend = offs[node + 1];
            for (; p + 1 < pend; p += 2) {
                uint4 v = S4[(size_t)esrc[p] * 64 + ln];
                uint4 w = S4[(size_t)esrc[p + 1] * 64 + ln];
                a0 += __uint_as_float(v.x << 16) + __uint_as_float(w.x << 16);
                a1 += __uint_as_float(v.x & 0xffff0000u) + __uint_as_float(w.x & 0xffff0000u);
                a2 += __uint_as_float(v.y << 16) + __uint_as_float(w.y << 16);
                a3 += __uint_as_float(v.y & 0xffff0000u) + __uint_as_float(w.y & 0xffff0000u);
                a4 += __uint_as_float(v.z << 16) + __uint_as_float(w.z << 16);
                a5 += __uint_as_float(v.z & 0xffff0000u) + __uint_as_float(w.z & 0xffff0000u);
                a6 += __uint_as_float(v.w << 16) + __uint_as_float(w.w << 16);
                a7 += __uint_as_float(v.w & 0xffff0000u) + __uint_as_float(w.w & 0xffff0000u);
            }
            if (p < pend) {
                uint4 v = S4[(size_t)esrc[p] * 64 + ln];
                a0 += __uint_as_float(v.x << 16);  a1 += __uint_as_float(v.x & 0xffff0000u);
                a2 += __uint_as_float(v.y << 16);  a3 += __uint_as_float(v.y & 0xffff0000u);
                a4 += __uint_as_float(v.z << 16);  a5 += __uint_as_float(v.z & 0xffff0000u);
                a6 += __uint_as_float(v.w << 16);  a7 += __uint_as_float(v.w & 0xffff0000u);
            }
        }
        uint4 o;
        o.x = packbf(a0, a1); o.y = packbf(a2, a3);
        o.z = packbf(a4, a5); o.w = packbf(a6, a7);
        *(uint4*)&tl[r * 520 + ln * 8] = o;
    }
    __syncthreads();
    // phase 2: transposed 64B full-line stores: G_T[k][base..base+31]
#pragma unroll
    for (int h = 0; h < 2; ++h) {
        int k = threadIdx.x + h * 256;
        unsigned wb[8];
#pragma unroll
        for (int j = 0; j < 8; ++j) {
            unsigned short lo = tl[(2 * j)     * 520 + k];
            unsigned short hi = tl[(2 * j + 1) * 520 + k];
            wb[j] = ((unsigned)hi << 16) | (unsigned)lo;
        }
        unsigned wc[8];
#pragma unroll
        for (int j = 0; j < 8; ++j) {
            unsigned short lo = tl[(16 + 2 * j) * 520 + k];
            unsigned short hi = tl[(17 + 2 * j) * 520 + k];
            wc[j] = ((unsigned)hi << 16) | (unsigned)lo;
        }
        size_t ob = (size_t)k * NPAD + base;
        *(uint4*)&G_T[ob]      = make_uint4(wb[0], wb[1], wb[2], wb[3]);
        *(uint4*)&G_T[ob + 8]  = make_uint4(wb[4], wb[5], wb[6], wb[7]);
        *(uint4*)&G_T[ob + 16] = make_uint4(wc[0], wc[1], wc[2], wc[3]);
        *(uint4*)&G_T[ob + 24] = make_uint4(wc[4], wc[5], wc[6], wc[7]);
    }
}

// ---------------- bf16 transpose: in[N][Cin] -> out[Cout][NPAD], zero-filled ----------------
__global__ void transpose_bf16(const unsigned short* __restrict__ in, unsigned short* __restrict__ out,
                               int N, int Cin) {
    __shared__ unsigned short tl[64 * 72];
    int n0 = blockIdx.x * 64, c0 = blockIdx.y * 64;
    int t = threadIdx.x;
    int r = t >> 2, s = t & 3;
    int n = n0 + r;
#pragma unroll
    for (int h = 0; h < 2; ++h) {
        int c = c0 + s * 16 + h * 8;
        uint4 v = make_uint4(0u, 0u, 0u, 0u);
        if (n < N && c < Cin) v = *(const uint4*)&in[(size_t)n * Cin + c];
        *(uint4*)&tl[r * 72 + s * 16 + h * 8] = v;
    }
    __syncthreads();
    int cc = t >> 2, seg = t & 3;
    unsigned wbuf[8];
#pragma unroll
    for (int k = 0; k < 8; ++k) {
        unsigned short lo = tl[(seg * 16 + 2 * k)     * 72 + cc];
        unsigned short hi = tl[(seg * 16 + 2 * k + 1) * 72 + cc];
        wbuf[k] = ((unsigned)hi << 16) | (unsigned)lo;
    }
    size_t ob = (size_t)(c0 + cc) * NPAD + n0 + seg * 16;
    *(uint4*)&out[ob]     = make_uint4(wbuf[0], wbuf[1], wbuf[2], wbuf[3]);
    *(uint4*)&out[ob + 8] = make_uint4(wbuf[4], wbuf[5], wbuf[6], wbuf[7]);
}

// ---------------- MFMA TN GEMM: partial[z][a][b] = sum_{n in slice} A_T[a][n]*B_T[b][n] ---------
__global__ void __launch_bounds__(256) mfma_tn_kernel(
        const unsigned short* __restrict__ A_T, const unsigned short* __restrict__ B_T,
        float* __restrict__ partial, int nPer, int NBpad) {
    const int a0 = blockIdx.x * 128, b0 = blockIdx.y * 128;
    const int nbeg = blockIdx.z * nPer;
    const int nend = min(nbeg + nPer, NPAD);
    __shared__ unsigned short Al[128 * 72];
    __shared__ unsigned short Bl[128 * 72];
    const int t = threadIdx.x;
    const int ln = t & 63, wv = t >> 6;
    const int wa = (wv & 1) * 64, wb = (wv >> 1) * 64;
    const int lm = ln & 15, lk = (ln >> 4) * 8;
    f32x4 acc[4][4];
#pragma unroll
    for (int i = 0; i < 4; ++i)
#pragma unroll
        for (int j = 0; j < 4; ++j) acc[i][j] = (f32x4){0.f, 0.f, 0.f, 0.f};
    for (int nb = nbeg; nb < nend; nb += 64) {
        __syncthreads();
#pragma unroll
        for (int i = 0; i < 4; ++i) {
            int idx = t + i * 256;
            int r = idx >> 3, c8 = (idx & 7) * 8;
            uint4 va = *(const uint4*)&A_T[(size_t)(a0 + r) * NPAD + nb + c8];
            uint4 vb = *(const uint4*)&B_T[(size_t)(b0 + r) * NPAD + nb + c8];
            *(uint4*)&Al[r * 72 + c8] = va;
            *(uint4*)&Bl[r * 72 + c8] = vb;
        }
        __syncthreads();
#pragma unroll
        for (int ks = 0; ks < 64; ks += 32) {
            bf16x8 af[4], bfr[4];
#pragma unroll
            for (int i = 0; i < 4; ++i)
                af[i] = *(const bf16x8*)&Al[(wa + i * 16 + lm) * 72 + ks + lk];
#pragma unroll
            for (int j = 0; j < 4; ++j)
                bfr[j] = *(const bf16x8*)&Bl[(wb + j * 16 + lm) * 72 + ks + lk];
#pragma unroll
            for (int i = 0; i < 4; ++i)
#pragma unroll
                for (int j = 0; j < 4; ++j)
                    acc[i][j] = __builtin_amdgcn_mfma_f32_16x16x32_bf16(af[i], bfr[j], acc[i][j], 0, 0, 0);
        }
    }
    float* op = partial + (size_t)blockIdx.z * 512 * NBpad;
#pragma unroll
    for (int i = 0; i < 4; ++i) {
#pragma unroll
        for (int j = 0; j < 4; ++j) {
            int bg = b0 + wb + j * 16 + lm;
#pragma unroll
            for (int r = 0; r < 4; ++r) {
                int ag = a0 + wa + i * 16 + (ln >> 4) * 4 + r;
                op[(size_t)ag * NBpad + bg] = acc[i][j][r];
            }
        }
    }
}

// ---------------- split-K reduce: out[a][b] = sum_z partial[z][a][b] ----------------
__global__ void reduce_kernel(const float* __restrict__ partial, float* __restrict__ out,
                              int rows, int cols, int NBpad, int Z) {
    int idx = blockIdx.x * blockDim.x + threadIdx.x;
    if (idx >= rows * cols) return;
    int a = idx / cols, b = idx - a * cols;
    const float* p = partial + (size_t)a * NBpad + b;
    size_t step = (size_t)512 * NBpad;
    float s = 0.f;
    for (int z = 0; z < Z; ++z) s += p[(size_t)z * step];
    out[idx] = s;
}

extern "C" void kernel_launch(void* const* d_in, const int* in_sizes, int n_in,
                              void* d_out, int out_size, void* d_ws, size_t ws_size,
                              hipStream_t stream) {
    const float* x        = (const float*)d_in[0];
    const int*   ei       = (const int*)d_in[1];
    const float* W_embed  = (const float*)d_in[2];
    const float* b_embed  = (const float*)d_in[3];
    const float* W_assign = (const float*)d_in[4];
    const float* b_assign = (const float*)d_in[5];

    const int N = in_sizes[0] / DD;     // 50000
    const int E = in_sizes[1] / 2;      // 800000
    const int C = in_sizes[3];          // 64
    const int K = in_sizes[5];          // 500

    const int* rowv = ei;
    const int* colv = ei + E;

    char* p = (char*)d_ws;
    auto alloc = [&](size_t bytes) -> void* {
        void* r = (void*)p;
        p += (bytes + 255) & ~(size_t)255;
        return r;
    };
    int*   cnt_col  = (int*)alloc((size_t)N * 4);
    int*   cnt_row  = (int*)alloc((size_t)N * 4);
    int*   offs_col = (int*)alloc((size_t)(N + 1) * 4);
    int*   cur_col  = (int*)alloc((size_t)N * 4);
    float* dinv     = (float*)alloc((size_t)N * 4);
    float* tsum     = (float*)alloc((size_t)N * 4);
    int*   esrc     = (int*)alloc((size_t)E * 4);
    float* u        = (float*)alloc((size_t)N * DD * 4);
    unsigned short* Sb   = (unsigned short*)alloc((size_t)N * KPAD * 2);   // 51.2 MB
    unsigned short* S_T  = (unsigned short*)alloc((size_t)KPAD * NPAD * 2);
    unsigned short* G_T  = (unsigned short*)alloc((size_t)KPAD * NPAD * 2);
    unsigned short* Zb   = (unsigned short*)alloc((size_t)N * DD * 2);
    unsigned short* Z_T  = (unsigned short*)alloc((size_t)128 * NPAD * 2);

    // split-K partials overlay Sb (dead after g_agg + S transpose):
    float* partialX = (float*)Sb;                                   // 61*512*128*4  = 16.0 MB
    float* partialA = (float*)((char*)Sb + (size_t)16384 * 1024);   // 32*512*512*4 = 33.6 MB

    float* outX = (float*)d_out;            // [500][64]
    float* outA = outX + (size_t)K * C;     // [500][500]

    hipMemsetAsync(cnt_col, 0, (size_t)N * 4, stream);
    hipMemsetAsync(cnt_row, 0, (size_t)N * 4, stream);

    hist_kernel<<<(E + 255) / 256, 256, 0, stream>>>(rowv, colv, cnt_row, cnt_col, E);
    dinv_kernel<<<(N + 255) / 256, 256, 0, stream>>>(cnt_row, dinv, N);
    scan1_kernel<<<1, 1024, 0, stream>>>(cnt_col, offs_col, cur_col, N);
    place_kernel<<<(E + 255) / 256, 256, 0, stream>>>(rowv, colv, cur_col, esrc, E);

    // u = shared GCN aggregation; t folded in
    agg_kernel<<<(N + 3) / 4, 256, 0, stream>>>(x, dinv, offs_col, esrc, u, tsum, N);

    // Z_b = bf16 GCN embed output [N][64]
    zgemm_kernel<<<(N + 31) / 32, 256, 0, stream>>>(u, W_embed, b_embed, dinv, tsum, Zb, N);

    // S_b = bf16 softmax assignments [N][512]
    lsoftmax_kernel<<<(N + 15) / 16, 256, 0, stream>>>(u, W_assign, b_assign, dinv, tsum, Sb, N);

    // S_T, Z_T transposes
    {
        dim3 g(NPAD / 64, KPAD / 64);
        transpose_bf16<<<g, 256, 0, stream>>>(Sb, S_T, N, KPAD);
        dim3 gz(NPAD / 64, 2);
        transpose_bf16<<<gz, 256, 0, stream>>>(Zb, Z_T, N, DD);
    }

    // G_T = (A^T S)^T via in-CSR, written transposed directly
    g_agg_t_kernel<<<NPAD / GT_ROWS, 256, 0, stream>>>(Sb, offs_col, esrc, G_T, N);

    // next_X = S^T @ Z : mfma(S_T, Z_T)
    {
        const int nPer = 832;
        const int ZX = (NPAD + nPer - 1) / nPer;    // 61
        dim3 g(4, 1, ZX);
        mfma_tn_kernel<<<g, 256, 0, stream>>>(S_T, Z_T, partialX, nPer, 128);
        reduce_kernel<<<(K * C + 255) / 256, 256, 0, stream>>>(partialX, outX, K, C, 128, ZX);
    }
    // next_A = G^T @ S : mfma(G_T, S_T)  [= S^T A S]
    {
        const int nPer = 1600;
        const int ZA = (NPAD + nPer - 1) / nPer;    // 32
        dim3 g(4, 4, ZA);
        mfma_tn_kernel<<<g, 256, 0, stream>>>(G_T, S_T, partialA, nPer, 512);
        reduce_kernel<<<(K * K + 255) / 256, 256, 0, stream>>>(partialA, outA, K, K, 512, ZA);
    }
}

// Round 5
// 725.405 us; speedup vs baseline: 2.8794x; 1.0102x over previous
//
#include <hip/hip_runtime.h>
#include <hip/hip_bf16.h>
#include <math.h>

// Problem constants: N=50000, E=800000, D=64, K=500, C=64
#define DD 64
#define KK 500
#define KPAD 512
#define NPAD 50048   // N padded to multiple of 64

typedef __attribute__((ext_vector_type(8))) short bf16x8;
typedef __attribute__((ext_vector_type(4))) float f32x4;

__device__ inline unsigned short f2bf(float f) {
    unsigned u = __float_as_uint(f);
    u += 0x7fffu + ((u >> 16) & 1u);          // RNE
    return (unsigned short)(u >> 16);
}
__device__ inline unsigned packbf(float lo, float hi) {
    return ((unsigned)f2bf(hi) << 16) | (unsigned)f2bf(lo);
}
__device__ inline void acc8(float* a, uint4 v) {
    a[0] += __uint_as_float(v.x << 16);  a[1] += __uint_as_float(v.x & 0xffff0000u);
    a[2] += __uint_as_float(v.y << 16);  a[3] += __uint_as_float(v.y & 0xffff0000u);
    a[4] += __uint_as_float(v.z << 16);  a[5] += __uint_as_float(v.z & 0xffff0000u);
    a[6] += __uint_as_float(v.w << 16);  a[7] += __uint_as_float(v.w & 0xffff0000u);
}

// ---------------- degree histogram ----------------
__global__ void hist_kernel(const int* __restrict__ rowv, const int* __restrict__ colv,
                            int* __restrict__ cnt_row, int* __restrict__ cnt_col, int E) {
    int e = blockIdx.x * blockDim.x + threadIdx.x;
    if (e >= E) return;
    atomicAdd(&cnt_row[rowv[e]], 1);
    atomicAdd(&cnt_col[colv[e]], 1);
}

__global__ void dinv_kernel(const int* __restrict__ cnt_row, float* __restrict__ dinv, int n) {
    int i = blockIdx.x * blockDim.x + threadIdx.x;
    if (i >= n) return;
    dinv[i] = 1.0f / sqrtf((float)(cnt_row[i] + 1));
}

// ---------------- exclusive scan (single array, one block) ----------------
__global__ void scan1_kernel(const int* __restrict__ cnt, int* __restrict__ offs,
                             int* __restrict__ cur, int n) {
    __shared__ int sums[1024];
    int t = threadIdx.x;
    int chunk = (n + 1023) / 1024;
    int begin = min(t * chunk, n);
    int end   = min(begin + chunk, n);
    int s = 0;
    for (int i = begin; i < end; ++i) s += cnt[i];
    sums[t] = s;
    __syncthreads();
    for (int off = 1; off < 1024; off <<= 1) {
        int v = (t >= off) ? sums[t - off] : 0;
        __syncthreads();
        sums[t] += v;
        __syncthreads();
    }
    int run = (t == 0) ? 0 : sums[t - 1];
    for (int i = begin; i < end; ++i) {
        offs[i] = run; cur[i] = run; run += cnt[i];
    }
    if (t == 1023) offs[n] = sums[1023];
}

// ---------------- in-CSR placement (counting sort by col) ----------------
__global__ void place_kernel(const int* __restrict__ rowv, const int* __restrict__ colv,
                             int* __restrict__ cur_col, int* __restrict__ esrc, int E) {
    int e = blockIdx.x * blockDim.x + threadIdx.x;
    if (e >= E) return;
    int p = atomicAdd(&cur_col[colv[e]], 1);
    esrc[p] = rowv[e];
}

// ---- u[i] = dinv[i]*x[i] + sum_{in} dinv[s]*x[s];  t[i] = dinv[i] + sum_{in} dinv[s] ----
__global__ void agg_kernel(const float* __restrict__ x, const float* __restrict__ dinv,
                           const int* __restrict__ offs, const int* __restrict__ esrc,
                           float* __restrict__ u, float* __restrict__ t, int n) {
    int wv = (blockIdx.x * blockDim.x + threadIdx.x) >> 6;
    int lane = threadIdx.x & 63;
    if (wv >= n) return;
    float di = dinv[wv];
    float acc = di * x[(size_t)wv * 64 + lane];
    float ts = 0.f;
    int p = offs[wv], pend = offs[wv + 1];
    for (; p + 3 < pend; p += 4) {              // 4 independent gathers in flight
        int s0 = esrc[p], s1 = esrc[p + 1], s2 = esrc[p + 2], s3 = esrc[p + 3];
        float w0 = dinv[s0], w1 = dinv[s1], w2 = dinv[s2], w3 = dinv[s3];
        float x0 = x[(size_t)s0 * 64 + lane];
        float x1 = x[(size_t)s1 * 64 + lane];
        float x2 = x[(size_t)s2 * 64 + lane];
        float x3 = x[(size_t)s3 * 64 + lane];
        acc += w0 * x0 + w1 * x1 + w2 * x2 + w3 * x3;
        ts += w0 + w1 + w2 + w3;
    }
    for (; p < pend; ++p) {
        int s = esrc[p]; float w = dinv[s];
        acc += w * x[(size_t)s * 64 + lane]; ts += w;
    }
    u[(size_t)wv * 64 + lane] = acc;
    if (lane == 0) t[wv] = di + ts;
}

// ---------------- Z_b = bf16( dinv*(u@W + t*b) ); [N][64] bf16 ----------------
__global__ void zgemm_kernel(const float* __restrict__ u, const float* __restrict__ W,
                             const float* __restrict__ bias, const float* __restrict__ dinv,
                             const float* __restrict__ tsum, unsigned short* __restrict__ Zb, int n) {
    const int C4 = 16;
    int r0 = blockIdx.x * 32;
    __shared__ float us[32 * 68];
    int t = threadIdx.x;
#pragma unroll
    for (int k = 0; k < 2; ++k) {
        int idx = t * 2 + k;
        int rr = idx >> 4, c4 = idx & 15;
        int row = r0 + rr;
        float4 v = make_float4(0.f, 0.f, 0.f, 0.f);
        if (row < n) v = ((const float4*)u)[(size_t)row * 16 + c4];
        *(float4*)&us[rr * 68 + c4 * 4] = v;
    }
    __syncthreads();
    int lr = t >> 3;
    int cg = t & 7;
    int f40 = cg * 2, f41 = f40 + 1;
    float4 acc0 = make_float4(0.f,0.f,0.f,0.f), acc1 = make_float4(0.f,0.f,0.f,0.f);
    const float4* W4 = (const float4*)W;
    for (int d = 0; d < 64; ++d) {
        float uv = us[lr * 68 + d];
        float4 w0 = W4[(size_t)d * C4 + f40];
        float4 w1 = W4[(size_t)d * C4 + f41];
        acc0.x += uv*w0.x; acc0.y += uv*w0.y; acc0.z += uv*w0.z; acc0.w += uv*w0.w;
        acc1.x += uv*w1.x; acc1.y += uv*w1.y; acc1.z += uv*w1.z; acc1.w += uv*w1.w;
    }
    int row = r0 + lr;
    if (row < n) {
        float di = dinv[row], tv = tsum[row];
        const float4* b4 = (const float4*)bias;
        float4 bv0 = b4[f40], bv1 = b4[f41];
        float z0 = di*(acc0.x+tv*bv0.x), z1 = di*(acc0.y+tv*bv0.y);
        float z2 = di*(acc0.z+tv*bv0.z), z3 = di*(acc0.w+tv*bv0.w);
        float z4 = di*(acc1.x+tv*bv1.x), z5 = di*(acc1.y+tv*bv1.y);
        float z6 = di*(acc1.z+tv*bv1.z), z7 = di*(acc1.w+tv*bv1.w);
        uint4 o;
        o.x = packbf(z0, z1); o.y = packbf(z2, z3);
        o.z = packbf(z4, z5); o.w = packbf(z6, z7);
        ((uint4*)Zb)[(size_t)row * 8 + cg] = o;
    }
}

// ---------------- fused L = dinv*(u@W + t*b) + row softmax -> S_b bf16 [N][512] ----------------
__global__ void lsoftmax_kernel(const float* __restrict__ u, const float* __restrict__ W,
                                const float* __restrict__ bias, const float* __restrict__ dinv,
                                const float* __restrict__ tsum, unsigned short* __restrict__ Sb, int n) {
    __shared__ float us[16 * 64];
    __shared__ float Ls[16 * 512];
    __shared__ float sd[16], st[16];
    int r0 = blockIdx.x * 16;
    int t = threadIdx.x;
    {
        int row = r0 + (t >> 4);
        float4 v = make_float4(0.f,0.f,0.f,0.f);
        if (row < n) v = ((const float4*)u)[(size_t)row * 16 + (t & 15)];
        *(float4*)&us[t * 4] = v;
        if (t < 16 && r0 + t < n) { sd[t] = dinv[r0 + t]; st[t] = tsum[r0 + t]; }
    }
    __syncthreads();
    int c0 = t * 2;
    if (c0 < KK) {
        float acc[16][2] = {};
        for (int d = 0; d < 64; ++d) {
            float w0 = W[(size_t)d * KK + c0], w1 = W[(size_t)d * KK + c0 + 1];
#pragma unroll
            for (int r = 0; r < 16; ++r) {
                float uv = us[r * 64 + d];
                acc[r][0] += uv * w0;
                acc[r][1] += uv * w1;
            }
        }
        float bv0 = bias[c0], bv1 = bias[c0 + 1];
#pragma unroll
        for (int r = 0; r < 16; ++r) {
            Ls[r * 512 + c0]     = sd[r] * (acc[r][0] + st[r] * bv0);
            Ls[r * 512 + c0 + 1] = sd[r] * (acc[r][1] + st[r] * bv1);
        }
    }
    __syncthreads();
    int w = t >> 6, lane = t & 63;
#pragma unroll
    for (int rr = 0; rr < 4; ++rr) {
        int r = w * 4 + rr;
        int grow = r0 + r;
        float v[8];
        float m = -1e30f;
#pragma unroll
        for (int j = 0; j < 8; ++j) {
            int idx = lane + j * 64;
            v[j] = (idx < KK) ? Ls[r * 512 + idx] : -1e30f;
            m = fmaxf(m, v[j]);
        }
#pragma unroll
        for (int o = 32; o > 0; o >>= 1) m = fmaxf(m, __shfl_xor(m, o, 64));
        float s = 0.f;
#pragma unroll
        for (int j = 0; j < 8; ++j) {
            int idx = lane + j * 64;
            if (idx < KK) { v[j] = expf(v[j] - m); s += v[j]; }
        }
#pragma unroll
        for (int o = 32; o > 0; o >>= 1) s += __shfl_xor(s, o, 64);
        float rs = 1.0f / s;
        if (grow < n) {
#pragma unroll
            for (int j = 0; j < 8; ++j) {
                int idx = lane + j * 64;
                unsigned short h = (idx < KK) ? f2bf(v[j] * rs) : (unsigned short)0;
                Sb[(size_t)grow * KPAD + idx] = h;
            }
        }
    }
}

// -------- G = A^T S via in-CSR, written TRANSPOSED: G_T[k][n]; 32 nodes/block --------
#define GT_ROWS 32
__global__ void g_agg_t_kernel(const unsigned short* __restrict__ Sb, const int* __restrict__ offs,
                               const int* __restrict__ esrc, unsigned short* __restrict__ G_T, int n) {
    __shared__ unsigned short tl[GT_ROWS * 520];
    int base = blockIdx.x * GT_ROWS;
    int wv = threadIdx.x >> 6, ln = threadIdx.x & 63;
    const uint4* S4 = (const uint4*)Sb;
#pragma unroll
    for (int i = 0; i < GT_ROWS / 4; ++i) {
        int r = wv * (GT_ROWS / 4) + i;
        int node = base + r;
        float a[8] = {0.f,0.f,0.f,0.f,0.f,0.f,0.f,0.f};
        if (node < n) {
            int p = offs[node], pend = offs[node + 1];
            for (; p + 3 < pend; p += 4) {       // 4 independent 16B gathers in flight
                int s0 = esrc[p], s1 = esrc[p + 1], s2 = esrc[p + 2], s3 = esrc[p + 3];
                uint4 v0 = S4[(size_t)s0 * 64 + ln];
                uint4 v1 = S4[(size_t)s1 * 64 + ln];
                uint4 v2 = S4[(size_t)s2 * 64 + ln];
                uint4 v3 = S4[(size_t)s3 * 64 + ln];
                acc8(a, v0); acc8(a, v1); acc8(a, v2); acc8(a, v3);
            }
            for (; p < pend; ++p) {
                uint4 v = S4[(size_t)esrc[p] * 64 + ln];
                acc8(a, v);
            }
        }
        uint4 o;
        o.x = packbf(a[0], a[1]); o.y = packbf(a[2], a[3]);
        o.z = packbf(a[4], a[5]); o.w = packbf(a[6], a[7]);
        *(uint4*)&tl[r * 520 + ln * 8] = o;
    }
    __syncthreads();
#pragma unroll
    for (int h = 0; h < 2; ++h) {
        int k = threadIdx.x + h * 256;
        unsigned wb[8];
#pragma unroll
        for (int j = 0; j < 8; ++j) {
            unsigned short lo = tl[(2 * j)     * 520 + k];
            unsigned short hi = tl[(2 * j + 1) * 520 + k];
            wb[j] = ((unsigned)hi << 16) | (unsigned)lo;
        }
        unsigned wc[8];
#pragma unroll
        for (int j = 0; j < 8; ++j) {
            unsigned short lo = tl[(16 + 2 * j) * 520 + k];
            unsigned short hi = tl[(17 + 2 * j) * 520 + k];
            wc[j] = ((unsigned)hi << 16) | (unsigned)lo;
        }
        size_t ob = (size_t)k * NPAD + base;
        *(uint4*)&G_T[ob]      = make_uint4(wb[0], wb[1], wb[2], wb[3]);
        *(uint4*)&G_T[ob + 8]  = make_uint4(wb[4], wb[5], wb[6], wb[7]);
        *(uint4*)&G_T[ob + 16] = make_uint4(wc[0], wc[1], wc[2], wc[3]);
        *(uint4*)&G_T[ob + 24] = make_uint4(wc[4], wc[5], wc[6], wc[7]);
    }
}

// ---------------- bf16 transpose: in[N][Cin] -> out[Cout][NPAD], zero-filled ----------------
__global__ void transpose_bf16(const unsigned short* __restrict__ in, unsigned short* __restrict__ out,
                               int N, int Cin) {
    __shared__ unsigned short tl[64 * 72];
    int n0 = blockIdx.x * 64, c0 = blockIdx.y * 64;
    int t = threadIdx.x;
    int r = t >> 2, s = t & 3;
    int n = n0 + r;
#pragma unroll
    for (int h = 0; h < 2; ++h) {
        int c = c0 + s * 16 + h * 8;
        uint4 v = make_uint4(0u, 0u, 0u, 0u);
        if (n < N && c < Cin) v = *(const uint4*)&in[(size_t)n * Cin + c];
        *(uint4*)&tl[r * 72 + s * 16 + h * 8] = v;
    }
    __syncthreads();
    int cc = t >> 2, seg = t & 3;
    unsigned wbuf[8];
#pragma unroll
    for (int k = 0; k < 8; ++k) {
        unsigned short lo = tl[(seg * 16 + 2 * k)     * 72 + cc];
        unsigned short hi = tl[(seg * 16 + 2 * k + 1) * 72 + cc];
        wbuf[k] = ((unsigned)hi << 16) | (unsigned)lo;
    }
    size_t ob = (size_t)(c0 + cc) * NPAD + n0 + seg * 16;
    *(uint4*)&out[ob]     = make_uint4(wbuf[0], wbuf[1], wbuf[2], wbuf[3]);
    *(uint4*)&out[ob + 8] = make_uint4(wbuf[4], wbuf[5], wbuf[6], wbuf[7]);
}

// ---------------- MFMA TN GEMM 128x128 (used for next_X) ----------------
__global__ void __launch_bounds__(256) mfma_tn_kernel(
        const unsigned short* __restrict__ A_T, const unsigned short* __restrict__ B_T,
        float* __restrict__ partial, int nPer, int NBpad) {
    const int a0 = blockIdx.x * 128, b0 = blockIdx.y * 128;
    const int nbeg = blockIdx.z * nPer;
    const int nend = min(nbeg + nPer, NPAD);
    __shared__ unsigned short Al[128 * 72];
    __shared__ unsigned short Bl[128 * 72];
    const int t = threadIdx.x;
    const int ln = t & 63, wv = t >> 6;
    const int wa = (wv & 1) * 64, wb = (wv >> 1) * 64;
    const int lm = ln & 15, lk = (ln >> 4) * 8;
    f32x4 acc[4][4];
#pragma unroll
    for (int i = 0; i < 4; ++i)
#pragma unroll
        for (int j = 0; j < 4; ++j) acc[i][j] = (f32x4){0.f, 0.f, 0.f, 0.f};
    for (int nb = nbeg; nb < nend; nb += 64) {
        __syncthreads();
#pragma unroll
        for (int i = 0; i < 4; ++i) {
            int idx = t + i * 256;
            int r = idx >> 3, c8 = (idx & 7) * 8;
            uint4 va = *(const uint4*)&A_T[(size_t)(a0 + r) * NPAD + nb + c8];
            uint4 vb = *(const uint4*)&B_T[(size_t)(b0 + r) * NPAD + nb + c8];
            *(uint4*)&Al[r * 72 + c8] = va;
            *(uint4*)&Bl[r * 72 + c8] = vb;
        }
        __syncthreads();
#pragma unroll
        for (int ks = 0; ks < 64; ks += 32) {
            bf16x8 af[4], bfr[4];
#pragma unroll
            for (int i = 0; i < 4; ++i)
                af[i] = *(const bf16x8*)&Al[(wa + i * 16 + lm) * 72 + ks + lk];
#pragma unroll
            for (int j = 0; j < 4; ++j)
                bfr[j] = *(const bf16x8*)&Bl[(wb + j * 16 + lm) * 72 + ks + lk];
#pragma unroll
            for (int i = 0; i < 4; ++i)
#pragma unroll
                for (int j = 0; j < 4; ++j)
                    acc[i][j] = __builtin_amdgcn_mfma_f32_16x16x32_bf16(af[i], bfr[j], acc[i][j], 0, 0, 0);
        }
    }
    float* op = partial + (size_t)blockIdx.z * 512 * NBpad;
#pragma unroll
    for (int i = 0; i < 4; ++i) {
#pragma unroll
        for (int j = 0; j < 4; ++j) {
            int bg = b0 + wb + j * 16 + lm;
#pragma unroll
            for (int r = 0; r < 4; ++r) {
                int ag = a0 + wa + i * 16 + (ln >> 4) * 4 + r;
                op[(size_t)ag * NBpad + bg] = acc[i][j][r];
            }
        }
    }
}

// ---------------- MFMA TN GEMM 256a x 128b (used for next_A; halves A re-reads) ----------------
__global__ void __launch_bounds__(256) mfma_tn256_kernel(
        const unsigned short* __restrict__ A_T, const unsigned short* __restrict__ B_T,
        float* __restrict__ partial, int nPer) {
    const int a0 = blockIdx.x * 256, b0 = blockIdx.y * 128;
    const int nbeg = blockIdx.z * nPer;
    const int nend = min(nbeg + nPer, NPAD);
    __shared__ unsigned short Al[256 * 72];   // 36.9 KB
    __shared__ unsigned short Bl[128 * 72];   // 18.4 KB
    const int t = threadIdx.x;
    const int ln = t & 63, wv = t >> 6;
    const int wa = wv * 64;                   // wave tile: 64a x 128b
    const int lm = ln & 15, lk = (ln >> 4) * 8;
    f32x4 acc[4][8];
#pragma unroll
    for (int i = 0; i < 4; ++i)
#pragma unroll
        for (int j = 0; j < 8; ++j) acc[i][j] = (f32x4){0.f, 0.f, 0.f, 0.f};
    for (int nb = nbeg; nb < nend; nb += 64) {
        __syncthreads();
#pragma unroll
        for (int i = 0; i < 8; ++i) {         // Al: 256 rows x 8 uint4
            int idx = t + i * 256;
            int r = idx >> 3, c8 = (idx & 7) * 8;
            uint4 va = *(const uint4*)&A_T[(size_t)(a0 + r) * NPAD + nb + c8];
            *(uint4*)&Al[r * 72 + c8] = va;
        }
#pragma unroll
        for (int i = 0; i < 4; ++i) {         // Bl: 128 rows x 8 uint4
            int idx = t + i * 256;
            int r = idx >> 3, c8 = (idx & 7) * 8;
            uint4 vb = *(const uint4*)&B_T[(size_t)(b0 + r) * NPAD + nb + c8];
            *(uint4*)&Bl[r * 72 + c8] = vb;
        }
        __syncthreads();
#pragma unroll
        for (int ks = 0; ks < 64; ks += 32) {
            bf16x8 af[4], bfr[8];
#pragma unroll
            for (int i = 0; i < 4; ++i)
                af[i] = *(const bf16x8*)&Al[(wa + i * 16 + lm) * 72 + ks + lk];
#pragma unroll
            for (int j = 0; j < 8; ++j)
                bfr[j] = *(const bf16x8*)&Bl[(j * 16 + lm) * 72 + ks + lk];
#pragma unroll
            for (int i = 0; i < 4; ++i)
#pragma unroll
                for (int j = 0; j < 8; ++j)
                    acc[i][j] = __builtin_amdgcn_mfma_f32_16x16x32_bf16(af[i], bfr[j], acc[i][j], 0, 0, 0);
        }
    }
    float* op = partial + (size_t)blockIdx.z * 512 * 512;
#pragma unroll
    for (int i = 0; i < 4; ++i) {
#pragma unroll
        for (int j = 0; j < 8; ++j) {
            int bg = b0 + j * 16 + lm;
#pragma unroll
            for (int r = 0; r < 4; ++r) {
                int ag = a0 + wa + i * 16 + (ln >> 4) * 4 + r;
                op[(size_t)ag * 512 + bg] = acc[i][j][r];
            }
        }
    }
}

// ---------------- split-K reduce: out[a][b] = sum_z partial[z][a][b] ----------------
__global__ void reduce_kernel(const float* __restrict__ partial, float* __restrict__ out,
                              int rows, int cols, int NBpad, int Z) {
    int idx = blockIdx.x * blockDim.x + threadIdx.x;
    if (idx >= rows * cols) return;
    int a = idx / cols, b = idx - a * cols;
    const float* p = partial + (size_t)a * NBpad + b;
    size_t step = (size_t)512 * NBpad;
    float s = 0.f;
    for (int z = 0; z < Z; ++z) s += p[(size_t)z * step];
    out[idx] = s;
}

extern "C" void kernel_launch(void* const* d_in, const int* in_sizes, int n_in,
                              void* d_out, int out_size, void* d_ws, size_t ws_size,
                              hipStream_t stream) {
    const float* x        = (const float*)d_in[0];
    const int*   ei       = (const int*)d_in[1];
    const float* W_embed  = (const float*)d_in[2];
    const float* b_embed  = (const float*)d_in[3];
    const float* W_assign = (const float*)d_in[4];
    const float* b_assign = (const float*)d_in[5];

    const int N = in_sizes[0] / DD;     // 50000
    const int E = in_sizes[1] / 2;      // 800000
    const int C = in_sizes[3];          // 64
    const int K = in_sizes[5];          // 500

    const int* rowv = ei;
    const int* colv = ei + E;

    char* p = (char*)d_ws;
    auto alloc = [&](size_t bytes) -> void* {
        void* r = (void*)p;
        p += (bytes + 255) & ~(size_t)255;
        return r;
    };
    int*   cnt_col  = (int*)alloc((size_t)N * 4);
    int*   cnt_row  = (int*)alloc((size_t)N * 4);
    int*   offs_col = (int*)alloc((size_t)(N + 1) * 4);
    int*   cur_col  = (int*)alloc((size_t)N * 4);
    float* dinv     = (float*)alloc((size_t)N * 4);
    float* tsum     = (float*)alloc((size_t)N * 4);
    int*   esrc     = (int*)alloc((size_t)E * 4);
    float* u        = (float*)alloc((size_t)N * DD * 4);               // 12.8 MB
    unsigned short* Sb   = (unsigned short*)alloc((size_t)N * KPAD * 2);   // 51.2 MB
    unsigned short* S_T  = (unsigned short*)alloc((size_t)KPAD * NPAD * 2);
    unsigned short* G_T  = (unsigned short*)alloc((size_t)KPAD * NPAD * 2);
    unsigned short* Zb   = (unsigned short*)alloc((size_t)N * DD * 2);
    unsigned short* Z_T  = (unsigned short*)alloc((size_t)128 * NPAD * 2);

    // split-K partials overlay buffers dead by GEMM time:
    // nPer=1088, Z=46 (1088*46 == 50048 == NPAD)
    const int nPer = 1088, ZSK = 46;
    float* partialA = (float*)Sb;   // 46*512*512*4 = 48.2 MB <= 51.2 MB (Sb dead after g_agg)
    float* partialX = (float*)u;    // 46*512*128*4 = 12.06 MB <= 12.8 MB (u dead after lsoftmax)

    float* outX = (float*)d_out;            // [500][64]
    float* outA = outX + (size_t)K * C;     // [500][500]

    hipMemsetAsync(cnt_col, 0, (size_t)N * 4, stream);
    hipMemsetAsync(cnt_row, 0, (size_t)N * 4, stream);

    hist_kernel<<<(E + 255) / 256, 256, 0, stream>>>(rowv, colv, cnt_row, cnt_col, E);
    dinv_kernel<<<(N + 255) / 256, 256, 0, stream>>>(cnt_row, dinv, N);
    scan1_kernel<<<1, 1024, 0, stream>>>(cnt_col, offs_col, cur_col, N);
    place_kernel<<<(E + 255) / 256, 256, 0, stream>>>(rowv, colv, cur_col, esrc, E);

    // u = shared GCN aggregation; t folded in
    agg_kernel<<<(N + 3) / 4, 256, 0, stream>>>(x, dinv, offs_col, esrc, u, tsum, N);

    // Z_b = bf16 GCN embed output [N][64]
    zgemm_kernel<<<(N + 31) / 32, 256, 0, stream>>>(u, W_embed, b_embed, dinv, tsum, Zb, N);

    // S_b = bf16 softmax assignments [N][512]
    lsoftmax_kernel<<<(N + 15) / 16, 256, 0, stream>>>(u, W_assign, b_assign, dinv, tsum, Sb, N);

    // S_T, Z_T transposes
    {
        dim3 g(NPAD / 64, KPAD / 64);
        transpose_bf16<<<g, 256, 0, stream>>>(Sb, S_T, N, KPAD);
        dim3 gz(NPAD / 64, 2);
        transpose_bf16<<<gz, 256, 0, stream>>>(Zb, Z_T, N, DD);
    }

    // G_T = (A^T S)^T via in-CSR, written transposed directly
    g_agg_t_kernel<<<NPAD / GT_ROWS, 256, 0, stream>>>(Sb, offs_col, esrc, G_T, N);

    // next_X = S^T @ Z : mfma(S_T, Z_T) -> partial in u
    {
        dim3 g(4, 1, ZSK);
        mfma_tn_kernel<<<g, 256, 0, stream>>>(S_T, Z_T, partialX, nPer, 128);
        reduce_kernel<<<(K * C + 255) / 256, 256, 0, stream>>>(partialX, outX, K, C, 128, ZSK);
    }
    // next_A = G^T @ S : mfma256(G_T, S_T) -> partial in Sb
    {
        dim3 g(2, 4, ZSK);
        mfma_tn256_kernel<<<g, 256, 0, stream>>>(G_T, S_T, partialA, nPer);
        reduce_kernel<<<(K * K + 255) / 256, 256, 0, stream>>>(partialA, outA, K, K, 512, ZSK);
    }
}

// Round 7
// 716.612 us; speedup vs baseline: 2.9147x; 1.0123x over previous
//
#include <hip/hip_runtime.h>
#include <hip/hip_bf16.h>
#include <math.h>

// Problem constants: N=50000, E=800000, D=64, K=500, C=64
#define DD 64
#define KK 500
#define KPAD 512
#define NPAD 50048   // N padded to multiple of 64
#define NS 50176     // N padded to multiple of 1024 (scan tiles)

typedef __attribute__((ext_vector_type(8))) short bf16x8;
typedef __attribute__((ext_vector_type(4))) float f32x4;

#if defined(__has_builtin)
#if __has_builtin(__builtin_amdgcn_cvt_pk_f32_fp8) && __has_builtin(__builtin_amdgcn_cvt_pk_fp8_f32)
#define HAS_FP8_CVT 1
#endif
#endif

__device__ inline unsigned short f2bf(float f) {
    unsigned u = __float_as_uint(f);
    u += 0x7fffu + ((u >> 16) & 1u);          // RNE
    return (unsigned short)(u >> 16);
}
__device__ inline unsigned packbf(float lo, float hi) {
    return ((unsigned)f2bf(hi) << 16) | (unsigned)f2bf(lo);
}
__device__ inline float bf2f(unsigned short h) {
    return __uint_as_float((unsigned)h << 16);
}

#ifndef HAS_FP8_CVT
// fallback e4m3fn conversions (slow path; only if builtins missing)
__device__ inline float fp8_to_f32_slow(unsigned b) {
    unsigned s = (b >> 7) & 1, e = (b >> 3) & 15, m = b & 7;
    float v = (e == 0) ? ldexpf((float)m, -9) : ldexpf((float)(8 + m), (int)e - 10);
    return s ? -v : v;
}
__device__ inline unsigned f32_to_fp8_slow(float f) {
    unsigned sgn = (__float_as_uint(f) >> 24) & 0x80u;
    float af = fabsf(f);
    if (!(af > 0.f)) return sgn;
    if (af >= 448.f) return sgn | 0x7E;
    int e; frexpf(af, &e);
    int E = e - 1 + 7;
    if (E < 1) { unsigned q = (unsigned)rintf(ldexpf(af, 9)); return sgn | q; }
    unsigned q = (unsigned)rintf(ldexpf(af, 10 - E));
    if (q >= 16) { q = 8; E++; }
    if (E > 15 || (E == 15 && q - 8 >= 7)) return sgn | 0x7E;
    return sgn | ((unsigned)E << 3) | (q - 8);
}
#endif

__device__ inline void accf8(float* a, uint2 v) {
#ifdef HAS_FP8_CVT
    auto f0 = __builtin_amdgcn_cvt_pk_f32_fp8(v.x, false);
    a[0] += f0[0]; a[1] += f0[1];
    auto f1 = __builtin_amdgcn_cvt_pk_f32_fp8(v.x, true);
    a[2] += f1[0]; a[3] += f1[1];
    auto f2 = __builtin_amdgcn_cvt_pk_f32_fp8(v.y, false);
    a[4] += f2[0]; a[5] += f2[1];
    auto f3 = __builtin_amdgcn_cvt_pk_f32_fp8(v.y, true);
    a[6] += f3[0]; a[7] += f3[1];
#else
    a[0] += fp8_to_f32_slow(v.x & 0xff);         a[1] += fp8_to_f32_slow((v.x >> 8) & 0xff);
    a[2] += fp8_to_f32_slow((v.x >> 16) & 0xff); a[3] += fp8_to_f32_slow((v.x >> 24) & 0xff);
    a[4] += fp8_to_f32_slow(v.y & 0xff);         a[5] += fp8_to_f32_slow((v.y >> 8) & 0xff);
    a[6] += fp8_to_f32_slow((v.y >> 16) & 0xff); a[7] += fp8_to_f32_slow((v.y >> 24) & 0xff);
#endif
}

// ---------------- degree histogram ----------------
__global__ void hist_kernel(const int* __restrict__ rowv, const int* __restrict__ colv,
                            int* __restrict__ cnt_row, int* __restrict__ cnt_col, int E) {
    int e = blockIdx.x * blockDim.x + threadIdx.x;
    if (e >= E) return;
    atomicAdd(&cnt_row[rowv[e]], 1);
    atomicAdd(&cnt_col[colv[e]], 1);
}

// ---------------- hierarchical coalesced scan: A (tile sums) ----------------
__global__ void scanA_kernel(const int* __restrict__ cnt, int* __restrict__ bsum) {
    __shared__ int red[256];
    int t = threadIdx.x;
    int4 c = *(const int4*)&cnt[blockIdx.x * 1024 + t * 4];
    red[t] = c.x + c.y + c.z + c.w;
    __syncthreads();
    for (int o = 128; o > 0; o >>= 1) {
        if (t < o) red[t] += red[t + o];
        __syncthreads();
    }
    if (t == 0) bsum[blockIdx.x] = red[0];
}

// ---------------- scan B: exclusive scan of <=64 tile sums (one wave) ----------------
__global__ void scanB_kernel(const int* __restrict__ bsum, int* __restrict__ bbase,
                             int* __restrict__ offs_n, int nb) {
    int t = threadIdx.x;
    int v = (t < nb) ? bsum[t] : 0;
    int own = v;
    for (int o = 1; o < 64; o <<= 1) {
        int w = __shfl_up(v, o, 64);
        if (t >= o) v += w;
    }
    if (t < nb) bbase[t] = v - own;
    if (t == 63) *offs_n = v;
}

// ---------------- scan C: final offs/cur + dinv fold ----------------
__global__ void scanC_kernel(const int* __restrict__ cnt, const int* __restrict__ cnt_row,
                             const int* __restrict__ bbase, int* __restrict__ offs,
                             int* __restrict__ cur, float* __restrict__ dinv, int n) {
    __shared__ int sums[256];
    int t = threadIdx.x;
    int i0 = blockIdx.x * 1024 + t * 4;
    int4 c = *(const int4*)&cnt[i0];
    int s = c.x + c.y + c.z + c.w;
    sums[t] = s;
    __syncthreads();
    for (int o = 1; o < 256; o <<= 1) {
        int w = (t >= o) ? sums[t - o] : 0;
        __syncthreads();
        sums[t] += w;
        __syncthreads();
    }
    int base = bbase[blockIdx.x] + sums[t] - s;
    int p0 = base, p1 = base + c.x, p2 = p1 + c.y, p3 = p2 + c.z;
    if (i0 + 0 < n) { offs[i0 + 0] = p0; cur[i0 + 0] = p0; }
    if (i0 + 1 < n) { offs[i0 + 1] = p1; cur[i0 + 1] = p1; }
    if (i0 + 2 < n) { offs[i0 + 2] = p2; cur[i0 + 2] = p2; }
    if (i0 + 3 < n) { offs[i0 + 3] = p3; cur[i0 + 3] = p3; }
    int4 cr = *(const int4*)&cnt_row[i0];
    if (i0 + 0 < n) dinv[i0 + 0] = 1.0f / sqrtf((float)(cr.x + 1));
    if (i0 + 1 < n) dinv[i0 + 1] = 1.0f / sqrtf((float)(cr.y + 1));
    if (i0 + 2 < n) dinv[i0 + 2] = 1.0f / sqrtf((float)(cr.z + 1));
    if (i0 + 3 < n) dinv[i0 + 3] = 1.0f / sqrtf((float)(cr.w + 1));
}

// ---------------- in-CSR placement (counting sort by col) ----------------
__global__ void place_kernel(const int* __restrict__ rowv, const int* __restrict__ colv,
                             int* __restrict__ cur_col, int* __restrict__ esrc, int E) {
    int e = blockIdx.x * blockDim.x + threadIdx.x;
    if (e >= E) return;
    int p = atomicAdd(&cur_col[colv[e]], 1);
    esrc[p] = rowv[e];
}

// ---------------- xb = bf16(dinv[i] * x[i]) ----------------
__global__ void xscale_kernel(const float* __restrict__ x, const float* __restrict__ dinv,
                              unsigned short* __restrict__ xb, int n16) {
    int idx = blockIdx.x * blockDim.x + threadIdx.x;
    if (idx >= n16) return;
    int i = idx >> 4;
    float di = dinv[i];
    float4 v = ((const float4*)x)[idx];
    uint2 o;
    o.x = packbf(di * v.x, di * v.y);
    o.y = packbf(di * v.z, di * v.w);
    ((uint2*)xb)[idx] = o;
}

// ---- u[i] = xb[i] + sum_{in} xb[s] (fp32 acc);  t[i] = dinv[i] + sum_{in} dinv[s] ----
__global__ void agg_kernel(const unsigned short* __restrict__ xb, const float* __restrict__ dinv,
                           const int* __restrict__ offs, const int* __restrict__ esrc,
                           float* __restrict__ u, float* __restrict__ t, int n) {
    int wv = (blockIdx.x * blockDim.x + threadIdx.x) >> 6;
    int ln = threadIdx.x & 63;
    if (wv >= n) return;
    float di = dinv[wv];
    float acc = bf2f(xb[(size_t)wv * 64 + ln]);
    float ts = 0.f;
    int p = offs[wv], pend = offs[wv + 1];
    for (; p + 3 < pend; p += 4) {
        int s0 = esrc[p], s1 = esrc[p + 1], s2 = esrc[p + 2], s3 = esrc[p + 3];
        unsigned short h0 = xb[(size_t)s0 * 64 + ln];
        unsigned short h1 = xb[(size_t)s1 * 64 + ln];
        unsigned short h2 = xb[(size_t)s2 * 64 + ln];
        unsigned short h3 = xb[(size_t)s3 * 64 + ln];
        float w0 = dinv[s0], w1 = dinv[s1], w2 = dinv[s2], w3 = dinv[s3];
        acc += bf2f(h0) + bf2f(h1) + bf2f(h2) + bf2f(h3);
        ts += w0 + w1 + w2 + w3;
    }
    for (; p < pend; ++p) {
        int s = esrc[p];
        acc += bf2f(xb[(size_t)s * 64 + ln]);
        ts += dinv[s];
    }
    u[(size_t)wv * 64 + ln] = acc;
    if (ln == 0) t[wv] = di + ts;
}

// ---- fused: L = dinv*(u@Wa + t*ba); S = softmax(L) -> Sb(bf16) + Sf8(e4m3 x256);
//      Z = dinv*(u@We + t*be) -> Zb(bf16).  16 rows/block. ----
__global__ void fused_ls_kernel(const float* __restrict__ u,
                                const float* __restrict__ Wa, const float* __restrict__ ba,
                                const float* __restrict__ We, const float* __restrict__ be,
                                const float* __restrict__ dinv, const float* __restrict__ tsum,
                                unsigned short* __restrict__ Sb, unsigned char* __restrict__ Sf8,
                                unsigned short* __restrict__ Zb, int n) {
    __shared__ float us[16 * 64];
    __shared__ float Ls[16 * 512];
    __shared__ float sd[16], st[16];
    int r0 = blockIdx.x * 16;
    int t = threadIdx.x;
    {
        int row = r0 + (t >> 4);
        float4 v = make_float4(0.f, 0.f, 0.f, 0.f);
        if (row < n) v = ((const float4*)u)[(size_t)row * 16 + (t & 15)];
        *(float4*)&us[t * 4] = v;
        if (t < 16 && r0 + t < n) { sd[t] = dinv[r0 + t]; st[t] = tsum[r0 + t]; }
    }
    __syncthreads();
    // assign-logit GEMM -> Ls
    int c0 = t * 2;
    if (c0 < KK) {
        float acc[16][2] = {};
        for (int d = 0; d < 64; ++d) {
            float w0 = Wa[(size_t)d * KK + c0], w1 = Wa[(size_t)d * KK + c0 + 1];
#pragma unroll
            for (int r = 0; r < 16; ++r) {
                float uv = us[r * 64 + d];
                acc[r][0] += uv * w0;
                acc[r][1] += uv * w1;
            }
        }
        float bv0 = ba[c0], bv1 = ba[c0 + 1];
#pragma unroll
        for (int r = 0; r < 16; ++r) {
            Ls[r * 512 + c0]     = sd[r] * (acc[r][0] + st[r] * bv0);
            Ls[r * 512 + c0 + 1] = sd[r] * (acc[r][1] + st[r] * bv1);
        }
    }
    __syncthreads();
    // softmax: lane handles 8 CONTIGUOUS cols [ln*8, ln*8+8)
    int w = t >> 6, ln = t & 63;
    int cb = ln * 8;
#pragma unroll
    for (int rr = 0; rr < 4; ++rr) {
        int r = w * 4 + rr;
        int grow = r0 + r;
        float v[8];
        *(float4*)&v[0] = *(const float4*)&Ls[r * 512 + cb];
        *(float4*)&v[4] = *(const float4*)&Ls[r * 512 + cb + 4];
#pragma unroll
        for (int j = 0; j < 8; ++j) if (cb + j >= KK) v[j] = -1e30f;
        float m = -1e30f;
#pragma unroll
        for (int j = 0; j < 8; ++j) m = fmaxf(m, v[j]);
#pragma unroll
        for (int o = 32; o > 0; o >>= 1) m = fmaxf(m, __shfl_xor(m, o, 64));
        float s = 0.f;
#pragma unroll
        for (int j = 0; j < 8; ++j) { v[j] = expf(v[j] - m); s += v[j]; }
#pragma unroll
        for (int o = 32; o > 0; o >>= 1) s += __shfl_xor(s, o, 64);
        float rs = 1.0f / s;
        if (grow < n) {
            uint4 ob;
            ob.x = packbf(v[0] * rs, v[1] * rs);
            ob.y = packbf(v[2] * rs, v[3] * rs);
            ob.z = packbf(v[4] * rs, v[5] * rs);
            ob.w = packbf(v[6] * rs, v[7] * rs);
            *(uint4*)&Sb[(size_t)grow * KPAD + cb] = ob;
            float sc = 256.f * rs;
#ifdef HAS_FP8_CVT
            int pk0 = __builtin_amdgcn_cvt_pk_fp8_f32(v[0] * sc, v[1] * sc, 0, false);
            pk0     = __builtin_amdgcn_cvt_pk_fp8_f32(v[2] * sc, v[3] * sc, pk0, true);
            int pk1 = __builtin_amdgcn_cvt_pk_fp8_f32(v[4] * sc, v[5] * sc, 0, false);
            pk1     = __builtin_amdgcn_cvt_pk_fp8_f32(v[6] * sc, v[7] * sc, pk1, true);
#else
            int pk0 = (int)(f32_to_fp8_slow(v[0]*sc) | (f32_to_fp8_slow(v[1]*sc) << 8) |
                            (f32_to_fp8_slow(v[2]*sc) << 16) | (f32_to_fp8_slow(v[3]*sc) << 24));
            int pk1 = (int)(f32_to_fp8_slow(v[4]*sc) | (f32_to_fp8_slow(v[5]*sc) << 8) |
                            (f32_to_fp8_slow(v[6]*sc) << 16) | (f32_to_fp8_slow(v[7]*sc) << 24));
#endif
            uint2 of; of.x = (unsigned)pk0; of.y = (unsigned)pk1;
            *(uint2*)&Sf8[(size_t)grow * KPAD + cb] = of;
        }
    }
    // embed GEMM -> Zb (reuses us)
    {
        int c = t & 63;
        int rb = (t >> 6) * 4;
        float za[4] = {0.f, 0.f, 0.f, 0.f};
        for (int d = 0; d < 64; ++d) {
            float wv = We[(size_t)d * 64 + c];
            za[0] += us[(rb + 0) * 64 + d] * wv;
            za[1] += us[(rb + 1) * 64 + d] * wv;
            za[2] += us[(rb + 2) * 64 + d] * wv;
            za[3] += us[(rb + 3) * 64 + d] * wv;
        }
        float bv = be[c];
#pragma unroll
        for (int k = 0; k < 4; ++k) {
            int row = r0 + rb + k;
            if (row < n) {
                float z = sd[rb + k] * (za[k] + st[rb + k] * bv);
                Zb[(size_t)row * 64 + c] = f2bf(z);
            }
        }
    }
}

// -------- G = A^T S via in-CSR over fp8 S, written TRANSPOSED bf16: G_T[k][n] --------
#define GT_ROWS 32
__global__ void g_agg_t_kernel(const unsigned char* __restrict__ Sf8, const int* __restrict__ offs,
                               const int* __restrict__ esrc, unsigned short* __restrict__ G_T, int n) {
    __shared__ unsigned short tl[GT_ROWS * 520];
    int base = blockIdx.x * GT_ROWS;
    int wv = threadIdx.x >> 6, ln = threadIdx.x & 63;
    const uint2* S2 = (const uint2*)Sf8;   // 64 uint2 per row (512 fp8)
#pragma unroll
    for (int i = 0; i < GT_ROWS / 4; ++i) {
        int r = wv * (GT_ROWS / 4) + i;
        int node = base + r;
        float a[8] = {0.f,0.f,0.f,0.f,0.f,0.f,0.f,0.f};
        if (node < n) {
            int p = offs[node], pend = offs[node + 1];
            for (; p + 3 < pend; p += 4) {       // 4 independent 8B gathers in flight
                int s0 = esrc[p], s1 = esrc[p + 1], s2 = esrc[p + 2], s3 = esrc[p + 3];
                uint2 v0 = S2[(size_t)s0 * 64 + ln];
                uint2 v1 = S2[(size_t)s1 * 64 + ln];
                uint2 v2 = S2[(size_t)s2 * 64 + ln];
                uint2 v3 = S2[(size_t)s3 * 64 + ln];
                accf8(a, v0); accf8(a, v1); accf8(a, v2); accf8(a, v3);
            }
            for (; p < pend; ++p) {
                uint2 v = S2[(size_t)esrc[p] * 64 + ln];
                accf8(a, v);
            }
        }
        const float inv = 1.0f / 256.f;          // undo Sf8 scale
        uint4 o;
        o.x = packbf(a[0] * inv, a[1] * inv); o.y = packbf(a[2] * inv, a[3] * inv);
        o.z = packbf(a[4] * inv, a[5] * inv); o.w = packbf(a[6] * inv, a[7] * inv);
        *(uint4*)&tl[r * 520 + ln * 8] = o;
    }
    __syncthreads();
#pragma unroll
    for (int h = 0; h < 2; ++h) {
        int k = threadIdx.x + h * 256;
        unsigned wb[8];
#pragma unroll
        for (int j = 0; j < 8; ++j) {
            unsigned short lo = tl[(2 * j)     * 520 + k];
            unsigned short hi = tl[(2 * j + 1) * 520 + k];
            wb[j] = ((unsigned)hi << 16) | (unsigned)lo;
        }
        unsigned wc[8];
#pragma unroll
        for (int j = 0; j < 8; ++j) {
            unsigned short lo = tl[(16 + 2 * j) * 520 + k];
            unsigned short hi = tl[(17 + 2 * j) * 520 + k];
            wc[j] = ((unsigned)hi << 16) | (unsigned)lo;
        }
        size_t ob = (size_t)k * NPAD + base;
        *(uint4*)&G_T[ob]      = make_uint4(wb[0], wb[1], wb[2], wb[3]);
        *(uint4*)&G_T[ob + 8]  = make_uint4(wb[4], wb[5], wb[6], wb[7]);
        *(uint4*)&G_T[ob + 16] = make_uint4(wc[0], wc[1], wc[2], wc[3]);
        *(uint4*)&G_T[ob + 24] = make_uint4(wc[4], wc[5], wc[6], wc[7]);
    }
}

// ---------------- bf16 transpose: in[N][Cin] -> out[Cout][NPAD], zero-filled ----------------
__global__ void transpose_bf16(const unsigned short* __restrict__ in, unsigned short* __restrict__ out,
                               int N, int Cin) {
    __shared__ unsigned short tl[64 * 72];
    int n0 = blockIdx.x * 64, c0 = blockIdx.y * 64;
    int t = threadIdx.x;
    int r = t >> 2, s = t & 3;
    int n = n0 + r;
#pragma unroll
    for (int h = 0; h < 2; ++h) {
        int c = c0 + s * 16 + h * 8;
        uint4 v = make_uint4(0u, 0u, 0u, 0u);
        if (n < N && c < Cin) v = *(const uint4*)&in[(size_t)n * Cin + c];
        *(uint4*)&tl[r * 72 + s * 16 + h * 8] = v;
    }
    __syncthreads();
    int cc = t >> 2, seg = t & 3;
    unsigned wbuf[8];
#pragma unroll
    for (int k = 0; k < 8; ++k) {
        unsigned short lo = tl[(seg * 16 + 2 * k)     * 72 + cc];
        unsigned short hi = tl[(seg * 16 + 2 * k + 1) * 72 + cc];
        wbuf[k] = ((unsigned)hi << 16) | (unsigned)lo;
    }
    size_t ob = (size_t)(c0 + cc) * NPAD + n0 + seg * 16;
    *(uint4*)&out[ob]     = make_uint4(wbuf[0], wbuf[1], wbuf[2], wbuf[3]);
    *(uint4*)&out[ob + 8] = make_uint4(wbuf[4], wbuf[5], wbuf[6], wbuf[7]);
}

// ---------------- MFMA TN GEMM 128x128 (next_X) ----------------
__global__ void __launch_bounds__(256) mfma_tn_kernel(
        const unsigned short* __restrict__ A_T, const unsigned short* __restrict__ B_T,
        float* __restrict__ partial, int nPer, int NBpad) {
    const int a0 = blockIdx.x * 128, b0 = blockIdx.y * 128;
    const int nbeg = blockIdx.z * nPer;
    const int nend = min(nbeg + nPer, NPAD);
    __shared__ unsigned short Al[128 * 72];
    __shared__ unsigned short Bl[128 * 72];
    const int t = threadIdx.x;
    const int ln = t & 63, wv = t >> 6;
    const int wa = (wv & 1) * 64, wb = (wv >> 1) * 64;
    const int lm = ln & 15, lk = (ln >> 4) * 8;
    f32x4 acc[4][4];
#pragma unroll
    for (int i = 0; i < 4; ++i)
#pragma unroll
        for (int j = 0; j < 4; ++j) acc[i][j] = (f32x4){0.f, 0.f, 0.f, 0.f};
    for (int nb = nbeg; nb < nend; nb += 64) {
        __syncthreads();
#pragma unroll
        for (int i = 0; i < 4; ++i) {
            int idx = t + i * 256;
            int r = idx >> 3, c8 = (idx & 7) * 8;
            uint4 va = *(const uint4*)&A_T[(size_t)(a0 + r) * NPAD + nb + c8];
            uint4 vb = *(const uint4*)&B_T[(size_t)(b0 + r) * NPAD + nb + c8];
            *(uint4*)&Al[r * 72 + c8] = va;
            *(uint4*)&Bl[r * 72 + c8] = vb;
        }
        __syncthreads();
#pragma unroll
        for (int ks = 0; ks < 64; ks += 32) {
            bf16x8 af[4], bfr[4];
#pragma unroll
            for (int i = 0; i < 4; ++i)
                af[i] = *(const bf16x8*)&Al[(wa + i * 16 + lm) * 72 + ks + lk];
#pragma unroll
            for (int j = 0; j < 4; ++j)
                bfr[j] = *(const bf16x8*)&Bl[(wb + j * 16 + lm) * 72 + ks + lk];
#pragma unroll
            for (int i = 0; i < 4; ++i)
#pragma unroll
                for (int j = 0; j < 4; ++j)
                    acc[i][j] = __builtin_amdgcn_mfma_f32_16x16x32_bf16(af[i], bfr[j], acc[i][j], 0, 0, 0);
        }
    }
    float* op = partial + (size_t)blockIdx.z * 512 * NBpad;
#pragma unroll
    for (int i = 0; i < 4; ++i) {
#pragma unroll
        for (int j = 0; j < 4; ++j) {
            int bg = b0 + wb + j * 16 + lm;
#pragma unroll
            for (int r = 0; r < 4; ++r) {
                int ag = a0 + wa + i * 16 + (ln >> 4) * 4 + r;
                op[(size_t)ag * NBpad + bg] = acc[i][j][r];
            }
        }
    }
}

// ---------------- MFMA TN GEMM 256a x 128b (next_A) ----------------
__global__ void __launch_bounds__(256) mfma_tn256_kernel(
        const unsigned short* __restrict__ A_T, const unsigned short* __restrict__ B_T,
        float* __restrict__ partial, int nPer) {
    const int a0 = blockIdx.x * 256, b0 = blockIdx.y * 128;
    const int nbeg = blockIdx.z * nPer;
    const int nend = min(nbeg + nPer, NPAD);
    __shared__ unsigned short Al[256 * 72];
    __shared__ unsigned short Bl[128 * 72];
    const int t = threadIdx.x;
    const int ln = t & 63, wv = t >> 6;
    const int wa = wv * 64;
    const int lm = ln & 15, lk = (ln >> 4) * 8;
    f32x4 acc[4][8];
#pragma unroll
    for (int i = 0; i < 4; ++i)
#pragma unroll
        for (int j = 0; j < 8; ++j) acc[i][j] = (f32x4){0.f, 0.f, 0.f, 0.f};
    for (int nb = nbeg; nb < nend; nb += 64) {
        __syncthreads();
#pragma unroll
        for (int i = 0; i < 8; ++i) {
            int idx = t + i * 256;
            int r = idx >> 3, c8 = (idx & 7) * 8;
            uint4 va = *(const uint4*)&A_T[(size_t)(a0 + r) * NPAD + nb + c8];
            *(uint4*)&Al[r * 72 + c8] = va;
        }
#pragma unroll
        for (int i = 0; i < 4; ++i) {
            int idx = t + i * 256;
            int r = idx >> 3, c8 = (idx & 7) * 8;
            uint4 vb = *(const uint4*)&B_T[(size_t)(b0 + r) * NPAD + nb + c8];
            *(uint4*)&Bl[r * 72 + c8] = vb;
        }
        __syncthreads();
#pragma unroll
        for (int ks = 0; ks < 64; ks += 32) {
            bf16x8 af[4], bfr[8];
#pragma unroll
            for (int i = 0; i < 4; ++i)
                af[i] = *(const bf16x8*)&Al[(wa + i * 16 + lm) * 72 + ks + lk];
#pragma unroll
            for (int j = 0; j < 8; ++j)
                bfr[j] = *(const bf16x8*)&Bl[(j * 16 + lm) * 72 + ks + lk];
#pragma unroll
            for (int i = 0; i < 4; ++i)
#pragma unroll
                for (int j = 0; j < 8; ++j)
                    acc[i][j] = __builtin_amdgcn_mfma_f32_16x16x32_bf16(af[i], bfr[j], acc[i][j], 0, 0, 0);
        }
    }
    float* op = partial + (size_t)blockIdx.z * 512 * 512;
#pragma unroll
    for (int i = 0; i < 4; ++i) {
#pragma unroll
        for (int j = 0; j < 8; ++j) {
            int bg = b0 + j * 16 + lm;
#pragma unroll
            for (int r = 0; r < 4; ++r) {
                int ag = a0 + wa + i * 16 + (ln >> 4) * 4 + r;
                op[(size_t)ag * 512 + bg] = acc[i][j][r];
            }
        }
    }
}

// ---------------- split-K reduce ----------------
__global__ void reduce_kernel(const float* __restrict__ partial, float* __restrict__ out,
                              int rows, int cols, int NBpad, int Z) {
    int idx = blockIdx.x * blockDim.x + threadIdx.x;
    if (idx >= rows * cols) return;
    int a = idx / cols, b = idx - a * cols;
    const float* p = partial + (size_t)a * NBpad + b;
    size_t step = (size_t)512 * NBpad;
    float s = 0.f;
    for (int z = 0; z < Z; ++z) s += p[(size_t)z * step];
    out[idx] = s;
}

extern "C" void kernel_launch(void* const* d_in, const int* in_sizes, int n_in,
                              void* d_out, int out_size, void* d_ws, size_t ws_size,
                              hipStream_t stream) {
    const float* x        = (const float*)d_in[0];
    const int*   ei       = (const int*)d_in[1];
    const float* W_embed  = (const float*)d_in[2];
    const float* b_embed  = (const float*)d_in[3];
    const float* W_assign = (const float*)d_in[4];
    const float* b_assign = (const float*)d_in[5];

    const int N = in_sizes[0] / DD;     // 50000
    const int E = in_sizes[1] / 2;      // 800000
    const int C = in_sizes[3];          // 64
    const int K = in_sizes[5];          // 500

    const int* rowv = ei;
    const int* colv = ei + E;

    char* p = (char*)d_ws;
    auto alloc = [&](size_t bytes) -> void* {
        void* r = (void*)p;
        p += (bytes + 255) & ~(size_t)255;
        return r;
    };
    int*   cnt      = (int*)alloc((size_t)2 * NS * 4);   // [cnt_col | cnt_row], zero-padded tiles
    int*   cnt_col  = cnt;
    int*   cnt_row  = cnt + NS;
    int*   offs_col = (int*)alloc((size_t)(N + 1) * 4);
    int*   cur_col  = (int*)alloc((size_t)N * 4);
    int*   bsum     = (int*)alloc(64 * 4);
    int*   bbase    = (int*)alloc(64 * 4);
    float* dinv     = (float*)alloc((size_t)N * 4);
    float* tsum     = (float*)alloc((size_t)N * 4);
    int*   esrc     = (int*)alloc((size_t)E * 4);
    float* u        = (float*)alloc((size_t)N * DD * 4);                   // 12.8 MB
    unsigned short* xb   = (unsigned short*)alloc((size_t)N * DD * 2);     // 6.4 MB
    unsigned short* Sb   = (unsigned short*)alloc((size_t)N * KPAD * 2);   // 51.2 MB
    unsigned char*  Sf8  = (unsigned char*)alloc((size_t)N * KPAD);        // 25.6 MB
    unsigned short* S_T  = (unsigned short*)alloc((size_t)KPAD * NPAD * 2);
    unsigned short* G_T  = (unsigned short*)alloc((size_t)KPAD * NPAD * 2);
    unsigned short* Zb   = (unsigned short*)alloc((size_t)N * DD * 2);
    unsigned short* Z_T  = (unsigned short*)alloc((size_t)128 * NPAD * 2);

    // split-K partials overlay buffers dead by GEMM time (nPer=1088, Z=46: 1088*46==NPAD)
    const int nPer = 1088, ZSK = 46;
    float* partialA = (float*)Sb;   // 46*512*512*4 = 48.2 MB <= 51.2 MB
    float* partialX = (float*)u;    // 46*512*128*4 = 12.06 MB <= 12.8 MB

    float* outX = (float*)d_out;            // [500][64]
    float* outA = outX + (size_t)K * C;     // [500][500]

    const int NB = (N + 1023) / 1024;       // 49 scan tiles

    (void)hipMemsetAsync(cnt, 0, (size_t)2 * NS * 4, stream);

    hist_kernel<<<(E + 255) / 256, 256, 0, stream>>>(rowv, colv, cnt_row, cnt_col, E);
    scanA_kernel<<<NB, 256, 0, stream>>>(cnt_col, bsum);
    scanB_kernel<<<1, 64, 0, stream>>>(bsum, bbase, &offs_col[N], NB);
    scanC_kernel<<<NB, 256, 0, stream>>>(cnt_col, cnt_row, bbase, offs_col, cur_col, dinv, N);
    place_kernel<<<(E + 255) / 256, 256, 0, stream>>>(rowv, colv, cur_col, esrc, E);

    // xb = bf16(dinv * x)
    xscale_kernel<<<(N * 16 + 255) / 256, 256, 0, stream>>>(x, dinv, xb, N * 16);

    // u = shared GCN aggregation (bf16 gather, fp32 acc); tsum folded
    agg_kernel<<<(N + 3) / 4, 256, 0, stream>>>(xb, dinv, offs_col, esrc, u, tsum, N);

    // fused: S (bf16+fp8) and Z (bf16)
    fused_ls_kernel<<<(N + 15) / 16, 256, 0, stream>>>(u, W_assign, b_assign, W_embed, b_embed,
                                                       dinv, tsum, Sb, Sf8, Zb, N);

    // S_T, Z_T transposes
    {
        dim3 g(NPAD / 64, KPAD / 64);
        transpose_bf16<<<g, 256, 0, stream>>>(Sb, S_T, N, KPAD);
        dim3 gz(NPAD / 64, 2);
        transpose_bf16<<<gz, 256, 0, stream>>>(Zb, Z_T, N, DD);
    }

    // G_T = (A^T S)^T via fp8 gather, written transposed bf16
    g_agg_t_kernel<<<NPAD / GT_ROWS, 256, 0, stream>>>(Sf8, offs_col, esrc, G_T, N);

    // next_X = S^T @ Z : mfma(S_T, Z_T) -> partial in u
    {
        dim3 g(4, 1, ZSK);
        mfma_tn_kernel<<<g, 256, 0, stream>>>(S_T, Z_T, partialX, nPer, 128);
        reduce_kernel<<<(K * C + 255) / 256, 256, 0, stream>>>(partialX, outX, K, C, 128, ZSK);
    }
    // next_A = G^T @ S : mfma256(G_T, S_T) -> partial in Sb
    {
        dim3 g(2, 4, ZSK);
        mfma_tn256_kernel<<<g, 256, 0, stream>>>(G_T, S_T, partialA, nPer);
        reduce_kernel<<<(K * K + 255) / 256, 256, 0, stream>>>(partialA, outA, K, K, 512, ZSK);
    }
}

// Round 8
// 593.410 us; speedup vs baseline: 3.5199x; 1.2076x over previous
//
#include <hip/hip_runtime.h>
#include <hip/hip_bf16.h>
#include <math.h>

// Problem constants: N=50000, E=800000, D=64, K=500, C=64
#define DD 64
#define KK 500
#define KPAD 512
#define NPAD 50048   // N padded to multiple of 64
#define NS 50176     // N padded to multiple of 1024 (scan tiles)

typedef __attribute__((ext_vector_type(8))) short bf16x8;
typedef __attribute__((ext_vector_type(4))) float f32x4;

#if defined(__has_builtin)
#if __has_builtin(__builtin_amdgcn_cvt_pk_f32_fp8) && __has_builtin(__builtin_amdgcn_cvt_pk_fp8_f32)
#define HAS_FP8_CVT 1
#endif
#endif

__device__ inline unsigned short f2bf(float f) {
    unsigned u = __float_as_uint(f);
    u += 0x7fffu + ((u >> 16) & 1u);          // RNE
    return (unsigned short)(u >> 16);
}
__device__ inline unsigned packbf(float lo, float hi) {
    return ((unsigned)f2bf(hi) << 16) | (unsigned)f2bf(lo);
}
__device__ inline float bf2f(unsigned short h) {
    return __uint_as_float((unsigned)h << 16);
}

#ifndef HAS_FP8_CVT
__device__ inline float fp8_to_f32_slow(unsigned b) {
    unsigned s = (b >> 7) & 1, e = (b >> 3) & 15, m = b & 7;
    float v = (e == 0) ? ldexpf((float)m, -9) : ldexpf((float)(8 + m), (int)e - 10);
    return s ? -v : v;
}
__device__ inline unsigned f32_to_fp8_slow(float f) {
    unsigned sgn = (__float_as_uint(f) >> 24) & 0x80u;
    float af = fabsf(f);
    if (!(af > 0.f)) return sgn;
    if (af >= 448.f) return sgn | 0x7E;
    int e; frexpf(af, &e);
    int E = e - 1 + 7;
    if (E < 1) { unsigned q = (unsigned)rintf(ldexpf(af, 9)); return sgn | q; }
    unsigned q = (unsigned)rintf(ldexpf(af, 10 - E));
    if (q >= 16) { q = 8; E++; }
    if (E > 15 || (E == 15 && q - 8 >= 7)) return sgn | 0x7E;
    return sgn | ((unsigned)E << 3) | (q - 8);
}
#endif

__device__ inline void accf8(float* a, uint2 v) {
#ifdef HAS_FP8_CVT
    auto f0 = __builtin_amdgcn_cvt_pk_f32_fp8(v.x, false);
    a[0] += f0[0]; a[1] += f0[1];
    auto f1 = __builtin_amdgcn_cvt_pk_f32_fp8(v.x, true);
    a[2] += f1[0]; a[3] += f1[1];
    auto f2 = __builtin_amdgcn_cvt_pk_f32_fp8(v.y, false);
    a[4] += f2[0]; a[5] += f2[1];
    auto f3 = __builtin_amdgcn_cvt_pk_f32_fp8(v.y, true);
    a[6] += f3[0]; a[7] += f3[1];
#else
    a[0] += fp8_to_f32_slow(v.x & 0xff);         a[1] += fp8_to_f32_slow((v.x >> 8) & 0xff);
    a[2] += fp8_to_f32_slow((v.x >> 16) & 0xff); a[3] += fp8_to_f32_slow((v.x >> 24) & 0xff);
    a[4] += fp8_to_f32_slow(v.y & 0xff);         a[5] += fp8_to_f32_slow((v.y >> 8) & 0xff);
    a[6] += fp8_to_f32_slow((v.y >> 16) & 0xff); a[7] += fp8_to_f32_slow((v.y >> 24) & 0xff);
#endif
}

// ---------------- degree histogram ----------------
__global__ void hist_kernel(const int* __restrict__ rowv, const int* __restrict__ colv,
                            int* __restrict__ cnt_row, int* __restrict__ cnt_col, int E) {
    int e = blockIdx.x * blockDim.x + threadIdx.x;
    if (e >= E) return;
    atomicAdd(&cnt_row[rowv[e]], 1);
    atomicAdd(&cnt_col[colv[e]], 1);
}

// ---------------- hierarchical coalesced scan ----------------
__global__ void scanA_kernel(const int* __restrict__ cnt, int* __restrict__ bsum) {
    __shared__ int red[256];
    int t = threadIdx.x;
    int4 c = *(const int4*)&cnt[blockIdx.x * 1024 + t * 4];
    red[t] = c.x + c.y + c.z + c.w;
    __syncthreads();
    for (int o = 128; o > 0; o >>= 1) {
        if (t < o) red[t] += red[t + o];
        __syncthreads();
    }
    if (t == 0) bsum[blockIdx.x] = red[0];
}

__global__ void scanB_kernel(const int* __restrict__ bsum, int* __restrict__ bbase,
                             int* __restrict__ offs_n, int nb) {
    int t = threadIdx.x;
    int v = (t < nb) ? bsum[t] : 0;
    int own = v;
    for (int o = 1; o < 64; o <<= 1) {
        int w = __shfl_up(v, o, 64);
        if (t >= o) v += w;
    }
    if (t < nb) bbase[t] = v - own;
    if (t == 63) *offs_n = v;
}

__global__ void scanC_kernel(const int* __restrict__ cnt, const int* __restrict__ cnt_row,
                             const int* __restrict__ bbase, int* __restrict__ offs,
                             int* __restrict__ cur, float* __restrict__ dinv, int n) {
    __shared__ int sums[256];
    int t = threadIdx.x;
    int i0 = blockIdx.x * 1024 + t * 4;
    int4 c = *(const int4*)&cnt[i0];
    int s = c.x + c.y + c.z + c.w;
    sums[t] = s;
    __syncthreads();
    for (int o = 1; o < 256; o <<= 1) {
        int w = (t >= o) ? sums[t - o] : 0;
        __syncthreads();
        sums[t] += w;
        __syncthreads();
    }
    int base = bbase[blockIdx.x] + sums[t] - s;
    int p0 = base, p1 = base + c.x, p2 = p1 + c.y, p3 = p2 + c.z;
    if (i0 + 0 < n) { offs[i0 + 0] = p0; cur[i0 + 0] = p0; }
    if (i0 + 1 < n) { offs[i0 + 1] = p1; cur[i0 + 1] = p1; }
    if (i0 + 2 < n) { offs[i0 + 2] = p2; cur[i0 + 2] = p2; }
    if (i0 + 3 < n) { offs[i0 + 3] = p3; cur[i0 + 3] = p3; }
    int4 cr = *(const int4*)&cnt_row[i0];
    if (i0 + 0 < n) dinv[i0 + 0] = 1.0f / sqrtf((float)(cr.x + 1));
    if (i0 + 1 < n) dinv[i0 + 1] = 1.0f / sqrtf((float)(cr.y + 1));
    if (i0 + 2 < n) dinv[i0 + 2] = 1.0f / sqrtf((float)(cr.z + 1));
    if (i0 + 3 < n) dinv[i0 + 3] = 1.0f / sqrtf((float)(cr.w + 1));
}

// ---------------- in-CSR placement ----------------
__global__ void place_kernel(const int* __restrict__ rowv, const int* __restrict__ colv,
                             int* __restrict__ cur_col, int* __restrict__ esrc, int E) {
    int e = blockIdx.x * blockDim.x + threadIdx.x;
    if (e >= E) return;
    int p = atomicAdd(&cur_col[colv[e]], 1);
    esrc[p] = rowv[e];
}

// ---------------- xb = bf16(dinv[i] * x[i]) ----------------
__global__ void xscale_kernel(const float* __restrict__ x, const float* __restrict__ dinv,
                              unsigned short* __restrict__ xb, int n16) {
    int idx = blockIdx.x * blockDim.x + threadIdx.x;
    if (idx >= n16) return;
    int i = idx >> 4;
    float di = dinv[i];
    float4 v = ((const float4*)x)[idx];
    uint2 o;
    o.x = packbf(di * v.x, di * v.y);
    o.y = packbf(di * v.z, di * v.w);
    ((uint2*)xb)[idx] = o;
}

// ---- u[i] = xb[i] + sum_{in} xb[s];  t[i] = dinv[i] + sum_{in} dinv[s] ----
__global__ void agg_kernel(const unsigned short* __restrict__ xb, const float* __restrict__ dinv,
                           const int* __restrict__ offs, const int* __restrict__ esrc,
                           float* __restrict__ u, float* __restrict__ t, int n) {
    int wv = (blockIdx.x * blockDim.x + threadIdx.x) >> 6;
    int ln = threadIdx.x & 63;
    if (wv >= n) return;
    float di = dinv[wv];
    float acc = bf2f(xb[(size_t)wv * 64 + ln]);
    float ts = 0.f;
    int p = offs[wv], pend = offs[wv + 1];
    for (; p + 3 < pend; p += 4) {
        int s0 = esrc[p], s1 = esrc[p + 1], s2 = esrc[p + 2], s3 = esrc[p + 3];
        unsigned short h0 = xb[(size_t)s0 * 64 + ln];
        unsigned short h1 = xb[(size_t)s1 * 64 + ln];
        unsigned short h2 = xb[(size_t)s2 * 64 + ln];
        unsigned short h3 = xb[(size_t)s3 * 64 + ln];
        float w0 = dinv[s0], w1 = dinv[s1], w2 = dinv[s2], w3 = dinv[s3];
        acc += bf2f(h0) + bf2f(h1) + bf2f(h2) + bf2f(h3);
        ts += w0 + w1 + w2 + w3;
    }
    for (; p < pend; ++p) {
        int s = esrc[p];
        acc += bf2f(xb[(size_t)s * 64 + ln]);
        ts += dinv[s];
    }
    u[(size_t)wv * 64 + ln] = acc;
    if (ln == 0) t[wv] = di + ts;
}

// ---------------- Z_b = bf16( dinv*(u@W + t*b) ); [N][64] bf16 (proven round-5) ----------------
__global__ void zgemm_kernel(const float* __restrict__ u, const float* __restrict__ W,
                             const float* __restrict__ bias, const float* __restrict__ dinv,
                             const float* __restrict__ tsum, unsigned short* __restrict__ Zb, int n) {
    const int C4 = 16;
    int r0 = blockIdx.x * 32;
    __shared__ float us[32 * 68];
    int t = threadIdx.x;
#pragma unroll
    for (int k = 0; k < 2; ++k) {
        int idx = t * 2 + k;
        int rr = idx >> 4, c4 = idx & 15;
        int row = r0 + rr;
        float4 v = make_float4(0.f, 0.f, 0.f, 0.f);
        if (row < n) v = ((const float4*)u)[(size_t)row * 16 + c4];
        *(float4*)&us[rr * 68 + c4 * 4] = v;
    }
    __syncthreads();
    int lr = t >> 3;
    int cg = t & 7;
    int f40 = cg * 2, f41 = f40 + 1;
    float4 acc0 = make_float4(0.f,0.f,0.f,0.f), acc1 = make_float4(0.f,0.f,0.f,0.f);
    const float4* W4 = (const float4*)W;
    for (int d = 0; d < 64; ++d) {
        float uv = us[lr * 68 + d];
        float4 w0 = W4[(size_t)d * C4 + f40];
        float4 w1 = W4[(size_t)d * C4 + f41];
        acc0.x += uv*w0.x; acc0.y += uv*w0.y; acc0.z += uv*w0.z; acc0.w += uv*w0.w;
        acc1.x += uv*w1.x; acc1.y += uv*w1.y; acc1.z += uv*w1.z; acc1.w += uv*w1.w;
    }
    int row = r0 + lr;
    if (row < n) {
        float di = dinv[row], tv = tsum[row];
        const float4* b4 = (const float4*)bias;
        float4 bv0 = b4[f40], bv1 = b4[f41];
        float z0 = di*(acc0.x+tv*bv0.x), z1 = di*(acc0.y+tv*bv0.y);
        float z2 = di*(acc0.z+tv*bv0.z), z3 = di*(acc0.w+tv*bv0.w);
        float z4 = di*(acc1.x+tv*bv1.x), z5 = di*(acc1.y+tv*bv1.y);
        float z6 = di*(acc1.z+tv*bv1.z), z7 = di*(acc1.w+tv*bv1.w);
        uint4 o;
        o.x = packbf(z0, z1); o.y = packbf(z2, z3);
        o.z = packbf(z4, z5); o.w = packbf(z6, z7);
        ((uint4*)Zb)[(size_t)row * 8 + cg] = o;
    }
}

// ---- fused assign: logits (bf16 in LDS) -> softmax -> S_T (transposed bf16, direct)
//      + Sf8 (row-major e4m3 x256). 32 rows/block. ----
#define FS_ROWS 32
__global__ void fused_s_kernel(const float* __restrict__ u,
                               const float* __restrict__ Wa, const float* __restrict__ ba,
                               const float* __restrict__ dinv, const float* __restrict__ tsum,
                               unsigned short* __restrict__ S_T, unsigned char* __restrict__ Sf8,
                               int n) {
    __shared__ float us[FS_ROWS * 64];            // 8 KB
    __shared__ unsigned short tl[FS_ROWS * 520];  // 33.3 KB: logits then S (bf16)
    __shared__ float sd[FS_ROWS], st[FS_ROWS];
    int r0 = blockIdx.x * FS_ROWS;
    int t = threadIdx.x;
#pragma unroll
    for (int h = 0; h < 2; ++h) {                 // load u tile: 32 rows x 16 float4
        int idx = t + h * 256;
        int row = r0 + (idx >> 4);
        float4 v = make_float4(0.f, 0.f, 0.f, 0.f);
        if (row < n) v = ((const float4*)u)[(size_t)row * 16 + (idx & 15)];
        *(float4*)&us[idx * 4] = v;
    }
    if (t < FS_ROWS) {
        int row = r0 + t;
        sd[t] = (row < n) ? dinv[row] : 0.f;
        st[t] = (row < n) ? tsum[row] : 0.f;
    }
    __syncthreads();
    // logit GEMM: thread t -> cols (2t, 2t+1), all 32 rows; bf16-pack into tl
    int c0 = t * 2;
    if (c0 < KK) {
        float acc[FS_ROWS][2] = {};
        for (int d = 0; d < 64; ++d) {
            float w0 = Wa[(size_t)d * KK + c0], w1 = Wa[(size_t)d * KK + c0 + 1];
#pragma unroll
            for (int r = 0; r < FS_ROWS; ++r) {
                float uv = us[r * 64 + d];
                acc[r][0] += uv * w0;
                acc[r][1] += uv * w1;
            }
        }
        float bv0 = ba[c0], bv1 = ba[c0 + 1];
#pragma unroll
        for (int r = 0; r < FS_ROWS; ++r) {
            float l0 = sd[r] * (acc[r][0] + st[r] * bv0);
            float l1 = sd[r] * (acc[r][1] + st[r] * bv1);
            *(unsigned*)&tl[r * 520 + c0] = packbf(l0, l1);
        }
    }
    __syncthreads();
    // softmax per row: wave wv handles rows wv*8..wv*8+7; lane ln owns cols [ln*8, ln*8+8)
    int wv = t >> 6, ln = t & 63;
    int cb = ln * 8;
#pragma unroll
    for (int rr = 0; rr < 8; ++rr) {
        int r = wv * 8 + rr;
        int grow = r0 + r;
        uint4 lv = *(const uint4*)&tl[r * 520 + cb];
        float v[8];
        v[0] = __uint_as_float(lv.x << 16); v[1] = __uint_as_float(lv.x & 0xffff0000u);
        v[2] = __uint_as_float(lv.y << 16); v[3] = __uint_as_float(lv.y & 0xffff0000u);
        v[4] = __uint_as_float(lv.z << 16); v[5] = __uint_as_float(lv.z & 0xffff0000u);
        v[6] = __uint_as_float(lv.w << 16); v[7] = __uint_as_float(lv.w & 0xffff0000u);
#pragma unroll
        for (int j = 0; j < 8; ++j) if (cb + j >= KK) v[j] = -1e30f;
        float m = -1e30f;
#pragma unroll
        for (int j = 0; j < 8; ++j) m = fmaxf(m, v[j]);
#pragma unroll
        for (int o = 32; o > 0; o >>= 1) m = fmaxf(m, __shfl_xor(m, o, 64));
        float s = 0.f;
#pragma unroll
        for (int j = 0; j < 8; ++j) { v[j] = expf(v[j] - m); s += v[j]; }
#pragma unroll
        for (int o = 32; o > 0; o >>= 1) s += __shfl_xor(s, o, 64);
        float rs = (grow < n) ? (1.0f / s) : 0.f;     // rows >= n -> S = 0
        // S bf16 back into tl (in place)
        uint4 ob;
        ob.x = packbf(v[0] * rs, v[1] * rs);
        ob.y = packbf(v[2] * rs, v[3] * rs);
        ob.z = packbf(v[4] * rs, v[5] * rs);
        ob.w = packbf(v[6] * rs, v[7] * rs);
        *(uint4*)&tl[r * 520 + cb] = ob;
        // Sf8 row-major (only for real rows)
        if (grow < n) {
            float sc = 256.f * rs;
#ifdef HAS_FP8_CVT
            int pk0 = __builtin_amdgcn_cvt_pk_fp8_f32(v[0] * sc, v[1] * sc, 0, false);
            pk0     = __builtin_amdgcn_cvt_pk_fp8_f32(v[2] * sc, v[3] * sc, pk0, true);
            int pk1 = __builtin_amdgcn_cvt_pk_fp8_f32(v[4] * sc, v[5] * sc, 0, false);
            pk1     = __builtin_amdgcn_cvt_pk_fp8_f32(v[6] * sc, v[7] * sc, pk1, true);
#else
            int pk0 = (int)(f32_to_fp8_slow(v[0]*sc) | (f32_to_fp8_slow(v[1]*sc) << 8) |
                            (f32_to_fp8_slow(v[2]*sc) << 16) | (f32_to_fp8_slow(v[3]*sc) << 24));
            int pk1 = (int)(f32_to_fp8_slow(v[4]*sc) | (f32_to_fp8_slow(v[5]*sc) << 8) |
                            (f32_to_fp8_slow(v[6]*sc) << 16) | (f32_to_fp8_slow(v[7]*sc) << 24));
#endif
            uint2 of; of.x = (unsigned)pk0; of.y = (unsigned)pk1;
            *(uint2*)&Sf8[(size_t)grow * KPAD + cb] = of;
        }
    }
    __syncthreads();
    // phase 2: transposed full-line stores S_T[k][r0..r0+31]
#pragma unroll
    for (int h = 0; h < 2; ++h) {
        int k = t + h * 256;
        unsigned wb[8];
#pragma unroll
        for (int j = 0; j < 8; ++j) {
            unsigned short lo = tl[(2 * j)     * 520 + k];
            unsigned short hi = tl[(2 * j + 1) * 520 + k];
            wb[j] = ((unsigned)hi << 16) | (unsigned)lo;
        }
        unsigned wc[8];
#pragma unroll
        for (int j = 0; j < 8; ++j) {
            unsigned short lo = tl[(16 + 2 * j) * 520 + k];
            unsigned short hi = tl[(17 + 2 * j) * 520 + k];
            wc[j] = ((unsigned)hi << 16) | (unsigned)lo;
        }
        size_t ob = (size_t)k * NPAD + r0;
        *(uint4*)&S_T[ob]      = make_uint4(wb[0], wb[1], wb[2], wb[3]);
        *(uint4*)&S_T[ob + 8]  = make_uint4(wb[4], wb[5], wb[6], wb[7]);
        *(uint4*)&S_T[ob + 16] = make_uint4(wc[0], wc[1], wc[2], wc[3]);
        *(uint4*)&S_T[ob + 24] = make_uint4(wc[4], wc[5], wc[6], wc[7]);
    }
}

// -------- G = A^T S via in-CSR over fp8 S, written TRANSPOSED bf16: G_T[k][n] --------
#define GT_ROWS 32
__global__ void g_agg_t_kernel(const unsigned char* __restrict__ Sf8, const int* __restrict__ offs,
                               const int* __restrict__ esrc, unsigned short* __restrict__ G_T, int n) {
    __shared__ unsigned short tl[GT_ROWS * 520];
    int base = blockIdx.x * GT_ROWS;
    int wv = threadIdx.x >> 6, ln = threadIdx.x & 63;
    const uint2* S2 = (const uint2*)Sf8;
#pragma unroll
    for (int i = 0; i < GT_ROWS / 4; ++i) {
        int r = wv * (GT_ROWS / 4) + i;
        int node = base + r;
        float a[8] = {0.f,0.f,0.f,0.f,0.f,0.f,0.f,0.f};
        if (node < n) {
            int p = offs[node], pend = offs[node + 1];
            for (; p + 3 < pend; p += 4) {
                int s0 = esrc[p], s1 = esrc[p + 1], s2 = esrc[p + 2], s3 = esrc[p + 3];
                uint2 v0 = S2[(size_t)s0 * 64 + ln];
                uint2 v1 = S2[(size_t)s1 * 64 + ln];
                uint2 v2 = S2[(size_t)s2 * 64 + ln];
                uint2 v3 = S2[(size_t)s3 * 64 + ln];
                accf8(a, v0); accf8(a, v1); accf8(a, v2); accf8(a, v3);
            }
            for (; p < pend; ++p) {
                uint2 v = S2[(size_t)esrc[p] * 64 + ln];
                accf8(a, v);
            }
        }
        const float inv = 1.0f / 256.f;
        uint4 o;
        o.x = packbf(a[0] * inv, a[1] * inv); o.y = packbf(a[2] * inv, a[3] * inv);
        o.z = packbf(a[4] * inv, a[5] * inv); o.w = packbf(a[6] * inv, a[7] * inv);
        *(uint4*)&tl[r * 520 + ln * 8] = o;
    }
    __syncthreads();
#pragma unroll
    for (int h = 0; h < 2; ++h) {
        int k = threadIdx.x + h * 256;
        unsigned wb[8];
#pragma unroll
        for (int j = 0; j < 8; ++j) {
            unsigned short lo = tl[(2 * j)     * 520 + k];
            unsigned short hi = tl[(2 * j + 1) * 520 + k];
            wb[j] = ((unsigned)hi << 16) | (unsigned)lo;
        }
        unsigned wc[8];
#pragma unroll
        for (int j = 0; j < 8; ++j) {
            unsigned short lo = tl[(16 + 2 * j) * 520 + k];
            unsigned short hi = tl[(17 + 2 * j) * 520 + k];
            wc[j] = ((unsigned)hi << 16) | (unsigned)lo;
        }
        size_t ob = (size_t)k * NPAD + base;
        *(uint4*)&G_T[ob]      = make_uint4(wb[0], wb[1], wb[2], wb[3]);
        *(uint4*)&G_T[ob + 8]  = make_uint4(wb[4], wb[5], wb[6], wb[7]);
        *(uint4*)&G_T[ob + 16] = make_uint4(wc[0], wc[1], wc[2], wc[3]);
        *(uint4*)&G_T[ob + 24] = make_uint4(wc[4], wc[5], wc[6], wc[7]);
    }
}

// ---------------- bf16 transpose (for Z only): in[N][Cin] -> out[Cout][NPAD] ----------------
__global__ void transpose_bf16(const unsigned short* __restrict__ in, unsigned short* __restrict__ out,
                               int N, int Cin) {
    __shared__ unsigned short tl[64 * 72];
    int n0 = blockIdx.x * 64, c0 = blockIdx.y * 64;
    int t = threadIdx.x;
    int r = t >> 2, s = t & 3;
    int n = n0 + r;
#pragma unroll
    for (int h = 0; h < 2; ++h) {
        int c = c0 + s * 16 + h * 8;
        uint4 v = make_uint4(0u, 0u, 0u, 0u);
        if (n < N && c < Cin) v = *(const uint4*)&in[(size_t)n * Cin + c];
        *(uint4*)&tl[r * 72 + s * 16 + h * 8] = v;
    }
    __syncthreads();
    int cc = t >> 2, seg = t & 3;
    unsigned wbuf[8];
#pragma unroll
    for (int k = 0; k < 8; ++k) {
        unsigned short lo = tl[(seg * 16 + 2 * k)     * 72 + cc];
        unsigned short hi = tl[(seg * 16 + 2 * k + 1) * 72 + cc];
        wbuf[k] = ((unsigned)hi << 16) | (unsigned)lo;
    }
    size_t ob = (size_t)(c0 + cc) * NPAD + n0 + seg * 16;
    *(uint4*)&out[ob]     = make_uint4(wbuf[0], wbuf[1], wbuf[2], wbuf[3]);
    *(uint4*)&out[ob + 8] = make_uint4(wbuf[4], wbuf[5], wbuf[6], wbuf[7]);
}

// ---------------- MFMA TN GEMM 128x128 (next_X) ----------------
__global__ void __launch_bounds__(256) mfma_tn_kernel(
        const unsigned short* __restrict__ A_T, const unsigned short* __restrict__ B_T,
        float* __restrict__ partial, int nPer, int NBpad) {
    const int a0 = blockIdx.x * 128, b0 = blockIdx.y * 128;
    const int nbeg = blockIdx.z * nPer;
    const int nend = min(nbeg + nPer, NPAD);
    __shared__ unsigned short Al[128 * 72];
    __shared__ unsigned short Bl[128 * 72];
    const int t = threadIdx.x;
    const int ln = t & 63, wv = t >> 6;
    const int wa = (wv & 1) * 64, wb = (wv >> 1) * 64;
    const int lm = ln & 15, lk = (ln >> 4) * 8;
    f32x4 acc[4][4];
#pragma unroll
    for (int i = 0; i < 4; ++i)
#pragma unroll
        for (int j = 0; j < 4; ++j) acc[i][j] = (f32x4){0.f, 0.f, 0.f, 0.f};
    for (int nb = nbeg; nb < nend; nb += 64) {
        __syncthreads();
#pragma unroll
        for (int i = 0; i < 4; ++i) {
            int idx = t + i * 256;
            int r = idx >> 3, c8 = (idx & 7) * 8;
            uint4 va = *(const uint4*)&A_T[(size_t)(a0 + r) * NPAD + nb + c8];
            uint4 vb = *(const uint4*)&B_T[(size_t)(b0 + r) * NPAD + nb + c8];
            *(uint4*)&Al[r * 72 + c8] = va;
            *(uint4*)&Bl[r * 72 + c8] = vb;
        }
        __syncthreads();
#pragma unroll
        for (int ks = 0; ks < 64; ks += 32) {
            bf16x8 af[4], bfr[4];
#pragma unroll
            for (int i = 0; i < 4; ++i)
                af[i] = *(const bf16x8*)&Al[(wa + i * 16 + lm) * 72 + ks + lk];
#pragma unroll
            for (int j = 0; j < 4; ++j)
                bfr[j] = *(const bf16x8*)&Bl[(wb + j * 16 + lm) * 72 + ks + lk];
#pragma unroll
            for (int i = 0; i < 4; ++i)
#pragma unroll
                for (int j = 0; j < 4; ++j)
                    acc[i][j] = __builtin_amdgcn_mfma_f32_16x16x32_bf16(af[i], bfr[j], acc[i][j], 0, 0, 0);
        }
    }
    float* op = partial + (size_t)blockIdx.z * 512 * NBpad;
#pragma unroll
    for (int i = 0; i < 4; ++i) {
#pragma unroll
        for (int j = 0; j < 4; ++j) {
            int bg = b0 + wb + j * 16 + lm;
#pragma unroll
            for (int r = 0; r < 4; ++r) {
                int ag = a0 + wa + i * 16 + (ln >> 4) * 4 + r;
                op[(size_t)ag * NBpad + bg] = acc[i][j][r];
            }
        }
    }
}

// ---------------- MFMA TN GEMM 256a x 128b (next_A) ----------------
__global__ void __launch_bounds__(256) mfma_tn256_kernel(
        const unsigned short* __restrict__ A_T, const unsigned short* __restrict__ B_T,
        float* __restrict__ partial, int nPer) {
    const int a0 = blockIdx.x * 256, b0 = blockIdx.y * 128;
    const int nbeg = blockIdx.z * nPer;
    const int nend = min(nbeg + nPer, NPAD);
    __shared__ unsigned short Al[256 * 72];
    __shared__ unsigned short Bl[128 * 72];
    const int t = threadIdx.x;
    const int ln = t & 63, wv = t >> 6;
    const int wa = wv * 64;
    const int lm = ln & 15, lk = (ln >> 4) * 8;
    f32x4 acc[4][8];
#pragma unroll
    for (int i = 0; i < 4; ++i)
#pragma unroll
        for (int j = 0; j < 8; ++j) acc[i][j] = (f32x4){0.f, 0.f, 0.f, 0.f};
    for (int nb = nbeg; nb < nend; nb += 64) {
        __syncthreads();
#pragma unroll
        for (int i = 0; i < 8; ++i) {
            int idx = t + i * 256;
            int r = idx >> 3, c8 = (idx & 7) * 8;
            uint4 va = *(const uint4*)&A_T[(size_t)(a0 + r) * NPAD + nb + c8];
            *(uint4*)&Al[r * 72 + c8] = va;
        }
#pragma unroll
        for (int i = 0; i < 4; ++i) {
            int idx = t + i * 256;
            int r = idx >> 3, c8 = (idx & 7) * 8;
            uint4 vb = *(const uint4*)&B_T[(size_t)(b0 + r) * NPAD + nb + c8];
            *(uint4*)&Bl[r * 72 + c8] = vb;
        }
        __syncthreads();
#pragma unroll
        for (int ks = 0; ks < 64; ks += 32) {
            bf16x8 af[4], bfr[8];
#pragma unroll
            for (int i = 0; i < 4; ++i)
                af[i] = *(const bf16x8*)&Al[(wa + i * 16 + lm) * 72 + ks + lk];
#pragma unroll
            for (int j = 0; j < 8; ++j)
                bfr[j] = *(const bf16x8*)&Bl[(j * 16 + lm) * 72 + ks + lk];
#pragma unroll
            for (int i = 0; i < 4; ++i)
#pragma unroll
                for (int j = 0; j < 8; ++j)
                    acc[i][j] = __builtin_amdgcn_mfma_f32_16x16x32_bf16(af[i], bfr[j], acc[i][j], 0, 0, 0);
        }
    }
    float* op = partial + (size_t)blockIdx.z * 512 * 512;
#pragma unroll
    for (int i = 0; i < 4; ++i) {
#pragma unroll
        for (int j = 0; j < 8; ++j) {
            int bg = b0 + j * 16 + lm;
#pragma unroll
            for (int r = 0; r < 4; ++r) {
                int ag = a0 + wa + i * 16 + (ln >> 4) * 4 + r;
                op[(size_t)ag * 512 + bg] = acc[i][j][r];
            }
        }
    }
}

// ---------------- split-K reduce ----------------
__global__ void reduce_kernel(const float* __restrict__ partial, float* __restrict__ out,
                              int rows, int cols, int NBpad, int Z) {
    int idx = blockIdx.x * blockDim.x + threadIdx.x;
    if (idx >= rows * cols) return;
    int a = idx / cols, b = idx - a * cols;
    const float* p = partial + (size_t)a * NBpad + b;
    size_t step = (size_t)512 * NBpad;
    float s = 0.f;
    for (int z = 0; z < Z; ++z) s += p[(size_t)z * step];
    out[idx] = s;
}

extern "C" void kernel_launch(void* const* d_in, const int* in_sizes, int n_in,
                              void* d_out, int out_size, void* d_ws, size_t ws_size,
                              hipStream_t stream) {
    const float* x        = (const float*)d_in[0];
    const int*   ei       = (const int*)d_in[1];
    const float* W_embed  = (const float*)d_in[2];
    const float* b_embed  = (const float*)d_in[3];
    const float* W_assign = (const float*)d_in[4];
    const float* b_assign = (const float*)d_in[5];

    const int N = in_sizes[0] / DD;     // 50000
    const int E = in_sizes[1] / 2;      // 800000
    const int C = in_sizes[3];          // 64
    const int K = in_sizes[5];          // 500

    const int* rowv = ei;
    const int* colv = ei + E;

    char* p = (char*)d_ws;
    auto alloc = [&](size_t bytes) -> void* {
        void* r = (void*)p;
        p += (bytes + 255) & ~(size_t)255;
        return r;
    };
    int*   cnt      = (int*)alloc((size_t)2 * NS * 4);
    int*   cnt_col  = cnt;
    int*   cnt_row  = cnt + NS;
    int*   offs_col = (int*)alloc((size_t)(N + 1) * 4);
    int*   cur_col  = (int*)alloc((size_t)N * 4);
    int*   bsum     = (int*)alloc(64 * 4);
    int*   bbase    = (int*)alloc(64 * 4);
    float* dinv     = (float*)alloc((size_t)N * 4);
    float* tsum     = (float*)alloc((size_t)N * 4);
    int*   esrc     = (int*)alloc((size_t)E * 4);
    float* u        = (float*)alloc((size_t)N * DD * 4);                   // 12.8 MB
    unsigned short* xb   = (unsigned short*)alloc((size_t)N * DD * 2);     // 6.4 MB
    unsigned char*  Sf8  = (unsigned char*)alloc((size_t)N * KPAD);        // 25.6 MB
    unsigned short* S_T  = (unsigned short*)alloc((size_t)KPAD * NPAD * 2);
    unsigned short* G_T  = (unsigned short*)alloc((size_t)KPAD * NPAD * 2);
    unsigned short* Zb   = (unsigned short*)alloc((size_t)N * DD * 2);
    unsigned short* Z_T  = (unsigned short*)alloc((size_t)128 * NPAD * 2);

    // split-K (nPer=1088, Z=46: 1088*46 == NPAD)
    const int nPer = 1088, ZSK = 46;
    float* partialA = (float*)alloc((size_t)ZSK * 512 * 512 * 4);          // 48.2 MB
    float* partialX = (float*)u;    // 46*512*128*4 = 12.06 MB <= 12.8 MB (u dead by then)

    float* outX = (float*)d_out;            // [500][64]
    float* outA = outX + (size_t)K * C;     // [500][500]

    const int NB = (N + 1023) / 1024;       // 49 scan tiles

    (void)hipMemsetAsync(cnt, 0, (size_t)2 * NS * 4, stream);

    hist_kernel<<<(E + 255) / 256, 256, 0, stream>>>(rowv, colv, cnt_row, cnt_col, E);
    scanA_kernel<<<NB, 256, 0, stream>>>(cnt_col, bsum);
    scanB_kernel<<<1, 64, 0, stream>>>(bsum, bbase, &offs_col[N], NB);
    scanC_kernel<<<NB, 256, 0, stream>>>(cnt_col, cnt_row, bbase, offs_col, cur_col, dinv, N);
    place_kernel<<<(E + 255) / 256, 256, 0, stream>>>(rowv, colv, cur_col, esrc, E);

    xscale_kernel<<<(N * 16 + 255) / 256, 256, 0, stream>>>(x, dinv, xb, N * 16);
    agg_kernel<<<(N + 3) / 4, 256, 0, stream>>>(xb, dinv, offs_col, esrc, u, tsum, N);

    // Z (bf16 row-major) then Z_T
    zgemm_kernel<<<(N + 31) / 32, 256, 0, stream>>>(u, W_embed, b_embed, dinv, tsum, Zb, N);
    {
        dim3 gz(NPAD / 64, 2);
        transpose_bf16<<<gz, 256, 0, stream>>>(Zb, Z_T, N, DD);
    }

    // fused assign: S_T (direct transposed) + Sf8
    fused_s_kernel<<<NPAD / FS_ROWS, 256, 0, stream>>>(u, W_assign, b_assign,
                                                       dinv, tsum, S_T, Sf8, N);

    // G_T = (A^T S)^T via fp8 gather
    g_agg_t_kernel<<<NPAD / GT_ROWS, 256, 0, stream>>>(Sf8, offs_col, esrc, G_T, N);

    // next_X = S^T @ Z
    {
        dim3 g(4, 1, ZSK);
        mfma_tn_kernel<<<g, 256, 0, stream>>>(S_T, Z_T, partialX, nPer, 128);
        reduce_kernel<<<(K * C + 255) / 256, 256, 0, stream>>>(partialX, outX, K, C, 128, ZSK);
    }
    // next_A = G^T @ S
    {
        dim3 g(2, 4, ZSK);
        mfma_tn256_kernel<<<g, 256, 0, stream>>>(G_T, S_T, partialA, nPer);
        reduce_kernel<<<(K * K + 255) / 256, 256, 0, stream>>>(partialA, outA, K, K, 512, ZSK);
    }
}

// Round 9
// 579.244 us; speedup vs baseline: 3.6060x; 1.0245x over previous
//
#include <hip/hip_runtime.h>
#include <hip/hip_bf16.h>
#include <math.h>

// Problem constants: N=50000, E=800000, D=64, K=500, C=64
#define DD 64
#define KK 500
#define KPAD 512
#define NPAD 50048   // N padded to multiple of 64
#define NS 50176     // N padded to multiple of 1024 (scan tiles)

typedef __attribute__((ext_vector_type(8))) short bf16x8;
typedef __attribute__((ext_vector_type(4))) float f32x4;

#if defined(__has_builtin)
#if __has_builtin(__builtin_amdgcn_cvt_pk_f32_fp8) && __has_builtin(__builtin_amdgcn_cvt_pk_fp8_f32)
#define HAS_FP8_CVT 1
#endif
#endif

__device__ inline unsigned short f2bf(float f) {
    unsigned u = __float_as_uint(f);
    u += 0x7fffu + ((u >> 16) & 1u);          // RNE
    return (unsigned short)(u >> 16);
}
__device__ inline unsigned packbf(float lo, float hi) {
    return ((unsigned)f2bf(hi) << 16) | (unsigned)f2bf(lo);
}
__device__ inline float bf2f(unsigned short h) {
    return __uint_as_float((unsigned)h << 16);
}

#ifndef HAS_FP8_CVT
__device__ inline float fp8_to_f32_slow(unsigned b) {
    unsigned s = (b >> 7) & 1, e = (b >> 3) & 15, m = b & 7;
    float v = (e == 0) ? ldexpf((float)m, -9) : ldexpf((float)(8 + m), (int)e - 10);
    return s ? -v : v;
}
__device__ inline unsigned f32_to_fp8_slow(float f) {
    unsigned sgn = (__float_as_uint(f) >> 24) & 0x80u;
    float af = fabsf(f);
    if (!(af > 0.f)) return sgn;
    if (af >= 448.f) return sgn | 0x7E;
    int e; frexpf(af, &e);
    int E = e - 1 + 7;
    if (E < 1) { unsigned q = (unsigned)rintf(ldexpf(af, 9)); return sgn | q; }
    unsigned q = (unsigned)rintf(ldexpf(af, 10 - E));
    if (q >= 16) { q = 8; E++; }
    if (E > 15 || (E == 15 && q - 8 >= 7)) return sgn | 0x7E;
    return sgn | ((unsigned)E << 3) | (q - 8);
}
#endif

__device__ inline void accf8(float* a, uint2 v) {
#ifdef HAS_FP8_CVT
    auto f0 = __builtin_amdgcn_cvt_pk_f32_fp8(v.x, false);
    a[0] += f0[0]; a[1] += f0[1];
    auto f1 = __builtin_amdgcn_cvt_pk_f32_fp8(v.x, true);
    a[2] += f1[0]; a[3] += f1[1];
    auto f2 = __builtin_amdgcn_cvt_pk_f32_fp8(v.y, false);
    a[4] += f2[0]; a[5] += f2[1];
    auto f3 = __builtin_amdgcn_cvt_pk_f32_fp8(v.y, true);
    a[6] += f3[0]; a[7] += f3[1];
#else
    a[0] += fp8_to_f32_slow(v.x & 0xff);         a[1] += fp8_to_f32_slow((v.x >> 8) & 0xff);
    a[2] += fp8_to_f32_slow((v.x >> 16) & 0xff); a[3] += fp8_to_f32_slow((v.x >> 24) & 0xff);
    a[4] += fp8_to_f32_slow(v.y & 0xff);         a[5] += fp8_to_f32_slow((v.y >> 8) & 0xff);
    a[6] += fp8_to_f32_slow((v.y >> 16) & 0xff); a[7] += fp8_to_f32_slow((v.y >> 24) & 0xff);
#endif
}

// ---------------- degree histogram ----------------
__global__ void hist_kernel(const int* __restrict__ rowv, const int* __restrict__ colv,
                            int* __restrict__ cnt_row, int* __restrict__ cnt_col, int E) {
    int e = blockIdx.x * blockDim.x + threadIdx.x;
    if (e >= E) return;
    atomicAdd(&cnt_row[rowv[e]], 1);
    atomicAdd(&cnt_col[colv[e]], 1);
}

// ---------------- hierarchical coalesced scan ----------------
__global__ void scanA_kernel(const int* __restrict__ cnt, int* __restrict__ bsum) {
    __shared__ int red[256];
    int t = threadIdx.x;
    int4 c = *(const int4*)&cnt[blockIdx.x * 1024 + t * 4];
    red[t] = c.x + c.y + c.z + c.w;
    __syncthreads();
    for (int o = 128; o > 0; o >>= 1) {
        if (t < o) red[t] += red[t + o];
        __syncthreads();
    }
    if (t == 0) bsum[blockIdx.x] = red[0];
}

__global__ void scanB_kernel(const int* __restrict__ bsum, int* __restrict__ bbase,
                             int* __restrict__ offs_n, int nb) {
    int t = threadIdx.x;
    int v = (t < nb) ? bsum[t] : 0;
    int own = v;
    for (int o = 1; o < 64; o <<= 1) {
        int w = __shfl_up(v, o, 64);
        if (t >= o) v += w;
    }
    if (t < nb) bbase[t] = v - own;
    if (t == 63) *offs_n = v;
}

__global__ void scanC_kernel(const int* __restrict__ cnt, const int* __restrict__ cnt_row,
                             const int* __restrict__ bbase, int* __restrict__ offs,
                             int* __restrict__ cur, float* __restrict__ dinv, int n) {
    __shared__ int sums[256];
    int t = threadIdx.x;
    int i0 = blockIdx.x * 1024 + t * 4;
    int4 c = *(const int4*)&cnt[i0];
    int s = c.x + c.y + c.z + c.w;
    sums[t] = s;
    __syncthreads();
    for (int o = 1; o < 256; o <<= 1) {
        int w = (t >= o) ? sums[t - o] : 0;
        __syncthreads();
        sums[t] += w;
        __syncthreads();
    }
    int base = bbase[blockIdx.x] + sums[t] - s;
    int p0 = base, p1 = base + c.x, p2 = p1 + c.y, p3 = p2 + c.z;
    if (i0 + 0 < n) { offs[i0 + 0] = p0; cur[i0 + 0] = p0; }
    if (i0 + 1 < n) { offs[i0 + 1] = p1; cur[i0 + 1] = p1; }
    if (i0 + 2 < n) { offs[i0 + 2] = p2; cur[i0 + 2] = p2; }
    if (i0 + 3 < n) { offs[i0 + 3] = p3; cur[i0 + 3] = p3; }
    int4 cr = *(const int4*)&cnt_row[i0];
    if (i0 + 0 < n) dinv[i0 + 0] = 1.0f / sqrtf((float)(cr.x + 1));
    if (i0 + 1 < n) dinv[i0 + 1] = 1.0f / sqrtf((float)(cr.y + 1));
    if (i0 + 2 < n) dinv[i0 + 2] = 1.0f / sqrtf((float)(cr.z + 1));
    if (i0 + 3 < n) dinv[i0 + 3] = 1.0f / sqrtf((float)(cr.w + 1));
}

// ---------------- in-CSR placement ----------------
__global__ void place_kernel(const int* __restrict__ rowv, const int* __restrict__ colv,
                             int* __restrict__ cur_col, int* __restrict__ esrc, int E) {
    int e = blockIdx.x * blockDim.x + threadIdx.x;
    if (e >= E) return;
    int p = atomicAdd(&cur_col[colv[e]], 1);
    esrc[p] = rowv[e];
}

// ---------------- xb = bf16(dinv[i] * x[i]) ----------------
__global__ void xscale_kernel(const float* __restrict__ x, const float* __restrict__ dinv,
                              unsigned short* __restrict__ xb, int n16) {
    int idx = blockIdx.x * blockDim.x + threadIdx.x;
    if (idx >= n16) return;
    int i = idx >> 4;
    float di = dinv[i];
    float4 v = ((const float4*)x)[idx];
    uint2 o;
    o.x = packbf(di * v.x, di * v.y);
    o.y = packbf(di * v.z, di * v.w);
    ((uint2*)xb)[idx] = o;
}

// ---------------- Wa_T[c][d] = bf16(Wa[d][c]); rows >= KK zero ----------------
__global__ void wat_kernel(const float* __restrict__ Wa, unsigned short* __restrict__ WaT) {
    int idx = blockIdx.x * blockDim.x + threadIdx.x;   // 0..512*64-1
    int c = idx >> 6, d = idx & 63;
    float v = (c < KK) ? Wa[(size_t)d * KK + c] : 0.f;
    WaT[idx] = f2bf(v);
}

// ---- u[i] = xb[i] + sum_{in} xb[s]; ub = bf16(u);  t[i] = dinv[i] + sum_{in} dinv[s] ----
// grid covers NPAD rows; tail rows write ub = 0.
__global__ void agg_kernel(const unsigned short* __restrict__ xb, const float* __restrict__ dinv,
                           const int* __restrict__ offs, const int* __restrict__ esrc,
                           float* __restrict__ u, float* __restrict__ t,
                           unsigned short* __restrict__ ub, int n) {
    int wv = (blockIdx.x * blockDim.x + threadIdx.x) >> 6;
    int ln = threadIdx.x & 63;
    if (wv >= NPAD) return;
    if (wv >= n) {                      // zero tail for MFMA operand
        ub[(size_t)wv * 64 + ln] = 0;
        return;
    }
    float di = dinv[wv];
    float acc = bf2f(xb[(size_t)wv * 64 + ln]);
    float ts = 0.f;
    int p = offs[wv], pend = offs[wv + 1];
    for (; p + 3 < pend; p += 4) {
        int s0 = esrc[p], s1 = esrc[p + 1], s2 = esrc[p + 2], s3 = esrc[p + 3];
        unsigned short h0 = xb[(size_t)s0 * 64 + ln];
        unsigned short h1 = xb[(size_t)s1 * 64 + ln];
        unsigned short h2 = xb[(size_t)s2 * 64 + ln];
        unsigned short h3 = xb[(size_t)s3 * 64 + ln];
        float w0 = dinv[s0], w1 = dinv[s1], w2 = dinv[s2], w3 = dinv[s3];
        acc += bf2f(h0) + bf2f(h1) + bf2f(h2) + bf2f(h3);
        ts += w0 + w1 + w2 + w3;
    }
    for (; p < pend; ++p) {
        int s = esrc[p];
        acc += bf2f(xb[(size_t)s * 64 + ln]);
        ts += dinv[s];
    }
    u[(size_t)wv * 64 + ln] = acc;
    ub[(size_t)wv * 64 + ln] = f2bf(acc);
    if (ln == 0) t[wv] = di + ts;
}

// ---------------- Z_b = bf16( dinv*(u@W + t*b) ); [N][64] bf16 ----------------
__global__ void zgemm_kernel(const float* __restrict__ u, const float* __restrict__ W,
                             const float* __restrict__ bias, const float* __restrict__ dinv,
                             const float* __restrict__ tsum, unsigned short* __restrict__ Zb, int n) {
    const int C4 = 16;
    int r0 = blockIdx.x * 32;
    __shared__ float us[32 * 68];
    int t = threadIdx.x;
#pragma unroll
    for (int k = 0; k < 2; ++k) {
        int idx = t * 2 + k;
        int rr = idx >> 4, c4 = idx & 15;
        int row = r0 + rr;
        float4 v = make_float4(0.f, 0.f, 0.f, 0.f);
        if (row < n) v = ((const float4*)u)[(size_t)row * 16 + c4];
        *(float4*)&us[rr * 68 + c4 * 4] = v;
    }
    __syncthreads();
    int lr = t >> 3;
    int cg = t & 7;
    int f40 = cg * 2, f41 = f40 + 1;
    float4 acc0 = make_float4(0.f,0.f,0.f,0.f), acc1 = make_float4(0.f,0.f,0.f,0.f);
    const float4* W4 = (const float4*)W;
    for (int d = 0; d < 64; ++d) {
        float uv = us[lr * 68 + d];
        float4 w0 = W4[(size_t)d * C4 + f40];
        float4 w1 = W4[(size_t)d * C4 + f41];
        acc0.x += uv*w0.x; acc0.y += uv*w0.y; acc0.z += uv*w0.z; acc0.w += uv*w0.w;
        acc1.x += uv*w1.x; acc1.y += uv*w1.y; acc1.z += uv*w1.z; acc1.w += uv*w1.w;
    }
    int row = r0 + lr;
    if (row < n) {
        float di = dinv[row], tv = tsum[row];
        const float4* b4 = (const float4*)bias;
        float4 bv0 = b4[f40], bv1 = b4[f41];
        float z0 = di*(acc0.x+tv*bv0.x), z1 = di*(acc0.y+tv*bv0.y);
        float z2 = di*(acc0.z+tv*bv0.z), z3 = di*(acc0.w+tv*bv0.w);
        float z4 = di*(acc1.x+tv*bv1.x), z5 = di*(acc1.y+tv*bv1.y);
        float z6 = di*(acc1.z+tv*bv1.z), z7 = di*(acc1.w+tv*bv1.w);
        uint4 o;
        o.x = packbf(z0, z1); o.y = packbf(z2, z3);
        o.z = packbf(z4, z5); o.w = packbf(z6, z7);
        ((uint4*)Zb)[(size_t)row * 8 + cg] = o;
    }
}

// ---- fused assign v2 (MFMA): L^T = Wa_T @ ub^T; softmax per node; -> S_T bf16 + Sf8 e4m3.
//      Block = 64 nodes (4 waves x 16 nodes); each wave: all 512 clusters (32 m-tiles). ----
#define F8ROW 520
__global__ void __launch_bounds__(256) fused_s2_kernel(
        const unsigned short* __restrict__ ub, const unsigned short* __restrict__ WaT,
        const float* __restrict__ ba, const float* __restrict__ dinv,
        const float* __restrict__ tsum, unsigned short* __restrict__ S_T,
        unsigned char* __restrict__ Sf8, int n) {
    __shared__ float bs[512];
    __shared__ unsigned char f8[64 * F8ROW];     // 33.3 KB fp8 node-major tile
    int t = threadIdx.x;
    int n0 = blockIdx.x * 64;
    {
        float b0 = (t * 2     < KK) ? ba[t * 2]     : 0.f;
        float b1 = (t * 2 + 1 < KK) ? ba[t * 2 + 1] : 0.f;
        bs[t * 2] = b0; bs[t * 2 + 1] = b1;
    }
    __syncthreads();
    int wv = t >> 6, ln = t & 63;
    int nl = ln & 15;                 // node within wave tile (C col)
    int g  = ln >> 4;                 // quad (C row group / frag k-chunk)
    int node = n0 + wv * 16 + nl;
    float sd = (node < n) ? dinv[node] : 0.f;
    float st = (node < n) ? tsum[node] : 0.f;
    // B fragments: ub[node][k], k-chunk = g*8, two k-steps
    const unsigned short* brow = ub + (size_t)node * 64;
    bf16x8 bf0 = *(const bf16x8*)&brow[g * 8];
    bf16x8 bf1 = *(const bf16x8*)&brow[32 + g * 8];
    f32x4 acc[32];
#pragma unroll
    for (int mt = 0; mt < 32; ++mt) {
        const unsigned short* arow = WaT + (size_t)(mt * 16 + nl) * 64;
        bf16x8 af0 = *(const bf16x8*)&arow[g * 8];
        bf16x8 af1 = *(const bf16x8*)&arow[32 + g * 8];
        f32x4 a = __builtin_amdgcn_mfma_f32_16x16x32_bf16(af0, bf0, (f32x4){0.f,0.f,0.f,0.f}, 0, 0, 0);
        acc[mt] = __builtin_amdgcn_mfma_f32_16x16x32_bf16(af1, bf1, a, 0, 0, 0);
    }
    // bias + mask + max
    float m = -1e30f;
#pragma unroll
    for (int mt = 0; mt < 32; ++mt) {
#pragma unroll
        for (int r = 0; r < 4; ++r) {
            int cl = mt * 16 + g * 4 + r;
            float L = sd * (acc[mt][r] + st * bs[cl]);
            if (cl >= KK) L = -1e30f;
            acc[mt][r] = L;
            m = fmaxf(m, L);
        }
    }
    m = fmaxf(m, __shfl_xor(m, 16, 64));
    m = fmaxf(m, __shfl_xor(m, 32, 64));
    float ssum = 0.f;
#pragma unroll
    for (int mt = 0; mt < 32; ++mt) {
#pragma unroll
        for (int r = 0; r < 4; ++r) {
            float e = expf(acc[mt][r] - m);
            acc[mt][r] = e;
            ssum += e;
        }
    }
    ssum += __shfl_xor(ssum, 16, 64);
    ssum += __shfl_xor(ssum, 32, 64);
    float rs = (node < n) ? (1.0f / ssum) : 0.f;
    float sc = 256.f * rs;
    unsigned char* frow = &f8[(wv * 16 + nl) * F8ROW];
#pragma unroll
    for (int mt = 0; mt < 32; ++mt) {
        // S_T stores: 16 lanes of quad g write 32B-contiguous bf16
#pragma unroll
        for (int r = 0; r < 4; ++r) {
            int cl = mt * 16 + g * 4 + r;
            S_T[(size_t)cl * NPAD + node] = f2bf(acc[mt][r] * rs);
        }
        // Sf8: 4 consecutive clusters -> packed uint into LDS tile
#ifdef HAS_FP8_CVT
        int pk = __builtin_amdgcn_cvt_pk_fp8_f32(acc[mt][0] * sc, acc[mt][1] * sc, 0, false);
        pk     = __builtin_amdgcn_cvt_pk_fp8_f32(acc[mt][2] * sc, acc[mt][3] * sc, pk, true);
#else
        int pk = (int)(f32_to_fp8_slow(acc[mt][0]*sc) | (f32_to_fp8_slow(acc[mt][1]*sc) << 8) |
                       (f32_to_fp8_slow(acc[mt][2]*sc) << 16) | (f32_to_fp8_slow(acc[mt][3]*sc) << 24));
#endif
        *(unsigned*)&frow[mt * 16 + g * 4] = (unsigned)pk;
    }
    __syncthreads();
    // coalesced Sf8 row stores: 64 rows x 512 B
#pragma unroll
    for (int h = 0; h < 8; ++h) {
        int idx = t + h * 256;            // uint4 index; 32 per row
        int row = idx >> 5;
        int off = (idx & 31) * 16;
        uint4 vv = *(const uint4*)&f8[row * F8ROW + off];
        int grow = n0 + row;
        if (grow < n) *(uint4*)&Sf8[(size_t)grow * KPAD + off] = vv;
    }
}

// -------- G = A^T S via in-CSR over fp8 S, written TRANSPOSED bf16: G_T[k][n] --------
#define GT_ROWS 32
__global__ void g_agg_t_kernel(const unsigned char* __restrict__ Sf8, const int* __restrict__ offs,
                               const int* __restrict__ esrc, unsigned short* __restrict__ G_T, int n) {
    __shared__ unsigned short tl[GT_ROWS * 520];
    int base = blockIdx.x * GT_ROWS;
    int wv = threadIdx.x >> 6, ln = threadIdx.x & 63;
    const uint2* S2 = (const uint2*)Sf8;
#pragma unroll
    for (int i = 0; i < GT_ROWS / 4; ++i) {
        int r = wv * (GT_ROWS / 4) + i;
        int node = base + r;
        float a[8] = {0.f,0.f,0.f,0.f,0.f,0.f,0.f,0.f};
        if (node < n) {
            int p = offs[node], pend = offs[node + 1];
            for (; p + 3 < pend; p += 4) {
                int s0 = esrc[p], s1 = esrc[p + 1], s2 = esrc[p + 2], s3 = esrc[p + 3];
                uint2 v0 = S2[(size_t)s0 * 64 + ln];
                uint2 v1 = S2[(size_t)s1 * 64 + ln];
                uint2 v2 = S2[(size_t)s2 * 64 + ln];
                uint2 v3 = S2[(size_t)s3 * 64 + ln];
                accf8(a, v0); accf8(a, v1); accf8(a, v2); accf8(a, v3);
            }
            for (; p < pend; ++p) {
                uint2 v = S2[(size_t)esrc[p] * 64 + ln];
                accf8(a, v);
            }
        }
        const float inv = 1.0f / 256.f;
        uint4 o;
        o.x = packbf(a[0] * inv, a[1] * inv); o.y = packbf(a[2] * inv, a[3] * inv);
        o.z = packbf(a[4] * inv, a[5] * inv); o.w = packbf(a[6] * inv, a[7] * inv);
        *(uint4*)&tl[r * 520 + ln * 8] = o;
    }
    __syncthreads();
#pragma unroll
    for (int h = 0; h < 2; ++h) {
        int k = threadIdx.x + h * 256;
        unsigned wb[8];
#pragma unroll
        for (int j = 0; j < 8; ++j) {
            unsigned short lo = tl[(2 * j)     * 520 + k];
            unsigned short hi = tl[(2 * j + 1) * 520 + k];
            wb[j] = ((unsigned)hi << 16) | (unsigned)lo;
        }
        unsigned wc[8];
#pragma unroll
        for (int j = 0; j < 8; ++j) {
            unsigned short lo = tl[(16 + 2 * j) * 520 + k];
            unsigned short hi = tl[(17 + 2 * j) * 520 + k];
            wc[j] = ((unsigned)hi << 16) | (unsigned)lo;
        }
        size_t ob = (size_t)k * NPAD + base;
        *(uint4*)&G_T[ob]      = make_uint4(wb[0], wb[1], wb[2], wb[3]);
        *(uint4*)&G_T[ob + 8]  = make_uint4(wb[4], wb[5], wb[6], wb[7]);
        *(uint4*)&G_T[ob + 16] = make_uint4(wc[0], wc[1], wc[2], wc[3]);
        *(uint4*)&G_T[ob + 24] = make_uint4(wc[4], wc[5], wc[6], wc[7]);
    }
}

// ---------------- bf16 transpose (for Z only) ----------------
__global__ void transpose_bf16(const unsigned short* __restrict__ in, unsigned short* __restrict__ out,
                               int N, int Cin) {
    __shared__ unsigned short tl[64 * 72];
    int n0 = blockIdx.x * 64, c0 = blockIdx.y * 64;
    int t = threadIdx.x;
    int r = t >> 2, s = t & 3;
    int n = n0 + r;
#pragma unroll
    for (int h = 0; h < 2; ++h) {
        int c = c0 + s * 16 + h * 8;
        uint4 v = make_uint4(0u, 0u, 0u, 0u);
        if (n < N && c < Cin) v = *(const uint4*)&in[(size_t)n * Cin + c];
        *(uint4*)&tl[r * 72 + s * 16 + h * 8] = v;
    }
    __syncthreads();
    int cc = t >> 2, seg = t & 3;
    unsigned wbuf[8];
#pragma unroll
    for (int k = 0; k < 8; ++k) {
        unsigned short lo = tl[(seg * 16 + 2 * k)     * 72 + cc];
        unsigned short hi = tl[(seg * 16 + 2 * k + 1) * 72 + cc];
        wbuf[k] = ((unsigned)hi << 16) | (unsigned)lo;
    }
    size_t ob = (size_t)(c0 + cc) * NPAD + n0 + seg * 16;
    *(uint4*)&out[ob]     = make_uint4(wbuf[0], wbuf[1], wbuf[2], wbuf[3]);
    *(uint4*)&out[ob + 8] = make_uint4(wbuf[4], wbuf[5], wbuf[6], wbuf[7]);
}

// ---------------- MFMA TN GEMM 128x128 (next_X) ----------------
__global__ void __launch_bounds__(256) mfma_tn_kernel(
        const unsigned short* __restrict__ A_T, const unsigned short* __restrict__ B_T,
        float* __restrict__ partial, int nPer, int NBpad) {
    const int a0 = blockIdx.x * 128, b0 = blockIdx.y * 128;
    const int nbeg = blockIdx.z * nPer;
    const int nend = min(nbeg + nPer, NPAD);
    __shared__ unsigned short Al[128 * 72];
    __shared__ unsigned short Bl[128 * 72];
    const int t = threadIdx.x;
    const int ln = t & 63, wv = t >> 6;
    const int wa = (wv & 1) * 64, wb = (wv >> 1) * 64;
    const int lm = ln & 15, lk = (ln >> 4) * 8;
    f32x4 acc[4][4];
#pragma unroll
    for (int i = 0; i < 4; ++i)
#pragma unroll
        for (int j = 0; j < 4; ++j) acc[i][j] = (f32x4){0.f, 0.f, 0.f, 0.f};
    for (int nb = nbeg; nb < nend; nb += 64) {
        __syncthreads();
#pragma unroll
        for (int i = 0; i < 4; ++i) {
            int idx = t + i * 256;
            int r = idx >> 3, c8 = (idx & 7) * 8;
            uint4 va = *(const uint4*)&A_T[(size_t)(a0 + r) * NPAD + nb + c8];
            uint4 vb = *(const uint4*)&B_T[(size_t)(b0 + r) * NPAD + nb + c8];
            *(uint4*)&Al[r * 72 + c8] = va;
            *(uint4*)&Bl[r * 72 + c8] = vb;
        }
        __syncthreads();
#pragma unroll
        for (int ks = 0; ks < 64; ks += 32) {
            bf16x8 af[4], bfr[4];
#pragma unroll
            for (int i = 0; i < 4; ++i)
                af[i] = *(const bf16x8*)&Al[(wa + i * 16 + lm) * 72 + ks + lk];
#pragma unroll
            for (int j = 0; j < 4; ++j)
                bfr[j] = *(const bf16x8*)&Bl[(wb + j * 16 + lm) * 72 + ks + lk];
#pragma unroll
            for (int i = 0; i < 4; ++i)
#pragma unroll
                for (int j = 0; j < 4; ++j)
                    acc[i][j] = __builtin_amdgcn_mfma_f32_16x16x32_bf16(af[i], bfr[j], acc[i][j], 0, 0, 0);
        }
    }
    float* op = partial + (size_t)blockIdx.z * 512 * NBpad;
#pragma unroll
    for (int i = 0; i < 4; ++i) {
#pragma unroll
        for (int j = 0; j < 4; ++j) {
            int bg = b0 + wb + j * 16 + lm;
#pragma unroll
            for (int r = 0; r < 4; ++r) {
                int ag = a0 + wa + i * 16 + (ln >> 4) * 4 + r;
                op[(size_t)ag * NBpad + bg] = acc[i][j][r];
            }
        }
    }
}

// ---------------- MFMA TN GEMM 256a x 128b (next_A) ----------------
__global__ void __launch_bounds__(256) mfma_tn256_kernel(
        const unsigned short* __restrict__ A_T, const unsigned short* __restrict__ B_T,
        float* __restrict__ partial, int nPer) {
    const int a0 = blockIdx.x * 256, b0 = blockIdx.y * 128;
    const int nbeg = blockIdx.z * nPer;
    const int nend = min(nbeg + nPer, NPAD);
    __shared__ unsigned short Al[256 * 72];
    __shared__ unsigned short Bl[128 * 72];
    const int t = threadIdx.x;
    const int ln = t & 63, wv = t >> 6;
    const int wa = wv * 64;
    const int lm = ln & 15, lk = (ln >> 4) * 8;
    f32x4 acc[4][8];
#pragma unroll
    for (int i = 0; i < 4; ++i)
#pragma unroll
        for (int j = 0; j < 8; ++j) acc[i][j] = (f32x4){0.f, 0.f, 0.f, 0.f};
    for (int nb = nbeg; nb < nend; nb += 64) {
        __syncthreads();
#pragma unroll
        for (int i = 0; i < 8; ++i) {
            int idx = t + i * 256;
            int r = idx >> 3, c8 = (idx & 7) * 8;
            uint4 va = *(const uint4*)&A_T[(size_t)(a0 + r) * NPAD + nb + c8];
            *(uint4*)&Al[r * 72 + c8] = va;
        }
#pragma unroll
        for (int i = 0; i < 4; ++i) {
            int idx = t + i * 256;
            int r = idx >> 3, c8 = (idx & 7) * 8;
            uint4 vb = *(const uint4*)&B_T[(size_t)(b0 + r) * NPAD + nb + c8];
            *(uint4*)&Bl[r * 72 + c8] = vb;
        }
        __syncthreads();
#pragma unroll
        for (int ks = 0; ks < 64; ks += 32) {
            bf16x8 af[4], bfr[8];
#pragma unroll
            for (int i = 0; i < 4; ++i)
                af[i] = *(const bf16x8*)&Al[(wa + i * 16 + lm) * 72 + ks + lk];
#pragma unroll
            for (int j = 0; j < 8; ++j)
                bfr[j] = *(const bf16x8*)&Bl[(j * 16 + lm) * 72 + ks + lk];
#pragma unroll
            for (int i = 0; i < 4; ++i)
#pragma unroll
                for (int j = 0; j < 8; ++j)
                    acc[i][j] = __builtin_amdgcn_mfma_f32_16x16x32_bf16(af[i], bfr[j], acc[i][j], 0, 0, 0);
        }
    }
    float* op = partial + (size_t)blockIdx.z * 512 * 512;
#pragma unroll
    for (int i = 0; i < 4; ++i) {
#pragma unroll
        for (int j = 0; j < 8; ++j) {
            int bg = b0 + j * 16 + lm;
#pragma unroll
            for (int r = 0; r < 4; ++r) {
                int ag = a0 + wa + i * 16 + (ln >> 4) * 4 + r;
                op[(size_t)ag * 512 + bg] = acc[i][j][r];
            }
        }
    }
}

// ---------------- split-K reduce ----------------
__global__ void reduce_kernel(const float* __restrict__ partial, float* __restrict__ out,
                              int rows, int cols, int NBpad, int Z) {
    int idx = blockIdx.x * blockDim.x + threadIdx.x;
    if (idx >= rows * cols) return;
    int a = idx / cols, b = idx - a * cols;
    const float* p = partial + (size_t)a * NBpad + b;
    size_t step = (size_t)512 * NBpad;
    float s = 0.f;
    for (int z = 0; z < Z; ++z) s += p[(size_t)z * step];
    out[idx] = s;
}

extern "C" void kernel_launch(void* const* d_in, const int* in_sizes, int n_in,
                              void* d_out, int out_size, void* d_ws, size_t ws_size,
                              hipStream_t stream) {
    const float* x        = (const float*)d_in[0];
    const int*   ei       = (const int*)d_in[1];
    const float* W_embed  = (const float*)d_in[2];
    const float* b_embed  = (const float*)d_in[3];
    const float* W_assign = (const float*)d_in[4];
    const float* b_assign = (const float*)d_in[5];

    const int N = in_sizes[0] / DD;     // 50000
    const int E = in_sizes[1] / 2;      // 800000
    const int C = in_sizes[3];          // 64
    const int K = in_sizes[5];          // 500

    const int* rowv = ei;
    const int* colv = ei + E;

    char* p = (char*)d_ws;
    auto alloc = [&](size_t bytes) -> void* {
        void* r = (void*)p;
        p += (bytes + 255) & ~(size_t)255;
        return r;
    };
    int*   cnt      = (int*)alloc((size_t)2 * NS * 4);
    int*   cnt_col  = cnt;
    int*   cnt_row  = cnt + NS;
    int*   offs_col = (int*)alloc((size_t)(N + 1) * 4);
    int*   cur_col  = (int*)alloc((size_t)N * 4);
    int*   bsum     = (int*)alloc(64 * 4);
    int*   bbase    = (int*)alloc(64 * 4);
    float* dinv     = (float*)alloc((size_t)N * 4);
    float* tsum     = (float*)alloc((size_t)N * 4);
    int*   esrc     = (int*)alloc((size_t)E * 4);
    float* u        = (float*)alloc((size_t)N * DD * 4);                   // 12.8 MB
    unsigned short* xb   = (unsigned short*)alloc((size_t)N * DD * 2);     // 6.4 MB
    unsigned short* ubuf = (unsigned short*)alloc((size_t)NPAD * DD * 2);  // 6.4 MB bf16 u
    unsigned short* WaT  = (unsigned short*)alloc((size_t)KPAD * DD * 2);  // 64 KB
    unsigned char*  Sf8  = (unsigned char*)alloc((size_t)N * KPAD);        // 25.6 MB
    unsigned short* S_T  = (unsigned short*)alloc((size_t)KPAD * NPAD * 2);
    unsigned short* G_T  = (unsigned short*)alloc((size_t)KPAD * NPAD * 2);
    unsigned short* Zb   = (unsigned short*)alloc((size_t)N * DD * 2);
    unsigned short* Z_T  = (unsigned short*)alloc((size_t)128 * NPAD * 2);

    // split-K (nPer=1088, Z=46: 1088*46 == NPAD)
    const int nPer = 1088, ZSK = 46;
    float* partialA = (float*)alloc((size_t)ZSK * 512 * 512 * 4);          // 48.2 MB
    float* partialX = (float*)u;    // 46*512*128*4 = 12.06 MB <= 12.8 MB (u dead by then)

    float* outX = (float*)d_out;            // [500][64]
    float* outA = outX + (size_t)K * C;     // [500][500]

    const int NB = (N + 1023) / 1024;       // 49 scan tiles

    (void)hipMemsetAsync(cnt, 0, (size_t)2 * NS * 4, stream);

    hist_kernel<<<(E + 255) / 256, 256, 0, stream>>>(rowv, colv, cnt_row, cnt_col, E);
    scanA_kernel<<<NB, 256, 0, stream>>>(cnt_col, bsum);
    scanB_kernel<<<1, 64, 0, stream>>>(bsum, bbase, &offs_col[N], NB);
    scanC_kernel<<<NB, 256, 0, stream>>>(cnt_col, cnt_row, bbase, offs_col, cur_col, dinv, N);
    place_kernel<<<(E + 255) / 256, 256, 0, stream>>>(rowv, colv, cur_col, esrc, E);

    xscale_kernel<<<(N * 16 + 255) / 256, 256, 0, stream>>>(x, dinv, xb, N * 16);
    wat_kernel<<<(KPAD * DD) / 256, 256, 0, stream>>>(W_assign, WaT);

    // u (fp32 + bf16) over NPAD rows; tsum folded
    agg_kernel<<<NPAD / 4, 256, 0, stream>>>(xb, dinv, offs_col, esrc, u, tsum, ubuf, N);

    // Z (bf16 row-major) then Z_T
    zgemm_kernel<<<(N + 31) / 32, 256, 0, stream>>>(u, W_embed, b_embed, dinv, tsum, Zb, N);
    {
        dim3 gz(NPAD / 64, 2);
        transpose_bf16<<<gz, 256, 0, stream>>>(Zb, Z_T, N, DD);
    }

    // fused assign v2 (MFMA): S_T + Sf8
    fused_s2_kernel<<<NPAD / 64, 256, 0, stream>>>(ubuf, WaT, b_assign, dinv, tsum, S_T, Sf8, N);

    // G_T = (A^T S)^T via fp8 gather
    g_agg_t_kernel<<<NPAD / GT_ROWS, 256, 0, stream>>>(Sf8, offs_col, esrc, G_T, N);

    // next_X = S^T @ Z
    {
        dim3 g(4, 1, ZSK);
        mfma_tn_kernel<<<g, 256, 0, stream>>>(S_T, Z_T, partialX, nPer, 128);
        reduce_kernel<<<(K * C + 255) / 256, 256, 0, stream>>>(partialX, outX, K, C, 128, ZSK);
    }
    // next_A = G^T @ S
    {
        dim3 g(2, 4, ZSK);
        mfma_tn256_kernel<<<g, 256, 0, stream>>>(G_T, S_T, partialA, nPer);
        reduce_kernel<<<(K * K + 255) / 256, 256, 0, stream>>>(partialA, outA, K, K, 512, ZSK);
    }
}

// Round 10
// 529.391 us; speedup vs baseline: 3.9455x; 1.0942x over previous
//
#include <hip/hip_runtime.h>
#include <hip/hip_bf16.h>
#include <math.h>

// Problem constants: N=50000, E=800000, D=64, K=500, C=64
#define DD 64
#define KK 500
#define KPAD 512
#define NPAD 50048   // N padded to multiple of 64
#define NS 50176     // N padded to multiple of 1024 (scan tiles)

typedef __attribute__((ext_vector_type(8))) short bf16x8;
typedef __attribute__((ext_vector_type(4))) float f32x4;

#if defined(__has_builtin)
#if __has_builtin(__builtin_amdgcn_cvt_pk_f32_fp8) && __has_builtin(__builtin_amdgcn_cvt_pk_fp8_f32)
#define HAS_FP8_CVT 1
#endif
#endif

__device__ inline unsigned short f2bf(float f) {
    unsigned u = __float_as_uint(f);
    u += 0x7fffu + ((u >> 16) & 1u);          // RNE
    return (unsigned short)(u >> 16);
}
__device__ inline unsigned packbf(float lo, float hi) {
    return ((unsigned)f2bf(hi) << 16) | (unsigned)f2bf(lo);
}
__device__ inline float bf2f(unsigned short h) {
    return __uint_as_float((unsigned)h << 16);
}

#ifndef HAS_FP8_CVT
__device__ inline float fp8_to_f32_slow(unsigned b) {
    unsigned s = (b >> 7) & 1, e = (b >> 3) & 15, m = b & 7;
    float v = (e == 0) ? ldexpf((float)m, -9) : ldexpf((float)(8 + m), (int)e - 10);
    return s ? -v : v;
}
__device__ inline unsigned f32_to_fp8_slow(float f) {
    unsigned sgn = (__float_as_uint(f) >> 24) & 0x80u;
    float af = fabsf(f);
    if (!(af > 0.f)) return sgn;
    if (af >= 448.f) return sgn | 0x7E;
    int e; frexpf(af, &e);
    int E = e - 1 + 7;
    if (E < 1) { unsigned q = (unsigned)rintf(ldexpf(af, 9)); return sgn | q; }
    unsigned q = (unsigned)rintf(ldexpf(af, 10 - E));
    if (q >= 16) { q = 8; E++; }
    if (E > 15 || (E == 15 && q - 8 >= 7)) return sgn | 0x7E;
    return sgn | ((unsigned)E << 3) | (q - 8);
}
#endif

__device__ inline void accf8(float* a, uint2 v) {
#ifdef HAS_FP8_CVT
    auto f0 = __builtin_amdgcn_cvt_pk_f32_fp8(v.x, false);
    a[0] += f0[0]; a[1] += f0[1];
    auto f1 = __builtin_amdgcn_cvt_pk_f32_fp8(v.x, true);
    a[2] += f1[0]; a[3] += f1[1];
    auto f2 = __builtin_amdgcn_cvt_pk_f32_fp8(v.y, false);
    a[4] += f2[0]; a[5] += f2[1];
    auto f3 = __builtin_amdgcn_cvt_pk_f32_fp8(v.y, true);
    a[6] += f3[0]; a[7] += f3[1];
#else
    a[0] += fp8_to_f32_slow(v.x & 0xff);         a[1] += fp8_to_f32_slow((v.x >> 8) & 0xff);
    a[2] += fp8_to_f32_slow((v.x >> 16) & 0xff); a[3] += fp8_to_f32_slow((v.x >> 24) & 0xff);
    a[4] += fp8_to_f32_slow(v.y & 0xff);         a[5] += fp8_to_f32_slow((v.y >> 8) & 0xff);
    a[6] += fp8_to_f32_slow((v.y >> 16) & 0xff); a[7] += fp8_to_f32_slow((v.y >> 24) & 0xff);
#endif
}

// ---------------- degree histogram ----------------
__global__ void hist_kernel(const int* __restrict__ rowv, const int* __restrict__ colv,
                            int* __restrict__ cnt_row, int* __restrict__ cnt_col, int E) {
    int e = blockIdx.x * blockDim.x + threadIdx.x;
    if (e >= E) return;
    atomicAdd(&cnt_row[rowv[e]], 1);
    atomicAdd(&cnt_col[colv[e]], 1);
}

// ---------------- hierarchical coalesced scan ----------------
__global__ void scanA_kernel(const int* __restrict__ cnt, int* __restrict__ bsum) {
    __shared__ int red[256];
    int t = threadIdx.x;
    int4 c = *(const int4*)&cnt[blockIdx.x * 1024 + t * 4];
    red[t] = c.x + c.y + c.z + c.w;
    __syncthreads();
    for (int o = 128; o > 0; o >>= 1) {
        if (t < o) red[t] += red[t + o];
        __syncthreads();
    }
    if (t == 0) bsum[blockIdx.x] = red[0];
}

__global__ void scanB_kernel(const int* __restrict__ bsum, int* __restrict__ bbase,
                             int* __restrict__ offs_n, int nb) {
    int t = threadIdx.x;
    int v = (t < nb) ? bsum[t] : 0;
    int own = v;
    for (int o = 1; o < 64; o <<= 1) {
        int w = __shfl_up(v, o, 64);
        if (t >= o) v += w;
    }
    if (t < nb) bbase[t] = v - own;
    if (t == 63) *offs_n = v;
}

__global__ void scanC_kernel(const int* __restrict__ cnt, const int* __restrict__ cnt_row,
                             const int* __restrict__ bbase, int* __restrict__ offs,
                             int* __restrict__ cur, float* __restrict__ dinv, int n) {
    __shared__ int sums[256];
    int t = threadIdx.x;
    int i0 = blockIdx.x * 1024 + t * 4;
    int4 c = *(const int4*)&cnt[i0];
    int s = c.x + c.y + c.z + c.w;
    sums[t] = s;
    __syncthreads();
    for (int o = 1; o < 256; o <<= 1) {
        int w = (t >= o) ? sums[t - o] : 0;
        __syncthreads();
        sums[t] += w;
        __syncthreads();
    }
    int base = bbase[blockIdx.x] + sums[t] - s;
    int p0 = base, p1 = base + c.x, p2 = p1 + c.y, p3 = p2 + c.z;
    if (i0 + 0 < n) { offs[i0 + 0] = p0; cur[i0 + 0] = p0; }
    if (i0 + 1 < n) { offs[i0 + 1] = p1; cur[i0 + 1] = p1; }
    if (i0 + 2 < n) { offs[i0 + 2] = p2; cur[i0 + 2] = p2; }
    if (i0 + 3 < n) { offs[i0 + 3] = p3; cur[i0 + 3] = p3; }
    int4 cr = *(const int4*)&cnt_row[i0];
    if (i0 + 0 < n) dinv[i0 + 0] = 1.0f / sqrtf((float)(cr.x + 1));
    if (i0 + 1 < n) dinv[i0 + 1] = 1.0f / sqrtf((float)(cr.y + 1));
    if (i0 + 2 < n) dinv[i0 + 2] = 1.0f / sqrtf((float)(cr.z + 1));
    if (i0 + 3 < n) dinv[i0 + 3] = 1.0f / sqrtf((float)(cr.w + 1));
}

// ---------------- in-CSR placement ----------------
__global__ void place_kernel(const int* __restrict__ rowv, const int* __restrict__ colv,
                             int* __restrict__ cur_col, int* __restrict__ esrc, int E) {
    int e = blockIdx.x * blockDim.x + threadIdx.x;
    if (e >= E) return;
    int p = atomicAdd(&cur_col[colv[e]], 1);
    esrc[p] = rowv[e];
}

// ---------------- xb = bf16(dinv[i] * x[i]) ----------------
__global__ void xscale_kernel(const float* __restrict__ x, const float* __restrict__ dinv,
                              unsigned short* __restrict__ xb, int n16) {
    int idx = blockIdx.x * blockDim.x + threadIdx.x;
    if (idx >= n16) return;
    int i = idx >> 4;
    float di = dinv[i];
    float4 v = ((const float4*)x)[idx];
    uint2 o;
    o.x = packbf(di * v.x, di * v.y);
    o.y = packbf(di * v.z, di * v.w);
    ((uint2*)xb)[idx] = o;
}

// ---------------- weight prep: WaT[c][d]=bf16(Wa[d][c]) (512x64, c>=KK zero);
//                  WeT[c][d]=bf16(We[d][c]) (64x64) ----------------
__global__ void wprep_kernel(const float* __restrict__ Wa, const float* __restrict__ We,
                             unsigned short* __restrict__ WaT, unsigned short* __restrict__ WeT) {
    int idx = blockIdx.x * blockDim.x + threadIdx.x;   // 0 .. (512+64)*64-1
    if (idx < KPAD * 64) {
        int c = idx >> 6, d = idx & 63;
        float v = (c < KK) ? Wa[(size_t)d * KK + c] : 0.f;
        WaT[idx] = f2bf(v);
    } else {
        int j = idx - KPAD * 64;
        int c = j >> 6, d = j & 63;
        WeT[j] = f2bf(We[(size_t)d * 64 + c]);
    }
}

// ---- u[i] = xb[i] + sum_{in} xb[s]; ub = bf16(u);  t[i] = dinv[i] + sum_{in} dinv[s] ----
__global__ void agg_kernel(const unsigned short* __restrict__ xb, const float* __restrict__ dinv,
                           const int* __restrict__ offs, const int* __restrict__ esrc,
                           float* __restrict__ u, float* __restrict__ t,
                           unsigned short* __restrict__ ub, int n) {
    int wv = (blockIdx.x * blockDim.x + threadIdx.x) >> 6;
    int ln = threadIdx.x & 63;
    if (wv >= NPAD) return;
    if (wv >= n) {                      // zero tail for MFMA operand
        ub[(size_t)wv * 64 + ln] = 0;
        return;
    }
    float di = dinv[wv];
    float acc = bf2f(xb[(size_t)wv * 64 + ln]);
    float ts = 0.f;
    int p = offs[wv], pend = offs[wv + 1];
    for (; p + 7 < pend; p += 8) {      // 8 independent gathers in flight
        int s0 = esrc[p],     s1 = esrc[p + 1], s2 = esrc[p + 2], s3 = esrc[p + 3];
        int s4 = esrc[p + 4], s5 = esrc[p + 5], s6 = esrc[p + 6], s7 = esrc[p + 7];
        unsigned short h0 = xb[(size_t)s0 * 64 + ln];
        unsigned short h1 = xb[(size_t)s1 * 64 + ln];
        unsigned short h2 = xb[(size_t)s2 * 64 + ln];
        unsigned short h3 = xb[(size_t)s3 * 64 + ln];
        unsigned short h4 = xb[(size_t)s4 * 64 + ln];
        unsigned short h5 = xb[(size_t)s5 * 64 + ln];
        unsigned short h6 = xb[(size_t)s6 * 64 + ln];
        unsigned short h7 = xb[(size_t)s7 * 64 + ln];
        float w0 = dinv[s0], w1 = dinv[s1], w2 = dinv[s2], w3 = dinv[s3];
        float w4 = dinv[s4], w5 = dinv[s5], w6 = dinv[s6], w7 = dinv[s7];
        acc += bf2f(h0) + bf2f(h1) + bf2f(h2) + bf2f(h3)
             + bf2f(h4) + bf2f(h5) + bf2f(h6) + bf2f(h7);
        ts += w0 + w1 + w2 + w3 + w4 + w5 + w6 + w7;
    }
    for (; p < pend; ++p) {
        int s = esrc[p];
        acc += bf2f(xb[(size_t)s * 64 + ln]);
        ts += dinv[s];
    }
    u[(size_t)wv * 64 + ln] = acc;
    ub[(size_t)wv * 64 + ln] = f2bf(acc);
    if (ln == 0) t[wv] = di + ts;
}

// ---- fused v3 (MFMA): L^T = WaT @ ub^T (softmax -> S_T bf16 + Sf8 e4m3)
//      and Z^T = WeT @ ub^T -> Z_T bf16 directly. Block = 64 nodes (4 waves x 16). ----
#define F8ROW 520
__global__ void __launch_bounds__(256) fused_s2_kernel(
        const unsigned short* __restrict__ ub, const unsigned short* __restrict__ WaT,
        const unsigned short* __restrict__ WeT,
        const float* __restrict__ ba, const float* __restrict__ be,
        const float* __restrict__ dinv, const float* __restrict__ tsum,
        unsigned short* __restrict__ S_T, unsigned char* __restrict__ Sf8,
        unsigned short* __restrict__ Z_T, int n) {
    __shared__ float bs[512];
    __shared__ float bes[64];
    __shared__ unsigned char f8[64 * F8ROW];     // 33.3 KB fp8 node-major tile
    int t = threadIdx.x;
    int n0 = blockIdx.x * 64;
    {
        float b0 = (t * 2     < KK) ? ba[t * 2]     : 0.f;
        float b1 = (t * 2 + 1 < KK) ? ba[t * 2 + 1] : 0.f;
        bs[t * 2] = b0; bs[t * 2 + 1] = b1;
        if (t < 64) bes[t] = be[t];
    }
    __syncthreads();
    int wv = t >> 6, ln = t & 63;
    int nl = ln & 15;                 // node within wave tile (C col)
    int g  = ln >> 4;                 // quad
    int node = n0 + wv * 16 + nl;
    float sd = (node < n) ? dinv[node] : 0.f;
    float st = (node < n) ? tsum[node] : 0.f;
    const unsigned short* brow = ub + (size_t)node * 64;
    bf16x8 bf0 = *(const bf16x8*)&brow[g * 8];
    bf16x8 bf1 = *(const bf16x8*)&brow[32 + g * 8];
    f32x4 acc[32];
#pragma unroll
    for (int mt = 0; mt < 32; ++mt) {
        const unsigned short* arow = WaT + (size_t)(mt * 16 + nl) * 64;
        bf16x8 af0 = *(const bf16x8*)&arow[g * 8];
        bf16x8 af1 = *(const bf16x8*)&arow[32 + g * 8];
        f32x4 a = __builtin_amdgcn_mfma_f32_16x16x32_bf16(af0, bf0, (f32x4){0.f,0.f,0.f,0.f}, 0, 0, 0);
        acc[mt] = __builtin_amdgcn_mfma_f32_16x16x32_bf16(af1, bf1, a, 0, 0, 0);
    }
    // bias + mask + max
    float m = -1e30f;
#pragma unroll
    for (int mt = 0; mt < 32; ++mt) {
#pragma unroll
        for (int r = 0; r < 4; ++r) {
            int cl = mt * 16 + g * 4 + r;
            float L = sd * (acc[mt][r] + st * bs[cl]);
            if (cl >= KK) L = -1e30f;
            acc[mt][r] = L;
            m = fmaxf(m, L);
        }
    }
    m = fmaxf(m, __shfl_xor(m, 16, 64));
    m = fmaxf(m, __shfl_xor(m, 32, 64));
    float ssum = 0.f;
#pragma unroll
    for (int mt = 0; mt < 32; ++mt) {
#pragma unroll
        for (int r = 0; r < 4; ++r) {
            float e = expf(acc[mt][r] - m);
            acc[mt][r] = e;
            ssum += e;
        }
    }
    ssum += __shfl_xor(ssum, 16, 64);
    ssum += __shfl_xor(ssum, 32, 64);
    float rs = (node < n) ? (1.0f / ssum) : 0.f;
    float sc = 256.f * rs;
    unsigned char* frow = &f8[(wv * 16 + nl) * F8ROW];
#pragma unroll
    for (int mt = 0; mt < 32; ++mt) {
#pragma unroll
        for (int r = 0; r < 4; ++r) {
            int cl = mt * 16 + g * 4 + r;
            S_T[(size_t)cl * NPAD + node] = f2bf(acc[mt][r] * rs);
        }
#ifdef HAS_FP8_CVT
        int pk = __builtin_amdgcn_cvt_pk_fp8_f32(acc[mt][0] * sc, acc[mt][1] * sc, 0, false);
        pk     = __builtin_amdgcn_cvt_pk_fp8_f32(acc[mt][2] * sc, acc[mt][3] * sc, pk, true);
#else
        int pk = (int)(f32_to_fp8_slow(acc[mt][0]*sc) | (f32_to_fp8_slow(acc[mt][1]*sc) << 8) |
                       (f32_to_fp8_slow(acc[mt][2]*sc) << 16) | (f32_to_fp8_slow(acc[mt][3]*sc) << 24));
#endif
        *(unsigned*)&frow[mt * 16 + g * 4] = (unsigned)pk;
    }
    // embed conv: Z^T = WeT @ ub^T, write Z_T directly
#pragma unroll
    for (int mt = 0; mt < 4; ++mt) {
        const unsigned short* arow = WeT + (size_t)(mt * 16 + nl) * 64;
        bf16x8 af0 = *(const bf16x8*)&arow[g * 8];
        bf16x8 af1 = *(const bf16x8*)&arow[32 + g * 8];
        f32x4 a = __builtin_amdgcn_mfma_f32_16x16x32_bf16(af0, bf0, (f32x4){0.f,0.f,0.f,0.f}, 0, 0, 0);
        a = __builtin_amdgcn_mfma_f32_16x16x32_bf16(af1, bf1, a, 0, 0, 0);
#pragma unroll
        for (int r = 0; r < 4; ++r) {
            int ch = mt * 16 + g * 4 + r;
            float z = sd * (a[r] + st * bes[ch]);
            Z_T[(size_t)ch * NPAD + node] = f2bf(z);
        }
    }
    __syncthreads();
    // coalesced Sf8 row stores
#pragma unroll
    for (int h = 0; h < 8; ++h) {
        int idx = t + h * 256;
        int row = idx >> 5;
        int off = (idx & 31) * 16;
        uint4 vv = *(const uint4*)&f8[row * F8ROW + off];
        int grow = n0 + row;
        if (grow < n) *(uint4*)&Sf8[(size_t)grow * KPAD + off] = vv;
    }
}

// -------- G = A^T S via in-CSR over fp8 S, written TRANSPOSED bf16: G_T[k][n] --------
#define GT_ROWS 32
__global__ void __launch_bounds__(256) g_agg_t_kernel(
        const unsigned char* __restrict__ Sf8, const int* __restrict__ offs,
        const int* __restrict__ esrc, unsigned short* __restrict__ G_T, int n) {
    __shared__ unsigned short tl[GT_ROWS * 520];
    int base = blockIdx.x * GT_ROWS;
    int wv = threadIdx.x >> 6, ln = threadIdx.x & 63;
    const uint2* S2 = (const uint2*)Sf8;
#pragma unroll
    for (int i = 0; i < GT_ROWS / 4; ++i) {
        int r = wv * (GT_ROWS / 4) + i;
        int node = base + r;
        float a[8] = {0.f,0.f,0.f,0.f,0.f,0.f,0.f,0.f};
        if (node < n) {
            int p = offs[node], pend = offs[node + 1];
            for (; p + 7 < pend; p += 8) {       // 8 independent 8B gathers in flight
                int s0 = esrc[p],     s1 = esrc[p + 1], s2 = esrc[p + 2], s3 = esrc[p + 3];
                int s4 = esrc[p + 4], s5 = esrc[p + 5], s6 = esrc[p + 6], s7 = esrc[p + 7];
                uint2 v0 = S2[(size_t)s0 * 64 + ln];
                uint2 v1 = S2[(size_t)s1 * 64 + ln];
                uint2 v2 = S2[(size_t)s2 * 64 + ln];
                uint2 v3 = S2[(size_t)s3 * 64 + ln];
                uint2 v4 = S2[(size_t)s4 * 64 + ln];
                uint2 v5 = S2[(size_t)s5 * 64 + ln];
                uint2 v6 = S2[(size_t)s6 * 64 + ln];
                uint2 v7 = S2[(size_t)s7 * 64 + ln];
                accf8(a, v0); accf8(a, v1); accf8(a, v2); accf8(a, v3);
                accf8(a, v4); accf8(a, v5); accf8(a, v6); accf8(a, v7);
            }
            for (; p < pend; ++p) {
                uint2 v = S2[(size_t)esrc[p] * 64 + ln];
                accf8(a, v);
            }
        }
        const float inv = 1.0f / 256.f;
        uint4 o;
        o.x = packbf(a[0] * inv, a[1] * inv); o.y = packbf(a[2] * inv, a[3] * inv);
        o.z = packbf(a[4] * inv, a[5] * inv); o.w = packbf(a[6] * inv, a[7] * inv);
        *(uint4*)&tl[r * 520 + ln * 8] = o;
    }
    __syncthreads();
#pragma unroll
    for (int h = 0; h < 2; ++h) {
        int k = threadIdx.x + h * 256;
        unsigned wb[8];
#pragma unroll
        for (int j = 0; j < 8; ++j) {
            unsigned short lo = tl[(2 * j)     * 520 + k];
            unsigned short hi = tl[(2 * j + 1) * 520 + k];
            wb[j] = ((unsigned)hi << 16) | (unsigned)lo;
        }
        unsigned wc[8];
#pragma unroll
        for (int j = 0; j < 8; ++j) {
            unsigned short lo = tl[(16 + 2 * j) * 520 + k];
            unsigned short hi = tl[(17 + 2 * j) * 520 + k];
            wc[j] = ((unsigned)hi << 16) | (unsigned)lo;
        }
        size_t ob = (size_t)k * NPAD + base;
        *(uint4*)&G_T[ob]      = make_uint4(wb[0], wb[1], wb[2], wb[3]);
        *(uint4*)&G_T[ob + 8]  = make_uint4(wb[4], wb[5], wb[6], wb[7]);
        *(uint4*)&G_T[ob + 16] = make_uint4(wc[0], wc[1], wc[2], wc[3]);
        *(uint4*)&G_T[ob + 24] = make_uint4(wc[4], wc[5], wc[6], wc[7]);
    }
}

// ---------------- MFMA TN GEMM 128x128 (next_X) ----------------
__global__ void __launch_bounds__(256) mfma_tn_kernel(
        const unsigned short* __restrict__ A_T, const unsigned short* __restrict__ B_T,
        float* __restrict__ partial, int nPer, int NBpad) {
    const int a0 = blockIdx.x * 128, b0 = blockIdx.y * 128;
    const int nbeg = blockIdx.z * nPer;
    const int nend = min(nbeg + nPer, NPAD);
    __shared__ unsigned short Al[128 * 72];
    __shared__ unsigned short Bl[128 * 72];
    const int t = threadIdx.x;
    const int ln = t & 63, wv = t >> 6;
    const int wa = (wv & 1) * 64, wb = (wv >> 1) * 64;
    const int lm = ln & 15, lk = (ln >> 4) * 8;
    f32x4 acc[4][4];
#pragma unroll
    for (int i = 0; i < 4; ++i)
#pragma unroll
        for (int j = 0; j < 4; ++j) acc[i][j] = (f32x4){0.f, 0.f, 0.f, 0.f};
    for (int nb = nbeg; nb < nend; nb += 64) {
        __syncthreads();
#pragma unroll
        for (int i = 0; i < 4; ++i) {
            int idx = t + i * 256;
            int r = idx >> 3, c8 = (idx & 7) * 8;
            uint4 va = *(const uint4*)&A_T[(size_t)(a0 + r) * NPAD + nb + c8];
            uint4 vb = *(const uint4*)&B_T[(size_t)(b0 + r) * NPAD + nb + c8];
            *(uint4*)&Al[r * 72 + c8] = va;
            *(uint4*)&Bl[r * 72 + c8] = vb;
        }
        __syncthreads();
#pragma unroll
        for (int ks = 0; ks < 64; ks += 32) {
            bf16x8 af[4], bfr[4];
#pragma unroll
            for (int i = 0; i < 4; ++i)
                af[i] = *(const bf16x8*)&Al[(wa + i * 16 + lm) * 72 + ks + lk];
#pragma unroll
            for (int j = 0; j < 4; ++j)
                bfr[j] = *(const bf16x8*)&Bl[(wb + j * 16 + lm) * 72 + ks + lk];
#pragma unroll
            for (int i = 0; i < 4; ++i)
#pragma unroll
                for (int j = 0; j < 4; ++j)
                    acc[i][j] = __builtin_amdgcn_mfma_f32_16x16x32_bf16(af[i], bfr[j], acc[i][j], 0, 0, 0);
        }
    }
    float* op = partial + (size_t)blockIdx.z * 512 * NBpad;
#pragma unroll
    for (int i = 0; i < 4; ++i) {
#pragma unroll
        for (int j = 0; j < 4; ++j) {
            int bg = b0 + wb + j * 16 + lm;
#pragma unroll
            for (int r = 0; r < 4; ++r) {
                int ag = a0 + wa + i * 16 + (ln >> 4) * 4 + r;
                op[(size_t)ag * NBpad + bg] = acc[i][j][r];
            }
        }
    }
}

// ---------------- MFMA TN GEMM 256a x 128b (next_A) ----------------
__global__ void __launch_bounds__(256) mfma_tn256_kernel(
        const unsigned short* __restrict__ A_T, const unsigned short* __restrict__ B_T,
        float* __restrict__ partial, int nPer) {
    const int a0 = blockIdx.x * 256, b0 = blockIdx.y * 128;
    const int nbeg = blockIdx.z * nPer;
    const int nend = min(nbeg + nPer, NPAD);
    __shared__ unsigned short Al[256 * 72];
    __shared__ unsigned short Bl[128 * 72];
    const int t = threadIdx.x;
    const int ln = t & 63, wv = t >> 6;
    const int wa = wv * 64;
    const int lm = ln & 15, lk = (ln >> 4) * 8;
    f32x4 acc[4][8];
#pragma unroll
    for (int i = 0; i < 4; ++i)
#pragma unroll
        for (int j = 0; j < 8; ++j) acc[i][j] = (f32x4){0.f, 0.f, 0.f, 0.f};
    for (int nb = nbeg; nb < nend; nb += 64) {
        __syncthreads();
#pragma unroll
        for (int i = 0; i < 8; ++i) {
            int idx = t + i * 256;
            int r = idx >> 3, c8 = (idx & 7) * 8;
            uint4 va = *(const uint4*)&A_T[(size_t)(a0 + r) * NPAD + nb + c8];
            *(uint4*)&Al[r * 72 + c8] = va;
        }
#pragma unroll
        for (int i = 0; i < 4; ++i) {
            int idx = t + i * 256;
            int r = idx >> 3, c8 = (idx & 7) * 8;
            uint4 vb = *(const uint4*)&B_T[(size_t)(b0 + r) * NPAD + nb + c8];
            *(uint4*)&Bl[r * 72 + c8] = vb;
        }
        __syncthreads();
#pragma unroll
        for (int ks = 0; ks < 64; ks += 32) {
            bf16x8 af[4], bfr[8];
#pragma unroll
            for (int i = 0; i < 4; ++i)
                af[i] = *(const bf16x8*)&Al[(wa + i * 16 + lm) * 72 + ks + lk];
#pragma unroll
            for (int j = 0; j < 8; ++j)
                bfr[j] = *(const bf16x8*)&Bl[(j * 16 + lm) * 72 + ks + lk];
#pragma unroll
            for (int i = 0; i < 4; ++i)
#pragma unroll
                for (int j = 0; j < 8; ++j)
                    acc[i][j] = __builtin_amdgcn_mfma_f32_16x16x32_bf16(af[i], bfr[j], acc[i][j], 0, 0, 0);
        }
    }
    float* op = partial + (size_t)blockIdx.z * 512 * 512;
#pragma unroll
    for (int i = 0; i < 4; ++i) {
#pragma unroll
        for (int j = 0; j < 8; ++j) {
            int bg = b0 + j * 16 + lm;
#pragma unroll
            for (int r = 0; r < 4; ++r) {
                int ag = a0 + wa + i * 16 + (ln >> 4) * 4 + r;
                op[(size_t)ag * 512 + bg] = acc[i][j][r];
            }
        }
    }
}

// ---------------- split-K reduce ----------------
__global__ void reduce_kernel(const float* __restrict__ partial, float* __restrict__ out,
                              int rows, int cols, int NBpad, int Z) {
    int idx = blockIdx.x * blockDim.x + threadIdx.x;
    if (idx >= rows * cols) return;
    int a = idx / cols, b = idx - a * cols;
    const float* p = partial + (size_t)a * NBpad + b;
    size_t step = (size_t)512 * NBpad;
    float s = 0.f;
    for (int z = 0; z < Z; ++z) s += p[(size_t)z * step];
    out[idx] = s;
}

extern "C" void kernel_launch(void* const* d_in, const int* in_sizes, int n_in,
                              void* d_out, int out_size, void* d_ws, size_t ws_size,
                              hipStream_t stream) {
    const float* x        = (const float*)d_in[0];
    const int*   ei       = (const int*)d_in[1];
    const float* W_embed  = (const float*)d_in[2];
    const float* b_embed  = (const float*)d_in[3];
    const float* W_assign = (const float*)d_in[4];
    const float* b_assign = (const float*)d_in[5];

    const int N = in_sizes[0] / DD;     // 50000
    const int E = in_sizes[1] / 2;      // 800000
    const int C = in_sizes[3];          // 64
    const int K = in_sizes[5];          // 500

    const int* rowv = ei;
    const int* colv = ei + E;

    char* p = (char*)d_ws;
    auto alloc = [&](size_t bytes) -> void* {
        void* r = (void*)p;
        p += (bytes + 255) & ~(size_t)255;
        return r;
    };
    int*   cnt      = (int*)alloc((size_t)2 * NS * 4);
    int*   cnt_col  = cnt;
    int*   cnt_row  = cnt + NS;
    int*   offs_col = (int*)alloc((size_t)(N + 1) * 4);
    int*   cur_col  = (int*)alloc((size_t)N * 4);
    int*   bsum     = (int*)alloc(64 * 4);
    int*   bbase    = (int*)alloc(64 * 4);
    float* dinv     = (float*)alloc((size_t)N * 4);
    float* tsum     = (float*)alloc((size_t)N * 4);
    int*   esrc     = (int*)alloc((size_t)E * 4);
    float* u        = (float*)alloc((size_t)N * DD * 4);                   // 12.8 MB
    unsigned short* xb   = (unsigned short*)alloc((size_t)N * DD * 2);     // 6.4 MB
    unsigned short* ubuf = (unsigned short*)alloc((size_t)NPAD * DD * 2);  // 6.4 MB
    unsigned short* WaT  = (unsigned short*)alloc((size_t)KPAD * DD * 2);  // 64 KB
    unsigned short* WeT  = (unsigned short*)alloc((size_t)DD * DD * 2);    // 8 KB
    unsigned char*  Sf8  = (unsigned char*)alloc((size_t)N * KPAD);        // 25.6 MB
    unsigned short* S_T  = (unsigned short*)alloc((size_t)KPAD * NPAD * 2);
    unsigned short* G_T  = (unsigned short*)alloc((size_t)KPAD * NPAD * 2);
    unsigned short* Z_T  = (unsigned short*)alloc((size_t)128 * NPAD * 2);

    // split-K (nPer=1088, Z=46: 1088*46 == NPAD)
    const int nPer = 1088, ZSK = 46;
    float* partialA = (float*)alloc((size_t)ZSK * 512 * 512 * 4);          // 48.2 MB
    float* partialX = (float*)u;    // 46*512*128*4 = 12.06 MB <= 12.8 MB (u dead by then)

    float* outX = (float*)d_out;            // [500][64]
    float* outA = outX + (size_t)K * C;     // [500][500]

    const int NB = (N + 1023) / 1024;       // 49 scan tiles

    (void)hipMemsetAsync(cnt, 0, (size_t)2 * NS * 4, stream);

    hist_kernel<<<(E + 255) / 256, 256, 0, stream>>>(rowv, colv, cnt_row, cnt_col, E);
    scanA_kernel<<<NB, 256, 0, stream>>>(cnt_col, bsum);
    scanB_kernel<<<1, 64, 0, stream>>>(bsum, bbase, &offs_col[N], NB);
    scanC_kernel<<<NB, 256, 0, stream>>>(cnt_col, cnt_row, bbase, offs_col, cur_col, dinv, N);
    place_kernel<<<(E + 255) / 256, 256, 0, stream>>>(rowv, colv, cur_col, esrc, E);

    xscale_kernel<<<(N * 16 + 255) / 256, 256, 0, stream>>>(x, dinv, xb, N * 16);
    wprep_kernel<<<((KPAD + DD) * DD) / 256, 256, 0, stream>>>(W_assign, W_embed, WaT, WeT);

    // u (fp32 + bf16) over NPAD rows; tsum folded
    agg_kernel<<<NPAD / 4, 256, 0, stream>>>(xb, dinv, offs_col, esrc, u, tsum, ubuf, N);

    // fused: S_T + Sf8 + Z_T (all MFMA)
    fused_s2_kernel<<<NPAD / 64, 256, 0, stream>>>(ubuf, WaT, WeT, b_assign, b_embed,
                                                   dinv, tsum, S_T, Sf8, Z_T, N);

    // G_T = (A^T S)^T via fp8 gather
    g_agg_t_kernel<<<NPAD / GT_ROWS, 256, 0, stream>>>(Sf8, offs_col, esrc, G_T, N);

    // next_X = S^T @ Z
    {
        dim3 g(4, 1, ZSK);
        mfma_tn_kernel<<<g, 256, 0, stream>>>(S_T, Z_T, partialX, nPer, 128);
        reduce_kernel<<<(K * C + 255) / 256, 256, 0, stream>>>(partialX, outX, K, C, 128, ZSK);
    }
    // next_A = G^T @ S
    {
        dim3 g(2, 4, ZSK);
        mfma_tn256_kernel<<<g, 256, 0, stream>>>(G_T, S_T, partialA, nPer);
        reduce_kernel<<<(K * K + 255) / 256, 256, 0, stream>>>(partialA, outA, K, K, 512, ZSK);
    }
}